// Round 4
// baseline (1142.378 us; speedup 1.0000x reference)
//
#include <hip/hip_runtime.h>
#include <hip/hip_bf16.h>
#include <math.h>

constexpr int SEQ = 256;
constexpr int DIM = 768;
constexpr int NH  = 8;
constexpr int HD  = 96;

typedef __attribute__((ext_vector_type(8))) short short8;
typedef __attribute__((ext_vector_type(4))) float f32x4;
using bf16 = __hip_bfloat16;

#define ASYNC_COPY16(gptr, lptr) \
  __builtin_amdgcn_global_load_lds((const __attribute__((address_space(1))) void*)(gptr), \
                                   (__attribute__((address_space(3))) void*)(lptr), 16, 0, 0)

// ---------------------------------------------------------------------------
// f32 tiled GEMM (tiny positional-bias precompute only)
// ---------------------------------------------------------------------------
__global__ __launch_bounds__(256) void gemm_kernel(
    const float* __restrict__ A, int lda, long aoz,
    const float* __restrict__ W, int ldw, long woz,
    const float* __restrict__ bias,
    float* __restrict__ C, int ldc, long coz,
    int M, int N, int K, float scale)
{
    A += (long)blockIdx.z * aoz;
    W += (long)blockIdx.z * woz;
    C += (long)blockIdx.z * coz;

    __shared__ float As[16][68];
    __shared__ float Ws[16][68];

    const int bm = blockIdx.y * 64;
    const int bn = blockIdx.x * 64;
    const int tid = threadIdx.x;
    const int tx = tid & 15;
    const int ty = tid >> 4;

    float acc[4][4] = {};

    for (int k0 = 0; k0 < K; k0 += 16) {
#pragma unroll
        for (int i = 0; i < 4; i++) {
            int idx = tid + i * 256;
            int r = idx >> 4, c = idx & 15;
            As[c][r] = A[(long)(bm + r) * lda + (k0 + c)];
            Ws[c][r] = W[(long)(bn + r) * ldw + (k0 + c)];
        }
        __syncthreads();
#pragma unroll
        for (int kk = 0; kk < 16; kk++) {
            const float4 a = *(const float4*)&As[kk][ty * 4];
            const float4 w = *(const float4*)&Ws[kk][tx * 4];
            acc[0][0] += a.x * w.x; acc[0][1] += a.x * w.y; acc[0][2] += a.x * w.z; acc[0][3] += a.x * w.w;
            acc[1][0] += a.y * w.x; acc[1][1] += a.y * w.y; acc[1][2] += a.y * w.z; acc[1][3] += a.y * w.w;
            acc[2][0] += a.z * w.x; acc[2][1] += a.z * w.y; acc[2][2] += a.z * w.z; acc[2][3] += a.z * w.w;
            acc[3][0] += a.w * w.x; acc[3][1] += a.w * w.y; acc[3][2] += a.w * w.z; acc[3][3] += a.w * w.w;
        }
        __syncthreads();
    }

    const int n0 = bn + tx * 4;
    float4 bv = make_float4(0.f, 0.f, 0.f, 0.f);
    if (bias) bv = *(const float4*)&bias[n0];
#pragma unroll
    for (int i = 0; i < 4; i++) {
        const int m = bm + ty * 4 + i;
        float4 r;
        r.x = (acc[i][0] + bv.x) * scale;
        r.y = (acc[i][1] + bv.y) * scale;
        r.z = (acc[i][2] + bv.z) * scale;
        r.w = (acc[i][3] + bv.w) * scale;
        *(float4*)&C[(long)m * ldc + n0] = r;
    }
}

// ---------------------------------------------------------------------------
// LayerNorm of pos_emb rows
// ---------------------------------------------------------------------------
__global__ __launch_bounds__(256) void posln_kernel(
    const float* __restrict__ pe, const float* __restrict__ g,
    const float* __restrict__ bb, float* __restrict__ w)
{
    __shared__ float buf[256];
    const int i = blockIdx.x, tid = threadIdx.x;
    const float* row = pe + (long)i * DIM;
    float v0 = row[tid], v1 = row[tid + 256], v2 = row[tid + 512];

    buf[tid] = v0 + v1 + v2;
    __syncthreads();
    for (int off = 128; off > 0; off >>= 1) {
        if (tid < off) buf[tid] += buf[tid + off];
        __syncthreads();
    }
    const float mean = buf[0] * (1.f / 768.f);
    __syncthreads();

    const float d0 = v0 - mean, d1 = v1 - mean, d2 = v2 - mean;
    buf[tid] = d0 * d0 + d1 * d1 + d2 * d2;
    __syncthreads();
    for (int off = 128; off > 0; off >>= 1) {
        if (tid < off) buf[tid] += buf[tid + off];
        __syncthreads();
    }
    const float rstd = rsqrtf(buf[0] * (1.f / 768.f) + 1e-5f);

    float* wr = w + (long)i * DIM;
    wr[tid]       = d0 * rstd * g[tid]       + bb[tid];
    wr[tid + 256] = d1 * rstd * g[tid + 256] + bb[tid + 256];
    wr[tid + 512] = d2 * rstd * g[tid + 512] + bb[tid + 512];
}

// bias[h, ij] += table[rp[ij], h]
__global__ __launch_bounds__(256) void relbias_kernel(
    const float* __restrict__ table, const int* __restrict__ rp,
    float* __restrict__ bias)
{
    const int ij = blockIdx.x * 256 + threadIdx.x;
    const int bucket = rp[ij];
#pragma unroll
    for (int h = 0; h < NH; h++)
        bias[(long)h * SEQ * SEQ + ij] += table[bucket * NH + h];
}

// ---------------------------------------------------------------------------
// weight / bias conversion to bf16 (q-scale folded)
// ---------------------------------------------------------------------------
__global__ __launch_bounds__(256) void convert_qkv_kernel(
    const float* __restrict__ Wq, const float* __restrict__ Wk,
    const float* __restrict__ Wv, bf16* __restrict__ wqkv, float scale)
{
    const long idx = (long)blockIdx.x * 256 + threadIdx.x; // over 6*2304*768/4
    const long e = idx * 4;
    const int k = (int)(e % 768);
    const long nl = e / 768;
    const int n = (int)(nl % 2304);
    const int l = (int)(nl / 2304);

    const float* src;
    float sc = 1.f;
    if (n < 768)       { src = Wq + ((long)l * 768 + n) * 768; sc = scale; }
    else if (n < 1536) { src = Wk + ((long)l * 768 + (n - 768)) * 768; }
    else               { src = Wv + ((long)l * 768 + (n - 1536)) * 768; }

    const float4 v = *(const float4*)&src[k];
    bf16 tmp[4];
    tmp[0] = __float2bfloat16(v.x * sc);
    tmp[1] = __float2bfloat16(v.y * sc);
    tmp[2] = __float2bfloat16(v.z * sc);
    tmp[3] = __float2bfloat16(v.w * sc);
    *(uint2*)&wqkv[((long)l * 2304 + n) * 768 + k] = *(uint2*)tmp;
}

__global__ __launch_bounds__(256) void convert_wo_kernel(
    const float* __restrict__ Wo, bf16* __restrict__ wo)
{
    const long idx = (long)blockIdx.x * 256 + threadIdx.x; // over 6*768*768/4
    const long e = idx * 4;
    const float4 v = *(const float4*)&Wo[e];
    bf16 tmp[4];
    tmp[0] = __float2bfloat16(v.x);
    tmp[1] = __float2bfloat16(v.y);
    tmp[2] = __float2bfloat16(v.z);
    tmp[3] = __float2bfloat16(v.w);
    *(uint2*)&wo[e] = *(uint2*)tmp;
}

__global__ __launch_bounds__(256) void convert_bias_kernel(
    const float* __restrict__ bq, const float* __restrict__ bk,
    const float* __restrict__ bv, float* __restrict__ bqkv, float scale)
{
    const int idx = blockIdx.x * 256 + threadIdx.x; // over 6*2304
    const int n = idx % 2304;
    const int l = idx / 2304;
    float v;
    if (n < 768)       v = bq[l * 768 + n] * scale;
    else if (n < 1536) v = bk[l * 768 + (n - 768)];
    else               v = bv[l * 768 + (n - 1536)];
    bqkv[idx] = v;
}

// x_bf[t,:] = bf16(embed[tokens[t],:])
__global__ __launch_bounds__(192) void gather_bf16_kernel(
    const int* __restrict__ tokens, const float* __restrict__ emb,
    bf16* __restrict__ x)
{
    const int t = blockIdx.x;
    const int tok = tokens[t];
    const float4 v = ((const float4*)(emb + (long)tok * DIM))[threadIdx.x];
    bf16 tmp[4];
    tmp[0] = __float2bfloat16(v.x);
    tmp[1] = __float2bfloat16(v.y);
    tmp[2] = __float2bfloat16(v.z);
    tmp[3] = __float2bfloat16(v.w);
    *(uint2*)&x[(long)t * DIM + threadIdx.x * 4] = *(uint2*)tmp;
}

// ---------------------------------------------------------------------------
// bf16 MFMA GEMM: C[m,n] = sum_k A[m,k]*B[n,k] + bias[n]
// 128x128 tile, BK=64, XOR-swizzled LDS, XCD M-stripe swizzle.
// vTout != null: blocks with bn >= 1536 (the V part of QKV) write transposed
// vT[b][h][d][s] instead of C.  Cf != null -> f32 output, else bf16.
// ---------------------------------------------------------------------------
__global__ __launch_bounds__(256) void gemm_bf16_kernel(
    const bf16* __restrict__ A, const bf16* __restrict__ B,
    const float* __restrict__ bias,
    bf16* __restrict__ Cb, float* __restrict__ Cf, bf16* __restrict__ vTout,
    int N, int K)
{
    __shared__ bf16 As[128 * 64];   // 16 KB each
    __shared__ bf16 Bs[128 * 64];

    const int tid = threadIdx.x;
    const int lane = tid & 63, wave = tid >> 6;
    const int wm = wave & 1, wn = wave >> 1;

    const int id = blockIdx.x + gridDim.x * blockIdx.y;
    const int xcd = id & 7, loc = id >> 3;
    const int bmt = xcd * 8 + (loc & 7);     // m-tile (gridDim.y==64)
    const int bnt = loc >> 3;                // n-tile
    const long bm = (long)bmt * 128, bn = (long)bnt * 128;

    const int col = lane & 15, quad = lane >> 4;

    f32x4 acc[4][4] = {};

    for (int k0 = 0; k0 < K; k0 += 64) {
        __syncthreads();
#pragma unroll
        for (int i = 0; i < 4; i++) {
            const int u = tid + i * 256;            // 0..1023
            const int r = u >> 3, c = u & 7;
            const int ca = c ^ (r & 7);             // swizzled k-chunk
            ASYNC_COPY16(A + (bm + r) * (long)K + k0 + ca * 8, &As[u * 8]);
            ASYNC_COPY16(B + (bn + r) * (long)K + k0 + ca * 8, &Bs[u * 8]);
        }
        __syncthreads();

#pragma unroll
        for (int ks = 0; ks < 2; ks++) {
            const int cc = ks * 4 + quad;           // content k-chunk
            short8 af[4], bfr[4];
#pragma unroll
            for (int t = 0; t < 4; t++) {
                const int ra = wm * 64 + t * 16 + col;
                const int rb = wn * 64 + t * 16 + col;
                af[t]  = *(const short8*)&As[ra * 64 + ((cc ^ (ra & 7)) * 8)];
                bfr[t] = *(const short8*)&Bs[rb * 64 + ((cc ^ (rb & 7)) * 8)];
            }
#pragma unroll
            for (int tm = 0; tm < 4; tm++)
#pragma unroll
                for (int tn = 0; tn < 4; tn++)
                    acc[tm][tn] = __builtin_amdgcn_mfma_f32_16x16x32_bf16(af[tm], bfr[tn], acc[tm][tn], 0, 0, 0);
        }
    }

    const bool toVT = (vTout != nullptr) && (bn >= 1536);   // block-uniform

#pragma unroll
    for (int tn = 0; tn < 4; tn++) {
        const long n = bn + wn * 64 + tn * 16 + col;
        const float bvv = bias[n];
#pragma unroll
        for (int tm = 0; tm < 4; tm++) {
#pragma unroll
            for (int r = 0; r < 4; r++) {
                const long m = bm + wm * 64 + tm * 16 + quad * 4 + r;
                const float v = acc[tm][tn][r] + bvv;
                if (toVT) {
                    // vT[b][h*96+d][s]: n-1536 = h*96+d, m = b*256+s
                    vTout[((m >> 8) * 768 + (n - 1536)) * 256 + (m & 255)] = __float2bfloat16(v);
                } else if (Cf) {
                    Cf[m * N + n] = v;
                } else {
                    Cb[m * N + n] = __float2bfloat16(v);
                }
            }
        }
    }
}

// ---------------------------------------------------------------------------
// MFMA attention, zero-staging: Q in regs, K/V fragments straight from global
// (K natural [j][d]; V pre-transposed vT[b][h][d][s]). LDS = Ps only.
// One __syncthreads per block. Block per (it, h, b), b innermost.
// ---------------------------------------------------------------------------
__global__ __launch_bounds__(256) void attn_mfma_kernel(
    const bf16* __restrict__ qkv, const bf16* __restrict__ vT,
    const float* __restrict__ bias, bf16* __restrict__ o)
{
    constexpr int PS = 264;  // Ps stride (bf16)
    __shared__ bf16 Ps[64 * PS];   // 33.8 KB -> 4 blocks/CU

    const int blk = blockIdx.x;          // 4*8*32
    const int b  = blk & 31;
    const int h  = (blk >> 5) & 7;
    const int it = blk >> 8;
    const int i0 = it * 64;
    const int tid = threadIdx.x, lane = tid & 63, wave = tid >> 6;
    const int col = lane & 15, quad = lane >> 4;
    const long rowbase = (long)b * SEQ;

    // Q fragments (A-operand layout): row i0+wave*16+col, k = ks*32+quad*8
    short8 aq[3];
    {
        const bf16* qrow = qkv + (rowbase + i0 + wave * 16 + col) * 2304 + h * 96;
#pragma unroll
        for (int ks = 0; ks < 3; ks++)
            aq[ks] = *(const short8*)&qrow[ks * 32 + quad * 8];
    }

    // ---- scores: K fragments direct from global (16 rows x 64B, coalesced) ----
    f32x4 accS[16];
#pragma unroll
    for (int jt = 0; jt < 16; jt++) {
        const bf16* krow = qkv + (rowbase + jt * 16 + col) * 2304 + 768 + h * 96;
        f32x4 a = {};
#pragma unroll
        for (int ks = 0; ks < 3; ks++) {
            const short8 bk_ = *(const short8*)&krow[ks * 32 + quad * 8];
            a = __builtin_amdgcn_mfma_f32_16x16x32_bf16(aq[ks], bk_, a, 0, 0, 0);
        }
        accS[jt] = a;
    }

    // ---- bias + softmax (rows i0+wave*16+quad*4+r, col jt*16+col) ----
    const float* bb = bias + ((long)h * SEQ + i0 + wave * 16 + quad * 4) * SEQ;
#pragma unroll
    for (int jt = 0; jt < 16; jt++)
#pragma unroll
        for (int r = 0; r < 4; r++)
            accS[jt][r] += bb[r * SEQ + jt * 16 + col];

#pragma unroll
    for (int r = 0; r < 4; r++) {
        float m = accS[0][r];
#pragma unroll
        for (int jt = 1; jt < 16; jt++) m = fmaxf(m, accS[jt][r]);
        for (int d = 1; d < 16; d <<= 1) m = fmaxf(m, __shfl_xor(m, d));
        float s = 0.f;
#pragma unroll
        for (int jt = 0; jt < 16; jt++) {
            const float e = __expf(accS[jt][r] - m);
            accS[jt][r] = e;
            s += e;
        }
        for (int d = 1; d < 16; d <<= 1) s += __shfl_xor(s, d);
        const float inv = 1.f / s;
        const int prow = wave * 16 + quad * 4 + r;
#pragma unroll
        for (int jt = 0; jt < 16; jt++)
            Ps[prow * PS + jt * 16 + col] = __float2bfloat16(accS[jt][r] * inv);
    }
    __syncthreads();   // each wave reads only its own 16 rows, but play safe

    // ---- O = P.V : V fragments direct from vT (16 rows x 64B, coalesced) ----
    f32x4 accO[6] = {};
    const bf16* vbase = vT + ((long)b * 768 + h * 96) * 256;
    for (int kc = 0; kc < 8; kc++) {
        const short8 ap = *(const short8*)&Ps[(wave * 16 + col) * PS + kc * 32 + quad * 8];
#pragma unroll
        for (int nt = 0; nt < 6; nt++) {
            const short8 bv_ = *(const short8*)&vbase[(nt * 16 + col) * 256 + kc * 32 + quad * 8];
            accO[nt] = __builtin_amdgcn_mfma_f32_16x16x32_bf16(ap, bv_, accO[nt], 0, 0, 0);
        }
    }

#pragma unroll
    for (int nt = 0; nt < 6; nt++)
#pragma unroll
        for (int r = 0; r < 4; r++) {
            const long m = rowbase + i0 + wave * 16 + quad * 4 + r;
            o[m * DIM + h * 96 + nt * 16 + col] = __float2bfloat16(accO[nt][r]);
        }
}

// out[b,:] = xf[b, 0, :]
__global__ __launch_bounds__(256) void out_kernel(
    const float* __restrict__ x, float* __restrict__ out)
{
    const int b = blockIdx.x, tid = threadIdx.x;
    out[b * DIM + tid]       = x[(long)b * SEQ * DIM + tid];
    out[b * DIM + tid + 256] = x[(long)b * SEQ * DIM + tid + 256];
    out[b * DIM + tid + 512] = x[(long)b * SEQ * DIM + tid + 512];
}

extern "C" void kernel_launch(void* const* d_in, const int* in_sizes, int n_in,
                              void* d_out, int out_size, void* d_ws, size_t ws_size,
                              hipStream_t stream)
{
    const int*   tokens   = (const int*)d_in[0];
    const float* embed    = (const float*)d_in[1];
    const float* pos_emb  = (const float*)d_in[2];
    const float* pos_q_w  = (const float*)d_in[3];
    const float* pos_q_b  = (const float*)d_in[4];
    const float* pos_k_w  = (const float*)d_in[5];
    const float* pos_k_b  = (const float*)d_in[6];
    const float* pos_ln_g = (const float*)d_in[7];
    const float* pos_ln_b = (const float*)d_in[8];
    const float* rel_tab  = (const float*)d_in[9];
    const int*   rp       = (const int*)d_in[10];
    const float* Wq = (const float*)d_in[11];
    const float* bq = (const float*)d_in[12];
    const float* Wk = (const float*)d_in[13];
    const float* bk = (const float*)d_in[14];
    const float* Wv = (const float*)d_in[15];
    const float* bv = (const float*)d_in[16];
    const float* Wo = (const float*)d_in[17];
    const float* bo = (const float*)d_in[18];
    float* out = (float*)d_out;

    char* p = (char*)d_ws;
    auto alloc = [&](size_t bytes) -> char* {
        char* r = p;
        p += (bytes + 255) & ~(size_t)255;
        return r;
    };
    const long NT = 32L * SEQ;  // 8192

    float* bias  = (float*)alloc(8L * SEQ * SEQ * 4);
    float* wln   = (float*)alloc((long)SEQ * DIM * 4);
    float* pq    = (float*)alloc((long)SEQ * DIM * 4);
    float* pk    = (float*)alloc((long)SEQ * DIM * 4);
    bf16*  xb    = (bf16*) alloc(NT * DIM * 2);
    bf16*  qkv   = (bf16*) alloc(NT * 2304 * 2);
    bf16*  vT    = (bf16*) alloc(NT * DIM * 2);   // [32][8][96][256]
    bf16*  ob    = (bf16*) alloc(NT * DIM * 2);
    float* xf    = (float*)alloc(NT * DIM * 4);
    bf16*  wqkv  = (bf16*) alloc(6L * 2304 * 768 * 2);
    bf16*  wo    = (bf16*) alloc(6L * 768 * 768 * 2);
    float* bqkv  = (float*)alloc(6L * 2304 * 4);

    const float SCALE = 0.07216878364870322f;   // (HD*2)^-0.5

    // weight conversion (bf16, q-scale folded)
    convert_qkv_kernel<<<(6L * 2304 * 768 / 4 + 255) / 256, 256, 0, stream>>>(Wq, Wk, Wv, wqkv, SCALE);
    convert_wo_kernel<<<(6L * 768 * 768 / 4 + 255) / 256, 256, 0, stream>>>(Wo, wo);
    convert_bias_kernel<<<(6 * 2304 + 255) / 256, 256, 0, stream>>>(bq, bk, bv, bqkv, SCALE);

    // positional bias precompute (f32)
    posln_kernel<<<256, 256, 0, stream>>>(pos_emb, pos_ln_g, pos_ln_b, wln);
    gemm_kernel<<<dim3(12, 4, 1), 256, 0, stream>>>(wln, DIM, 0, pos_q_w, DIM, 0, pos_q_b,
                                                    pq, DIM, 0, SEQ, DIM, DIM, SCALE);
    gemm_kernel<<<dim3(12, 4, 1), 256, 0, stream>>>(wln, DIM, 0, pos_k_w, DIM, 0, pos_k_b,
                                                    pk, DIM, 0, SEQ, DIM, DIM, 1.0f);
    gemm_kernel<<<dim3(4, 4, NH), 256, 0, stream>>>(pq, DIM, HD, pk, DIM, HD, nullptr,
                                                    bias, SEQ, (long)SEQ * SEQ, SEQ, SEQ, HD, 1.0f);
    relbias_kernel<<<256, 256, 0, stream>>>(rel_tab, rp, bias);

    // token embedding -> bf16
    gather_bf16_kernel<<<8192, 192, 0, stream>>>(tokens, embed, xb);

    for (int l = 0; l < 6; l++) {
        const bf16* wq_l = wqkv + (long)l * 2304 * 768;
        const bf16* wo_l = wo + (long)l * 768 * 768;
        const float* bq_l = bqkv + (long)l * 2304;
        const float* bo_l = bo + (long)l * 768;

        gemm_bf16_kernel<<<dim3(18, 64), 256, 0, stream>>>(xb, wq_l, bq_l, qkv, nullptr, vT, 2304, 768);
        attn_mfma_kernel<<<1024, 256, 0, stream>>>(qkv, vT, bias, ob);
        if (l < 5)
            gemm_bf16_kernel<<<dim3(6, 64), 256, 0, stream>>>(ob, wo_l, bo_l, xb, nullptr, nullptr, 768, 768);
        else
            gemm_bf16_kernel<<<dim3(6, 64), 256, 0, stream>>>(ob, wo_l, bo_l, nullptr, xf, nullptr, 768, 768);
    }

    out_kernel<<<32, 256, 0, stream>>>(xf, out);
}

// Round 5
// 998.001 us; speedup vs baseline: 1.1447x; 1.1447x over previous
//
#include <hip/hip_runtime.h>
#include <hip/hip_bf16.h>
#include <math.h>

constexpr int SEQ = 256;
constexpr int DIM = 768;
constexpr int NH  = 8;
constexpr int HD  = 96;

typedef __attribute__((ext_vector_type(8))) short short8;
typedef __attribute__((ext_vector_type(4))) float f32x4;
using bf16 = __hip_bfloat16;

#define ASYNC_COPY16(gptr, lptr) \
  __builtin_amdgcn_global_load_lds((const __attribute__((address_space(1))) void*)(gptr), \
                                   (__attribute__((address_space(3))) void*)(lptr), 16, 0, 0)

// ---------------------------------------------------------------------------
// f32 tiled GEMM (tiny positional-bias precompute only)
// ---------------------------------------------------------------------------
__global__ __launch_bounds__(256) void gemm_kernel(
    const float* __restrict__ A, int lda, long aoz,
    const float* __restrict__ W, int ldw, long woz,
    const float* __restrict__ bias,
    float* __restrict__ C, int ldc, long coz,
    int M, int N, int K, float scale)
{
    A += (long)blockIdx.z * aoz;
    W += (long)blockIdx.z * woz;
    C += (long)blockIdx.z * coz;

    __shared__ float As[16][68];
    __shared__ float Ws[16][68];

    const int bm = blockIdx.y * 64;
    const int bn = blockIdx.x * 64;
    const int tid = threadIdx.x;
    const int tx = tid & 15;
    const int ty = tid >> 4;

    float acc[4][4] = {};

    for (int k0 = 0; k0 < K; k0 += 16) {
#pragma unroll
        for (int i = 0; i < 4; i++) {
            int idx = tid + i * 256;
            int r = idx >> 4, c = idx & 15;
            As[c][r] = A[(long)(bm + r) * lda + (k0 + c)];
            Ws[c][r] = W[(long)(bn + r) * ldw + (k0 + c)];
        }
        __syncthreads();
#pragma unroll
        for (int kk = 0; kk < 16; kk++) {
            const float4 a = *(const float4*)&As[kk][ty * 4];
            const float4 w = *(const float4*)&Ws[kk][tx * 4];
            acc[0][0] += a.x * w.x; acc[0][1] += a.x * w.y; acc[0][2] += a.x * w.z; acc[0][3] += a.x * w.w;
            acc[1][0] += a.y * w.x; acc[1][1] += a.y * w.y; acc[1][2] += a.y * w.z; acc[1][3] += a.y * w.w;
            acc[2][0] += a.z * w.x; acc[2][1] += a.z * w.y; acc[2][2] += a.z * w.z; acc[2][3] += a.z * w.w;
            acc[3][0] += a.w * w.x; acc[3][1] += a.w * w.y; acc[3][2] += a.w * w.z; acc[3][3] += a.w * w.w;
        }
        __syncthreads();
    }

    const int n0 = bn + tx * 4;
    float4 bv = make_float4(0.f, 0.f, 0.f, 0.f);
    if (bias) bv = *(const float4*)&bias[n0];
#pragma unroll
    for (int i = 0; i < 4; i++) {
        const int m = bm + ty * 4 + i;
        float4 r;
        r.x = (acc[i][0] + bv.x) * scale;
        r.y = (acc[i][1] + bv.y) * scale;
        r.z = (acc[i][2] + bv.z) * scale;
        r.w = (acc[i][3] + bv.w) * scale;
        *(float4*)&C[(long)m * ldc + n0] = r;
    }
}

// ---------------------------------------------------------------------------
// LayerNorm of pos_emb rows
// ---------------------------------------------------------------------------
__global__ __launch_bounds__(256) void posln_kernel(
    const float* __restrict__ pe, const float* __restrict__ g,
    const float* __restrict__ bb, float* __restrict__ w)
{
    __shared__ float buf[256];
    const int i = blockIdx.x, tid = threadIdx.x;
    const float* row = pe + (long)i * DIM;
    float v0 = row[tid], v1 = row[tid + 256], v2 = row[tid + 512];

    buf[tid] = v0 + v1 + v2;
    __syncthreads();
    for (int off = 128; off > 0; off >>= 1) {
        if (tid < off) buf[tid] += buf[tid + off];
        __syncthreads();
    }
    const float mean = buf[0] * (1.f / 768.f);
    __syncthreads();

    const float d0 = v0 - mean, d1 = v1 - mean, d2 = v2 - mean;
    buf[tid] = d0 * d0 + d1 * d1 + d2 * d2;
    __syncthreads();
    for (int off = 128; off > 0; off >>= 1) {
        if (tid < off) buf[tid] += buf[tid + off];
        __syncthreads();
    }
    const float rstd = rsqrtf(buf[0] * (1.f / 768.f) + 1e-5f);

    float* wr = w + (long)i * DIM;
    wr[tid]       = d0 * rstd * g[tid]       + bb[tid];
    wr[tid + 256] = d1 * rstd * g[tid + 256] + bb[tid + 256];
    wr[tid + 512] = d2 * rstd * g[tid + 512] + bb[tid + 512];
}

// bias[h, ij] += table[rp[ij], h]
__global__ __launch_bounds__(256) void relbias_kernel(
    const float* __restrict__ table, const int* __restrict__ rp,
    float* __restrict__ bias)
{
    const int ij = blockIdx.x * 256 + threadIdx.x;
    const int bucket = rp[ij];
#pragma unroll
    for (int h = 0; h < NH; h++)
        bias[(long)h * SEQ * SEQ + ij] += table[bucket * NH + h];
}

// ---------------------------------------------------------------------------
// weight / bias conversion to bf16 (q-scale folded)
// ---------------------------------------------------------------------------
__global__ __launch_bounds__(256) void convert_qkv_kernel(
    const float* __restrict__ Wq, const float* __restrict__ Wk,
    const float* __restrict__ Wv, bf16* __restrict__ wqkv, float scale)
{
    const long idx = (long)blockIdx.x * 256 + threadIdx.x; // over 6*2304*768/4
    const long e = idx * 4;
    const int k = (int)(e % 768);
    const long nl = e / 768;
    const int n = (int)(nl % 2304);
    const int l = (int)(nl / 2304);

    const float* src;
    float sc = 1.f;
    if (n < 768)       { src = Wq + ((long)l * 768 + n) * 768; sc = scale; }
    else if (n < 1536) { src = Wk + ((long)l * 768 + (n - 768)) * 768; }
    else               { src = Wv + ((long)l * 768 + (n - 1536)) * 768; }

    const float4 v = *(const float4*)&src[k];
    bf16 tmp[4];
    tmp[0] = __float2bfloat16(v.x * sc);
    tmp[1] = __float2bfloat16(v.y * sc);
    tmp[2] = __float2bfloat16(v.z * sc);
    tmp[3] = __float2bfloat16(v.w * sc);
    *(uint2*)&wqkv[((long)l * 2304 + n) * 768 + k] = *(uint2*)tmp;
}

// woT[l][j][c] = bf16(Wo[l][c][j])  (LDS-tiled 32x32 transpose)
__global__ __launch_bounds__(256) void transpose_wo_kernel(
    const float* __restrict__ Wo, bf16* __restrict__ woT)
{
    __shared__ float t[32][33];
    const int l = blockIdx.z;
    const int c0 = blockIdx.x * 32, j0 = blockIdx.y * 32;
    const int tx = threadIdx.x & 31, ty = threadIdx.x >> 5;   // 32 x 8
    const float* src = Wo + (long)l * 768 * 768;
#pragma unroll
    for (int rr = 0; rr < 32; rr += 8)
        t[ty + rr][tx] = src[(long)(c0 + ty + rr) * 768 + j0 + tx];
    __syncthreads();
    bf16* dst = woT + (long)l * 768 * 768;
#pragma unroll
    for (int rr = 0; rr < 32; rr += 8)
        dst[(long)(j0 + ty + rr) * 768 + c0 + tx] = __float2bfloat16(t[tx][ty + rr]);
}

__global__ __launch_bounds__(256) void convert_bias_kernel(
    const float* __restrict__ bq, const float* __restrict__ bk,
    const float* __restrict__ bv, float* __restrict__ bqkv, float scale)
{
    const int idx = blockIdx.x * 256 + threadIdx.x; // over 6*2304
    const int n = idx % 2304;
    const int l = idx / 2304;
    float v;
    if (n < 768)       v = bq[l * 768 + n] * scale;
    else if (n < 1536) v = bk[l * 768 + (n - 768)];
    else               v = bv[l * 768 + (n - 1536)];
    bqkv[idx] = v;
}

// bf[l][n] = wqkv[l+1][n,:] . bo[l] + bqkv[l+1][n]   (l = 0..4)
__global__ __launch_bounds__(256) void fused_bias_kernel(
    const bf16* __restrict__ wqkv, const float* __restrict__ bo,
    const float* __restrict__ bqkv, float* __restrict__ bf_)
{
    const int l = blockIdx.y;                    // 0..4
    const int lane = threadIdx.x & 63, wave = threadIdx.x >> 6;
    const int nloc = wave * 8 + (lane >> 3);     // 0..31
    const int seg = lane & 7;                    // 0..7 (96 c each)
    const int n = blockIdx.x * 32 + nloc;
    const bf16* wrow = wqkv + ((long)(l + 1) * 2304 + n) * 768 + seg * 96;
    const float* bsrc = bo + (long)l * 768 + seg * 96;
    float s = 0.f;
    for (int c = 0; c < 96; c++) s += __bfloat162float(wrow[c]) * bsrc[c];
    s += __shfl_xor(s, 1);
    s += __shfl_xor(s, 2);
    s += __shfl_xor(s, 4);
    if (seg == 0) bf_[l * 2304 + n] = s + bqkv[(l + 1) * 2304 + n];
}

// x_bf[t,:] = bf16(embed[tokens[t],:])
__global__ __launch_bounds__(192) void gather_bf16_kernel(
    const int* __restrict__ tokens, const float* __restrict__ emb,
    bf16* __restrict__ x)
{
    const int t = blockIdx.x;
    const int tok = tokens[t];
    const float4 v = ((const float4*)(emb + (long)tok * DIM))[threadIdx.x];
    bf16 tmp[4];
    tmp[0] = __float2bfloat16(v.x);
    tmp[1] = __float2bfloat16(v.y);
    tmp[2] = __float2bfloat16(v.z);
    tmp[3] = __float2bfloat16(v.w);
    *(uint2*)&x[(long)t * DIM + threadIdx.x * 4] = *(uint2*)tmp;
}

// ---------------------------------------------------------------------------
// bf16 MFMA GEMM: C[m,n] = sum_k A[m,k]*B[n,k] + bias[n]
// 128x128 tile, BK=64, XOR-swizzled LDS. swz=1: XCD M-stripe (needs 64 m-tiles).
// vTout != null: n-tiles >= 1536 write packed-transposed vT[b][h*96+d][s]
// (uint2 of 4 consecutive s per lane — MFMA C-layout has m contiguous).
// ---------------------------------------------------------------------------
__global__ __launch_bounds__(256) void gemm_bf16_kernel(
    const bf16* __restrict__ A, const bf16* __restrict__ B,
    const float* __restrict__ bias,
    bf16* __restrict__ Cb, bf16* __restrict__ vTout,
    int N, int K, int swz)
{
    __shared__ bf16 As[128 * 64];   // 16 KB each
    __shared__ bf16 Bs[128 * 64];

    const int tid = threadIdx.x;
    const int lane = tid & 63, wave = tid >> 6;
    const int wm = wave & 1, wn = wave >> 1;

    int bmt, bnt;
    if (swz) {
        const int id = blockIdx.x + gridDim.x * blockIdx.y;
        const int xcd = id & 7, loc = id >> 3;
        bmt = xcd * 8 + (loc & 7);     // m-tile (gridDim.y==64)
        bnt = loc >> 3;                // n-tile
    } else {
        bmt = blockIdx.y;
        bnt = blockIdx.x;
    }
    const long bm = (long)bmt * 128, bn = (long)bnt * 128;

    const int col = lane & 15, quad = lane >> 4;

    f32x4 acc[4][4] = {};

    for (int k0 = 0; k0 < K; k0 += 64) {
        __syncthreads();
#pragma unroll
        for (int i = 0; i < 4; i++) {
            const int u = tid + i * 256;            // 0..1023
            const int r = u >> 3, c = u & 7;
            const int ca = c ^ (r & 7);             // swizzled k-chunk
            ASYNC_COPY16(A + (bm + r) * (long)K + k0 + ca * 8, &As[u * 8]);
            ASYNC_COPY16(B + (bn + r) * (long)K + k0 + ca * 8, &Bs[u * 8]);
        }
        __syncthreads();

#pragma unroll
        for (int ks = 0; ks < 2; ks++) {
            const int cc = ks * 4 + quad;           // content k-chunk
            short8 af[4], bfr[4];
#pragma unroll
            for (int t = 0; t < 4; t++) {
                const int ra = wm * 64 + t * 16 + col;
                const int rb = wn * 64 + t * 16 + col;
                af[t]  = *(const short8*)&As[ra * 64 + ((cc ^ (ra & 7)) * 8)];
                bfr[t] = *(const short8*)&Bs[rb * 64 + ((cc ^ (rb & 7)) * 8)];
            }
#pragma unroll
            for (int tm = 0; tm < 4; tm++)
#pragma unroll
                for (int tn = 0; tn < 4; tn++)
                    acc[tm][tn] = __builtin_amdgcn_mfma_f32_16x16x32_bf16(af[tm], bfr[tn], acc[tm][tn], 0, 0, 0);
        }
    }

    const bool toVT = (vTout != nullptr) && (bn >= 1536);   // block-uniform

#pragma unroll
    for (int tn = 0; tn < 4; tn++) {
        const long n = bn + wn * 64 + tn * 16 + col;
        const float bvv = bias ? bias[n] : 0.f;
#pragma unroll
        for (int tm = 0; tm < 4; tm++) {
            const long m0 = bm + wm * 64 + tm * 16 + quad * 4;
            if (toVT) {
                // vT[b][h*96+d][s]: packed 4 consecutive s (= m) per lane
                bf16 t4[4];
#pragma unroll
                for (int r = 0; r < 4; r++)
                    t4[r] = __float2bfloat16(acc[tm][tn][r] + bvv);
                *(uint2*)&vTout[((m0 >> 8) * 768 + (n - 1536)) * 256 + (m0 & 255)] = *(uint2*)t4;
            } else {
#pragma unroll
                for (int r = 0; r < 4; r++)
                    Cb[(m0 + r) * N + n] = __float2bfloat16(acc[tm][tn][r] + bvv);
            }
        }
    }
}

// ---------------------------------------------------------------------------
// MFMA attention, zero-staging: Q in regs, K direct from qkv, V direct from
// vT (pre-transposed). LDS = Ps only. Block per (it, h, b), b innermost;
// launch with grid=256 to restrict to it=0 (final layer).
// ---------------------------------------------------------------------------
__global__ __launch_bounds__(256) void attn_mfma_kernel(
    const bf16* __restrict__ qkv, const bf16* __restrict__ vT,
    const float* __restrict__ bias, bf16* __restrict__ o)
{
    constexpr int PS = 264;  // Ps stride (bf16)
    __shared__ bf16 Ps[64 * PS];   // 33.8 KB -> 4 blocks/CU

    const int blk = blockIdx.x;          // (it*8 + h)*32 + b
    const int b  = blk & 31;
    const int h  = (blk >> 5) & 7;
    const int it = blk >> 8;
    const int i0 = it * 64;
    const int tid = threadIdx.x, lane = tid & 63, wave = tid >> 6;
    const int col = lane & 15, quad = lane >> 4;
    const long rowbase = (long)b * SEQ;

    // Q fragments (A-operand layout): row i0+wave*16+col, k = ks*32+quad*8
    short8 aq[3];
    {
        const bf16* qrow = qkv + (rowbase + i0 + wave * 16 + col) * 2304 + h * 96;
#pragma unroll
        for (int ks = 0; ks < 3; ks++)
            aq[ks] = *(const short8*)&qrow[ks * 32 + quad * 8];
    }

    // ---- scores: K fragments direct from global (16 rows x 64B, coalesced) ----
    f32x4 accS[16];
#pragma unroll
    for (int jt = 0; jt < 16; jt++) {
        const bf16* krow = qkv + (rowbase + jt * 16 + col) * 2304 + 768 + h * 96;
        f32x4 a = {};
#pragma unroll
        for (int ks = 0; ks < 3; ks++) {
            const short8 bk_ = *(const short8*)&krow[ks * 32 + quad * 8];
            a = __builtin_amdgcn_mfma_f32_16x16x32_bf16(aq[ks], bk_, a, 0, 0, 0);
        }
        accS[jt] = a;
    }

    // ---- bias + softmax (rows i0+wave*16+quad*4+r, col jt*16+col) ----
    const float* bb = bias + ((long)h * SEQ + i0 + wave * 16 + quad * 4) * SEQ;
#pragma unroll
    for (int jt = 0; jt < 16; jt++)
#pragma unroll
        for (int r = 0; r < 4; r++)
            accS[jt][r] += bb[r * SEQ + jt * 16 + col];

#pragma unroll
    for (int r = 0; r < 4; r++) {
        float m = accS[0][r];
#pragma unroll
        for (int jt = 1; jt < 16; jt++) m = fmaxf(m, accS[jt][r]);
        for (int d = 1; d < 16; d <<= 1) m = fmaxf(m, __shfl_xor(m, d));
        float s = 0.f;
#pragma unroll
        for (int jt = 0; jt < 16; jt++) {
            const float e = __expf(accS[jt][r] - m);
            accS[jt][r] = e;
            s += e;
        }
        for (int d = 1; d < 16; d <<= 1) s += __shfl_xor(s, d);
        const float inv = 1.f / s;
        const int prow = wave * 16 + quad * 4 + r;
#pragma unroll
        for (int jt = 0; jt < 16; jt++)
            Ps[prow * PS + jt * 16 + col] = __float2bfloat16(accS[jt][r] * inv);
    }
    // no barrier: each wave reads only the 16 Ps rows it wrote (lgkmcnt order)

    // ---- O = P.V : V fragments direct from vT (16 rows x 64B, coalesced) ----
    f32x4 accO[6] = {};
    const bf16* vbase = vT + ((long)b * 768 + h * 96) * 256;
    for (int kc = 0; kc < 8; kc++) {
        const short8 ap = *(const short8*)&Ps[(wave * 16 + col) * PS + kc * 32 + quad * 8];
#pragma unroll
        for (int nt = 0; nt < 6; nt++) {
            const short8 bv_ = *(const short8*)&vbase[(nt * 16 + col) * 256 + kc * 32 + quad * 8];
            accO[nt] = __builtin_amdgcn_mfma_f32_16x16x32_bf16(ap, bv_, accO[nt], 0, 0, 0);
        }
    }

#pragma unroll
    for (int nt = 0; nt < 6; nt++)
#pragma unroll
        for (int r = 0; r < 4; r++) {
            const long m = rowbase + i0 + wave * 16 + quad * 4 + r;
            o[m * DIM + h * 96 + nt * 16 + col] = __float2bfloat16(accO[nt][r]);
        }
}

// out[b,n] = ob[b*256,:] . Wo5[n,:] + bo5[n]   (f32)
__global__ __launch_bounds__(256) void final_out_kernel(
    const bf16* __restrict__ ob, const float* __restrict__ Wo5,
    const float* __restrict__ bo5, float* __restrict__ out)
{
    __shared__ float os[768];
    const int b = blockIdx.x, tid = threadIdx.x;
    const bf16* orow = ob + (long)b * 256 * 768;
    for (int i = tid; i < 768; i += 256) os[i] = __bfloat162float(orow[i]);
    __syncthreads();
#pragma unroll
    for (int nn = 0; nn < 3; nn++) {
        const int n = tid + nn * 256;
        const float* wrow = Wo5 + (long)n * 768;
        float s = bo5[n];
        for (int k = 0; k < 768; k += 4) {
            const float4 w = *(const float4*)&wrow[k];
            s += os[k] * w.x + os[k + 1] * w.y + os[k + 2] * w.z + os[k + 3] * w.w;
        }
        out[b * 768 + n] = s;
    }
}

extern "C" void kernel_launch(void* const* d_in, const int* in_sizes, int n_in,
                              void* d_out, int out_size, void* d_ws, size_t ws_size,
                              hipStream_t stream)
{
    const int*   tokens   = (const int*)d_in[0];
    const float* embed    = (const float*)d_in[1];
    const float* pos_emb  = (const float*)d_in[2];
    const float* pos_q_w  = (const float*)d_in[3];
    const float* pos_q_b  = (const float*)d_in[4];
    const float* pos_k_w  = (const float*)d_in[5];
    const float* pos_k_b  = (const float*)d_in[6];
    const float* pos_ln_g = (const float*)d_in[7];
    const float* pos_ln_b = (const float*)d_in[8];
    const float* rel_tab  = (const float*)d_in[9];
    const int*   rp       = (const int*)d_in[10];
    const float* Wq = (const float*)d_in[11];
    const float* bq = (const float*)d_in[12];
    const float* Wk = (const float*)d_in[13];
    const float* bk = (const float*)d_in[14];
    const float* Wv = (const float*)d_in[15];
    const float* bv = (const float*)d_in[16];
    const float* Wo = (const float*)d_in[17];
    const float* bo = (const float*)d_in[18];
    float* out = (float*)d_out;

    char* p = (char*)d_ws;
    auto alloc = [&](size_t bytes) -> char* {
        char* r = p;
        p += (bytes + 255) & ~(size_t)255;
        return r;
    };
    const long NT = 32L * SEQ;  // 8192

    float* bias  = (float*)alloc(8L * SEQ * SEQ * 4);
    float* wln   = (float*)alloc((long)SEQ * DIM * 4);
    float* pq    = (float*)alloc((long)SEQ * DIM * 4);
    float* pk    = (float*)alloc((long)SEQ * DIM * 4);
    bf16*  xb    = (bf16*) alloc(NT * DIM * 2);
    bf16*  qkv   = (bf16*) alloc(NT * 2304 * 2);
    bf16*  vT    = (bf16*) alloc(NT * DIM * 2);   // [32][768][256]
    bf16*  ob    = (bf16*) alloc(NT * DIM * 2);
    bf16*  wqkv  = (bf16*) alloc(6L * 2304 * 768 * 2);
    bf16*  woT   = (bf16*) alloc(6L * 768 * 768 * 2);
    bf16*  wf    = (bf16*) alloc(5L * 2304 * 768 * 2);
    float* bqkv  = (float*)alloc(6L * 2304 * 4);
    float* bfus  = (float*)alloc(5L * 2304 * 4);

    const float SCALE = 0.07216878364870322f;   // (HD*2)^-0.5

    // ---- weight conversion / fusion ----
    convert_qkv_kernel<<<(6L * 2304 * 768 / 4 + 255) / 256, 256, 0, stream>>>(Wq, Wk, Wv, wqkv, SCALE);
    transpose_wo_kernel<<<dim3(24, 24, 6), 256, 0, stream>>>(Wo, woT);
    convert_bias_kernel<<<(6 * 2304 + 255) / 256, 256, 0, stream>>>(bq, bk, bv, bqkv, SCALE);
    // Wf_l = Wqkv_{l+1} . Wo_l   (MFMA, f32 accumulate, bf16 out)
    for (int l = 0; l < 5; l++)
        gemm_bf16_kernel<<<dim3(6, 18), 256, 0, stream>>>(
            wqkv + (long)(l + 1) * 2304 * 768, woT + (long)l * 768 * 768,
            nullptr, wf + (long)l * 2304 * 768, nullptr, 768, 768, 0);
    fused_bias_kernel<<<dim3(72, 5), 256, 0, stream>>>(wqkv, bo, bqkv, bfus);

    // ---- positional bias precompute (f32) ----
    posln_kernel<<<256, 256, 0, stream>>>(pos_emb, pos_ln_g, pos_ln_b, wln);
    gemm_kernel<<<dim3(12, 4, 1), 256, 0, stream>>>(wln, DIM, 0, pos_q_w, DIM, 0, pos_q_b,
                                                    pq, DIM, 0, SEQ, DIM, DIM, SCALE);
    gemm_kernel<<<dim3(12, 4, 1), 256, 0, stream>>>(wln, DIM, 0, pos_k_w, DIM, 0, pos_k_b,
                                                    pk, DIM, 0, SEQ, DIM, DIM, 1.0f);
    gemm_kernel<<<dim3(4, 4, NH), 256, 0, stream>>>(pq, DIM, HD, pk, DIM, HD, nullptr,
                                                    bias, SEQ, (long)SEQ * SEQ, SEQ, SEQ, HD, 1.0f);
    relbias_kernel<<<256, 256, 0, stream>>>(rel_tab, rp, bias);

    // ---- token embedding -> bf16 ----
    gather_bf16_kernel<<<8192, 192, 0, stream>>>(tokens, embed, xb);

    // ---- layer pipeline: qkv0, then {attn, fused-gemm} x5, attn, final ----
    gemm_bf16_kernel<<<dim3(18, 64), 256, 0, stream>>>(xb, wqkv, bqkv, qkv, vT, 2304, 768, 1);
    for (int l = 0; l < 5; l++) {
        attn_mfma_kernel<<<1024, 256, 0, stream>>>(qkv, vT, bias, ob);
        gemm_bf16_kernel<<<dim3(18, 64), 256, 0, stream>>>(
            ob, wf + (long)l * 2304 * 768, bfus + (long)l * 2304, qkv, vT, 2304, 768, 1);
    }
    attn_mfma_kernel<<<256, 256, 0, stream>>>(qkv, vT, bias, ob);   // it=0 only
    final_out_kernel<<<32, 256, 0, stream>>>(ob, Wo + 5L * 768 * 768, bo + 5L * 768, out);
}

// Round 6
// 949.102 us; speedup vs baseline: 1.2036x; 1.0515x over previous
//
#include <hip/hip_runtime.h>
#include <hip/hip_bf16.h>
#include <math.h>

constexpr int SEQ = 256;
constexpr int DIM = 768;
constexpr int NH  = 8;
constexpr int HD  = 96;

typedef __attribute__((ext_vector_type(8))) short short8;
typedef __attribute__((ext_vector_type(4))) float f32x4;
using bf16 = __hip_bfloat16;

#define ASYNC_COPY16(gptr, lptr) \
  __builtin_amdgcn_global_load_lds((const __attribute__((address_space(1))) void*)(gptr), \
                                   (__attribute__((address_space(3))) void*)(lptr), 16, 0, 0)

// ---------------------------------------------------------------------------
// f32 tiled GEMM (tiny positional-bias precompute only)
// ---------------------------------------------------------------------------
__global__ __launch_bounds__(256) void gemm_kernel(
    const float* __restrict__ A, int lda, long aoz,
    const float* __restrict__ W, int ldw, long woz,
    const float* __restrict__ bias,
    float* __restrict__ C, int ldc, long coz,
    int M, int N, int K, float scale)
{
    A += (long)blockIdx.z * aoz;
    W += (long)blockIdx.z * woz;
    C += (long)blockIdx.z * coz;

    __shared__ float As[16][68];
    __shared__ float Ws[16][68];

    const int bm = blockIdx.y * 64;
    const int bn = blockIdx.x * 64;
    const int tid = threadIdx.x;
    const int tx = tid & 15;
    const int ty = tid >> 4;

    float acc[4][4] = {};

    for (int k0 = 0; k0 < K; k0 += 16) {
#pragma unroll
        for (int i = 0; i < 4; i++) {
            int idx = tid + i * 256;
            int r = idx >> 4, c = idx & 15;
            As[c][r] = A[(long)(bm + r) * lda + (k0 + c)];
            Ws[c][r] = W[(long)(bn + r) * ldw + (k0 + c)];
        }
        __syncthreads();
#pragma unroll
        for (int kk = 0; kk < 16; kk++) {
            const float4 a = *(const float4*)&As[kk][ty * 4];
            const float4 w = *(const float4*)&Ws[kk][tx * 4];
            acc[0][0] += a.x * w.x; acc[0][1] += a.x * w.y; acc[0][2] += a.x * w.z; acc[0][3] += a.x * w.w;
            acc[1][0] += a.y * w.x; acc[1][1] += a.y * w.y; acc[1][2] += a.y * w.z; acc[1][3] += a.y * w.w;
            acc[2][0] += a.z * w.x; acc[2][1] += a.z * w.y; acc[2][2] += a.z * w.z; acc[2][3] += a.z * w.w;
            acc[3][0] += a.w * w.x; acc[3][1] += a.w * w.y; acc[3][2] += a.w * w.z; acc[3][3] += a.w * w.w;
        }
        __syncthreads();
    }

    const int n0 = bn + tx * 4;
    float4 bv = make_float4(0.f, 0.f, 0.f, 0.f);
    if (bias) bv = *(const float4*)&bias[n0];
#pragma unroll
    for (int i = 0; i < 4; i++) {
        const int m = bm + ty * 4 + i;
        float4 r;
        r.x = (acc[i][0] + bv.x) * scale;
        r.y = (acc[i][1] + bv.y) * scale;
        r.z = (acc[i][2] + bv.z) * scale;
        r.w = (acc[i][3] + bv.w) * scale;
        *(float4*)&C[(long)m * ldc + n0] = r;
    }
}

// ---------------------------------------------------------------------------
// LayerNorm of pos_emb rows
// ---------------------------------------------------------------------------
__global__ __launch_bounds__(256) void posln_kernel(
    const float* __restrict__ pe, const float* __restrict__ g,
    const float* __restrict__ bb, float* __restrict__ w)
{
    __shared__ float buf[256];
    const int i = blockIdx.x, tid = threadIdx.x;
    const float* row = pe + (long)i * DIM;
    float v0 = row[tid], v1 = row[tid + 256], v2 = row[tid + 512];

    buf[tid] = v0 + v1 + v2;
    __syncthreads();
    for (int off = 128; off > 0; off >>= 1) {
        if (tid < off) buf[tid] += buf[tid + off];
        __syncthreads();
    }
    const float mean = buf[0] * (1.f / 768.f);
    __syncthreads();

    const float d0 = v0 - mean, d1 = v1 - mean, d2 = v2 - mean;
    buf[tid] = d0 * d0 + d1 * d1 + d2 * d2;
    __syncthreads();
    for (int off = 128; off > 0; off >>= 1) {
        if (tid < off) buf[tid] += buf[tid + off];
        __syncthreads();
    }
    const float rstd = rsqrtf(buf[0] * (1.f / 768.f) + 1e-5f);

    float* wr = w + (long)i * DIM;
    wr[tid]       = d0 * rstd * g[tid]       + bb[tid];
    wr[tid + 256] = d1 * rstd * g[tid + 256] + bb[tid + 256];
    wr[tid + 512] = d2 * rstd * g[tid + 512] + bb[tid + 512];
}

// bias[h, ij] += table[rp[ij], h]
__global__ __launch_bounds__(256) void relbias_kernel(
    const float* __restrict__ table, const int* __restrict__ rp,
    float* __restrict__ bias)
{
    const int ij = blockIdx.x * 256 + threadIdx.x;
    const int bucket = rp[ij];
#pragma unroll
    for (int h = 0; h < NH; h++)
        bias[(long)h * SEQ * SEQ + ij] += table[bucket * NH + h];
}

// ---------------------------------------------------------------------------
// weight / bias conversion to bf16 (q-scale folded)
// ---------------------------------------------------------------------------
__global__ __launch_bounds__(256) void convert_qkv_kernel(
    const float* __restrict__ Wq, const float* __restrict__ Wk,
    const float* __restrict__ Wv, bf16* __restrict__ wqkv, float scale)
{
    const long idx = (long)blockIdx.x * 256 + threadIdx.x; // over 6*2304*768/4
    const long e = idx * 4;
    const int k = (int)(e % 768);
    const long nl = e / 768;
    const int n = (int)(nl % 2304);
    const int l = (int)(nl / 2304);

    const float* src;
    float sc = 1.f;
    if (n < 768)       { src = Wq + ((long)l * 768 + n) * 768; sc = scale; }
    else if (n < 1536) { src = Wk + ((long)l * 768 + (n - 768)) * 768; }
    else               { src = Wv + ((long)l * 768 + (n - 1536)) * 768; }

    const float4 v = *(const float4*)&src[k];
    bf16 tmp[4];
    tmp[0] = __float2bfloat16(v.x * sc);
    tmp[1] = __float2bfloat16(v.y * sc);
    tmp[2] = __float2bfloat16(v.z * sc);
    tmp[3] = __float2bfloat16(v.w * sc);
    *(uint2*)&wqkv[((long)l * 2304 + n) * 768 + k] = *(uint2*)tmp;
}

// woT[l][j][c] = bf16(Wo[l][c][j])  (LDS-tiled 32x32 transpose)
__global__ __launch_bounds__(256) void transpose_wo_kernel(
    const float* __restrict__ Wo, bf16* __restrict__ woT)
{
    __shared__ float t[32][33];
    const int l = blockIdx.z;
    const int c0 = blockIdx.x * 32, j0 = blockIdx.y * 32;
    const int tx = threadIdx.x & 31, ty = threadIdx.x >> 5;   // 32 x 8
    const float* src = Wo + (long)l * 768 * 768;
#pragma unroll
    for (int rr = 0; rr < 32; rr += 8)
        t[ty + rr][tx] = src[(long)(c0 + ty + rr) * 768 + j0 + tx];
    __syncthreads();
    bf16* dst = woT + (long)l * 768 * 768;
#pragma unroll
    for (int rr = 0; rr < 32; rr += 8)
        dst[(long)(j0 + ty + rr) * 768 + c0 + tx] = __float2bfloat16(t[tx][ty + rr]);
}

__global__ __launch_bounds__(256) void convert_bias_kernel(
    const float* __restrict__ bq, const float* __restrict__ bk,
    const float* __restrict__ bv, float* __restrict__ bqkv, float scale)
{
    const int idx = blockIdx.x * 256 + threadIdx.x; // over 6*2304
    const int n = idx % 2304;
    const int l = idx / 2304;
    float v;
    if (n < 768)       v = bq[l * 768 + n] * scale;
    else if (n < 1536) v = bk[l * 768 + (n - 768)];
    else               v = bv[l * 768 + (n - 1536)];
    bqkv[idx] = v;
}

// bf[l][n] = wqkv[l+1][n,:] . bo[l] + bqkv[l+1][n]   (l = 0..4)
__global__ __launch_bounds__(256) void fused_bias_kernel(
    const bf16* __restrict__ wqkv, const float* __restrict__ bo,
    const float* __restrict__ bqkv, float* __restrict__ bf_)
{
    const int l = blockIdx.y;                    // 0..4
    const int lane = threadIdx.x & 63, wave = threadIdx.x >> 6;
    const int nloc = wave * 8 + (lane >> 3);     // 0..31
    const int seg = lane & 7;                    // 0..7 (96 c each)
    const int n = blockIdx.x * 32 + nloc;
    const bf16* wrow = wqkv + ((long)(l + 1) * 2304 + n) * 768 + seg * 96;
    const float* bsrc = bo + (long)l * 768 + seg * 96;
    float s = 0.f;
    for (int c = 0; c < 96; c++) s += __bfloat162float(wrow[c]) * bsrc[c];
    s += __shfl_xor(s, 1);
    s += __shfl_xor(s, 2);
    s += __shfl_xor(s, 4);
    if (seg == 0) bf_[l * 2304 + n] = s + bqkv[(l + 1) * 2304 + n];
}

// x_bf[t,:] = bf16(embed[tokens[t],:])
__global__ __launch_bounds__(192) void gather_bf16_kernel(
    const int* __restrict__ tokens, const float* __restrict__ emb,
    bf16* __restrict__ x)
{
    const int t = blockIdx.x;
    const int tok = tokens[t];
    const float4 v = ((const float4*)(emb + (long)tok * DIM))[threadIdx.x];
    bf16 tmp[4];
    tmp[0] = __float2bfloat16(v.x);
    tmp[1] = __float2bfloat16(v.y);
    tmp[2] = __float2bfloat16(v.z);
    tmp[3] = __float2bfloat16(v.w);
    *(uint2*)&x[(long)t * DIM + threadIdx.x * 4] = *(uint2*)tmp;
}

// ---------------------------------------------------------------------------
// bf16 MFMA GEMM: C[m,n] = sum_k A[m,k]*B[n,k] + bias[n]
// 128x128 tile, BK=64, XOR-swizzled LDS. swz=1: XCD M-stripe (needs 64 m-tiles).
// blockIdx.z batching via az/bz/cz element strides.
// vTout != null: n-tiles >= 1536 write vT[b][h*96+d][s] via a wave-local
// LDS-bounce transpose (coalesced 128B global segments).
// ---------------------------------------------------------------------------
__global__ __launch_bounds__(256) void gemm_bf16_kernel(
    const bf16* __restrict__ A, const bf16* __restrict__ B,
    const float* __restrict__ bias,
    bf16* __restrict__ Cb, bf16* __restrict__ vTout,
    int N, int K, int swz, long az, long bz, long cz)
{
    __shared__ bf16 As[128 * 64];   // 16 KB each
    __shared__ bf16 Bs[128 * 64];

    A += (long)blockIdx.z * az;
    B += (long)blockIdx.z * bz;
    if (Cb) Cb += (long)blockIdx.z * cz;

    const int tid = threadIdx.x;
    const int lane = tid & 63, wave = tid >> 6;
    const int wm = wave & 1, wn = wave >> 1;

    int bmt, bnt;
    if (swz) {
        const int id = blockIdx.x + gridDim.x * blockIdx.y;
        const int xcd = id & 7, loc = id >> 3;
        bmt = xcd * 8 + (loc & 7);     // m-tile (gridDim.y==64)
        bnt = loc >> 3;                // n-tile
    } else {
        bmt = blockIdx.y;
        bnt = blockIdx.x;
    }
    const long bm = (long)bmt * 128, bn = (long)bnt * 128;

    const int col = lane & 15, quad = lane >> 4;

    f32x4 acc[4][4] = {};

    for (int k0 = 0; k0 < K; k0 += 64) {
        __syncthreads();
#pragma unroll
        for (int i = 0; i < 4; i++) {
            const int u = tid + i * 256;            // 0..1023
            const int r = u >> 3, c = u & 7;
            const int ca = c ^ (r & 7);             // swizzled k-chunk
            ASYNC_COPY16(A + (bm + r) * (long)K + k0 + ca * 8, &As[u * 8]);
            ASYNC_COPY16(B + (bn + r) * (long)K + k0 + ca * 8, &Bs[u * 8]);
        }
        __syncthreads();

#pragma unroll
        for (int ks = 0; ks < 2; ks++) {
            const int cc = ks * 4 + quad;           // content k-chunk
            short8 af[4], bfr[4];
#pragma unroll
            for (int t = 0; t < 4; t++) {
                const int ra = wm * 64 + t * 16 + col;
                const int rb = wn * 64 + t * 16 + col;
                af[t]  = *(const short8*)&As[ra * 64 + ((cc ^ (ra & 7)) * 8)];
                bfr[t] = *(const short8*)&Bs[rb * 64 + ((cc ^ (rb & 7)) * 8)];
            }
#pragma unroll
            for (int tm = 0; tm < 4; tm++)
#pragma unroll
                for (int tn = 0; tn < 4; tn++)
                    acc[tm][tn] = __builtin_amdgcn_mfma_f32_16x16x32_bf16(af[tm], bfr[tn], acc[tm][tn], 0, 0, 0);
        }
    }

    const bool toVT = (vTout != nullptr) && (bn >= 1536);   // block-uniform

    if (toVT) {
        // -------- wave-local 64x64 transpose through LDS, coalesced write ----
        __syncthreads();   // all waves done reading As/Bs
        bf16* tb = (wave < 2 ? As : Bs) + (wave & 1) * 4096;  // 8 KB / wave

        // store C fragments (bias added) at XOR-swizzled 8B units [nl][mc^nl]
#pragma unroll
        for (int tn = 0; tn < 4; tn++) {
            const int nl = tn * 16 + col;
            const float bvv = bias[bn + wn * 64 + nl];
#pragma unroll
            for (int tm = 0; tm < 4; tm++) {
                const int mc = tm * 4 + quad;       // m-chunk (4 bf16)
                bf16 t4[4];
#pragma unroll
                for (int r = 0; r < 4; r++)
                    t4[r] = __float2bfloat16(acc[tm][tn][r] + bvv);
                *(uint2*)&tb[(nl * 16 + (mc ^ (nl & 15))) * 4] = *(uint2*)t4;
            }
        }
        // read back transposed: lane -> (nl = it*4+quad, mc = col)
        const int b_  = (int)((bm + wm * 64) >> 8);
        const int s0  = (int)((bm + wm * 64) & 255);
        const long nb = bn + wn * 64 - 1536;        // h*96+d base
#pragma unroll
        for (int it2 = 0; it2 < 16; it2++) {
            const int nl = it2 * 4 + quad;
            const uint2 v = *(const uint2*)&tb[(nl * 16 + (col ^ (nl & 15))) * 4];
            *(uint2*)&vTout[((long)b_ * 768 + nb + nl) * 256 + s0 + col * 4] = v;
        }
    } else {
#pragma unroll
        for (int tn = 0; tn < 4; tn++) {
            const long n = bn + wn * 64 + tn * 16 + col;
            const float bvv = bias ? bias[n] : 0.f;
#pragma unroll
            for (int tm = 0; tm < 4; tm++) {
                const long m0 = bm + wm * 64 + tm * 16 + quad * 4;
#pragma unroll
                for (int r = 0; r < 4; r++)
                    Cb[(m0 + r) * N + n] = __float2bfloat16(acc[tm][tn][r] + bvv);
            }
        }
    }
}

// ---------------------------------------------------------------------------
// MFMA attention, zero-staging: Q in regs, K direct from qkv, V direct from
// vT (pre-transposed). LDS = Ps only. Block per (it, h, b), b innermost;
// launch with grid=256 to restrict to it=0 (final layer).
// ---------------------------------------------------------------------------
__global__ __launch_bounds__(256) void attn_mfma_kernel(
    const bf16* __restrict__ qkv, const bf16* __restrict__ vT,
    const float* __restrict__ bias, bf16* __restrict__ o)
{
    constexpr int PS = 264;  // Ps stride (bf16)
    __shared__ bf16 Ps[64 * PS];   // 33.8 KB -> 4 blocks/CU

    const int blk = blockIdx.x;          // (it*8 + h)*32 + b
    const int b  = blk & 31;
    const int h  = (blk >> 5) & 7;
    const int it = blk >> 8;
    const int i0 = it * 64;
    const int tid = threadIdx.x, lane = tid & 63, wave = tid >> 6;
    const int col = lane & 15, quad = lane >> 4;
    const long rowbase = (long)b * SEQ;

    // Q fragments (A-operand layout): row i0+wave*16+col, k = ks*32+quad*8
    short8 aq[3];
    {
        const bf16* qrow = qkv + (rowbase + i0 + wave * 16 + col) * 2304 + h * 96;
#pragma unroll
        for (int ks = 0; ks < 3; ks++)
            aq[ks] = *(const short8*)&qrow[ks * 32 + quad * 8];
    }

    // ---- scores: K fragments direct from global (16 rows x 64B, coalesced) ----
    f32x4 accS[16];
#pragma unroll
    for (int jt = 0; jt < 16; jt++) {
        const bf16* krow = qkv + (rowbase + jt * 16 + col) * 2304 + 768 + h * 96;
        f32x4 a = {};
#pragma unroll
        for (int ks = 0; ks < 3; ks++) {
            const short8 bk_ = *(const short8*)&krow[ks * 32 + quad * 8];
            a = __builtin_amdgcn_mfma_f32_16x16x32_bf16(aq[ks], bk_, a, 0, 0, 0);
        }
        accS[jt] = a;
    }

    // ---- bias + softmax (rows i0+wave*16+quad*4+r, col jt*16+col) ----
    const float* bb = bias + ((long)h * SEQ + i0 + wave * 16 + quad * 4) * SEQ;
#pragma unroll
    for (int jt = 0; jt < 16; jt++)
#pragma unroll
        for (int r = 0; r < 4; r++)
            accS[jt][r] += bb[r * SEQ + jt * 16 + col];

#pragma unroll
    for (int r = 0; r < 4; r++) {
        float m = accS[0][r];
#pragma unroll
        for (int jt = 1; jt < 16; jt++) m = fmaxf(m, accS[jt][r]);
        for (int d = 1; d < 16; d <<= 1) m = fmaxf(m, __shfl_xor(m, d));
        float s = 0.f;
#pragma unroll
        for (int jt = 0; jt < 16; jt++) {
            const float e = __expf(accS[jt][r] - m);
            accS[jt][r] = e;
            s += e;
        }
        for (int d = 1; d < 16; d <<= 1) s += __shfl_xor(s, d);
        const float inv = 1.f / s;
        const int prow = wave * 16 + quad * 4 + r;
#pragma unroll
        for (int jt = 0; jt < 16; jt++)
            Ps[prow * PS + jt * 16 + col] = __float2bfloat16(accS[jt][r] * inv);
    }
    // no barrier: each wave reads only the 16 Ps rows it wrote (lgkmcnt order)

    // ---- O = P.V : V fragments direct from vT (16 rows x 64B, coalesced) ----
    f32x4 accO[6] = {};
    const bf16* vbase = vT + ((long)b * 768 + h * 96) * 256;
    for (int kc = 0; kc < 8; kc++) {
        const short8 ap = *(const short8*)&Ps[(wave * 16 + col) * PS + kc * 32 + quad * 8];
#pragma unroll
        for (int nt = 0; nt < 6; nt++) {
            const short8 bv_ = *(const short8*)&vbase[(nt * 16 + col) * 256 + kc * 32 + quad * 8];
            accO[nt] = __builtin_amdgcn_mfma_f32_16x16x32_bf16(ap, bv_, accO[nt], 0, 0, 0);
        }
    }

#pragma unroll
    for (int nt = 0; nt < 6; nt++)
#pragma unroll
        for (int r = 0; r < 4; r++) {
            const long m = rowbase + i0 + wave * 16 + quad * 4 + r;
            o[m * DIM + h * 96 + nt * 16 + col] = __float2bfloat16(accO[nt][r]);
        }
}

// out[b, ng*32 + tid>>3] = ob[b*256,:] . Wo5[n,:] + bo5[n]
// grid (24, 32): 768 blocks, 8 lanes per dot product.
__global__ __launch_bounds__(256) void final_out_kernel(
    const bf16* __restrict__ ob, const float* __restrict__ Wo5,
    const float* __restrict__ bo5, float* __restrict__ out)
{
    __shared__ float os[768];
    const int b = blockIdx.y, ng = blockIdx.x, tid = threadIdx.x;
    const bf16* orow = ob + (long)b * 256 * 768;
    for (int i = tid; i < 768; i += 256) os[i] = __bfloat162float(orow[i]);
    __syncthreads();

    const int n = ng * 32 + (tid >> 3);
    const int seg = tid & 7;
    const float* wrow = Wo5 + (long)n * 768 + seg * 96;
    const float* xs = &os[seg * 96];
    float s = 0.f;
#pragma unroll
    for (int k = 0; k < 96; k += 4) {
        const float4 w = *(const float4*)&wrow[k];
        s += xs[k] * w.x + xs[k + 1] * w.y + xs[k + 2] * w.z + xs[k + 3] * w.w;
    }
    s += __shfl_xor(s, 1);
    s += __shfl_xor(s, 2);
    s += __shfl_xor(s, 4);
    if (seg == 0) out[b * 768 + n] = s + bo5[n];
}

extern "C" void kernel_launch(void* const* d_in, const int* in_sizes, int n_in,
                              void* d_out, int out_size, void* d_ws, size_t ws_size,
                              hipStream_t stream)
{
    const int*   tokens   = (const int*)d_in[0];
    const float* embed    = (const float*)d_in[1];
    const float* pos_emb  = (const float*)d_in[2];
    const float* pos_q_w  = (const float*)d_in[3];
    const float* pos_q_b  = (const float*)d_in[4];
    const float* pos_k_w  = (const float*)d_in[5];
    const float* pos_k_b  = (const float*)d_in[6];
    const float* pos_ln_g = (const float*)d_in[7];
    const float* pos_ln_b = (const float*)d_in[8];
    const float* rel_tab  = (const float*)d_in[9];
    const int*   rp       = (const int*)d_in[10];
    const float* Wq = (const float*)d_in[11];
    const float* bq = (const float*)d_in[12];
    const float* Wk = (const float*)d_in[13];
    const float* bk = (const float*)d_in[14];
    const float* Wv = (const float*)d_in[15];
    const float* bv = (const float*)d_in[16];
    const float* Wo = (const float*)d_in[17];
    const float* bo = (const float*)d_in[18];
    float* out = (float*)d_out;

    char* p = (char*)d_ws;
    auto alloc = [&](size_t bytes) -> char* {
        char* r = p;
        p += (bytes + 255) & ~(size_t)255;
        return r;
    };
    const long NT = 32L * SEQ;  // 8192

    float* bias  = (float*)alloc(8L * SEQ * SEQ * 4);
    float* wln   = (float*)alloc((long)SEQ * DIM * 4);
    float* pq    = (float*)alloc((long)SEQ * DIM * 4);
    float* pk    = (float*)alloc((long)SEQ * DIM * 4);
    bf16*  xb    = (bf16*) alloc(NT * DIM * 2);
    bf16*  qkv   = (bf16*) alloc(NT * 2304 * 2);
    bf16*  vT    = (bf16*) alloc(NT * DIM * 2);   // [32][768][256]
    bf16*  ob    = (bf16*) alloc(NT * DIM * 2);
    bf16*  wqkv  = (bf16*) alloc(6L * 2304 * 768 * 2);
    bf16*  woT   = (bf16*) alloc(6L * 768 * 768 * 2);
    bf16*  wf    = (bf16*) alloc(5L * 2304 * 768 * 2);
    float* bqkv  = (float*)alloc(6L * 2304 * 4);
    float* bfus  = (float*)alloc(5L * 2304 * 4);

    const float SCALE = 0.07216878364870322f;   // (HD*2)^-0.5

    // ---- weight conversion / fusion ----
    convert_qkv_kernel<<<(6L * 2304 * 768 / 4 + 255) / 256, 256, 0, stream>>>(Wq, Wk, Wv, wqkv, SCALE);
    transpose_wo_kernel<<<dim3(24, 24, 6), 256, 0, stream>>>(Wo, woT);
    convert_bias_kernel<<<(6 * 2304 + 255) / 256, 256, 0, stream>>>(bq, bk, bv, bqkv, SCALE);
    // Wf_l = Wqkv_{l+1} . Wo_l  — all 5 in ONE batched launch (z = l)
    gemm_bf16_kernel<<<dim3(6, 18, 5), 256, 0, stream>>>(
        wqkv + 2304L * 768, woT, nullptr, wf, nullptr, 768, 768, 0,
        2304L * 768, 768L * 768, 2304L * 768);
    fused_bias_kernel<<<dim3(72, 5), 256, 0, stream>>>(wqkv, bo, bqkv, bfus);

    // ---- positional bias precompute (f32) ----
    posln_kernel<<<256, 256, 0, stream>>>(pos_emb, pos_ln_g, pos_ln_b, wln);
    gemm_kernel<<<dim3(12, 4, 1), 256, 0, stream>>>(wln, DIM, 0, pos_q_w, DIM, 0, pos_q_b,
                                                    pq, DIM, 0, SEQ, DIM, DIM, SCALE);
    gemm_kernel<<<dim3(12, 4, 1), 256, 0, stream>>>(wln, DIM, 0, pos_k_w, DIM, 0, pos_k_b,
                                                    pk, DIM, 0, SEQ, DIM, DIM, 1.0f);
    gemm_kernel<<<dim3(4, 4, NH), 256, 0, stream>>>(pq, DIM, HD, pk, DIM, HD, nullptr,
                                                    bias, SEQ, (long)SEQ * SEQ, SEQ, SEQ, HD, 1.0f);
    relbias_kernel<<<256, 256, 0, stream>>>(rel_tab, rp, bias);

    // ---- token embedding -> bf16 ----
    gather_bf16_kernel<<<8192, 192, 0, stream>>>(tokens, embed, xb);

    // ---- layer pipeline: qkv0, then {attn, fused-gemm} x5, attn, final ----
    gemm_bf16_kernel<<<dim3(18, 64, 1), 256, 0, stream>>>(xb, wqkv, bqkv, qkv, vT, 2304, 768, 1, 0, 0, 0);
    for (int l = 0; l < 5; l++) {
        attn_mfma_kernel<<<1024, 256, 0, stream>>>(qkv, vT, bias, ob);
        gemm_bf16_kernel<<<dim3(18, 64, 1), 256, 0, stream>>>(
            ob, wf + (long)l * 2304 * 768, bfus + (long)l * 2304, qkv, vT, 2304, 768, 1, 0, 0, 0);
    }
    attn_mfma_kernel<<<256, 256, 0, stream>>>(qkv, vT, bias, ob);   // it=0 only
    final_out_kernel<<<dim3(24, 32), 256, 0, stream>>>(ob, Wo + 5L * 768 * 768, bo + 5L * 768, out);
}

// Round 7
// 882.661 us; speedup vs baseline: 1.2942x; 1.0753x over previous
//
#include <hip/hip_runtime.h>
#include <hip/hip_bf16.h>
#include <math.h>

constexpr int SEQ = 256;
constexpr int DIM = 768;
constexpr int NH  = 8;
constexpr int HD  = 96;

typedef __attribute__((ext_vector_type(8))) short short8;
typedef __attribute__((ext_vector_type(4))) float f32x4;
using bf16 = __hip_bfloat16;

#define ASYNC_COPY16(gptr, lptr) \
  __builtin_amdgcn_global_load_lds((const __attribute__((address_space(1))) void*)(gptr), \
                                   (__attribute__((address_space(3))) void*)(lptr), 16, 0, 0)

// ---------------------------------------------------------------------------
// f32 tiled GEMM (tiny positional-bias precompute only)
// ---------------------------------------------------------------------------
__global__ __launch_bounds__(256) void gemm_kernel(
    const float* __restrict__ A, int lda, long aoz,
    const float* __restrict__ W, int ldw, long woz,
    const float* __restrict__ bias,
    float* __restrict__ C, int ldc, long coz,
    int M, int N, int K, float scale)
{
    A += (long)blockIdx.z * aoz;
    W += (long)blockIdx.z * woz;
    C += (long)blockIdx.z * coz;

    __shared__ float As[16][68];
    __shared__ float Ws[16][68];

    const int bm = blockIdx.y * 64;
    const int bn = blockIdx.x * 64;
    const int tid = threadIdx.x;
    const int tx = tid & 15;
    const int ty = tid >> 4;

    float acc[4][4] = {};

    for (int k0 = 0; k0 < K; k0 += 16) {
#pragma unroll
        for (int i = 0; i < 4; i++) {
            int idx = tid + i * 256;
            int r = idx >> 4, c = idx & 15;
            As[c][r] = A[(long)(bm + r) * lda + (k0 + c)];
            Ws[c][r] = W[(long)(bn + r) * ldw + (k0 + c)];
        }
        __syncthreads();
#pragma unroll
        for (int kk = 0; kk < 16; kk++) {
            const float4 a = *(const float4*)&As[kk][ty * 4];
            const float4 w = *(const float4*)&Ws[kk][tx * 4];
            acc[0][0] += a.x * w.x; acc[0][1] += a.x * w.y; acc[0][2] += a.x * w.z; acc[0][3] += a.x * w.w;
            acc[1][0] += a.y * w.x; acc[1][1] += a.y * w.y; acc[1][2] += a.y * w.z; acc[1][3] += a.y * w.w;
            acc[2][0] += a.z * w.x; acc[2][1] += a.z * w.y; acc[2][2] += a.z * w.z; acc[2][3] += a.z * w.w;
            acc[3][0] += a.w * w.x; acc[3][1] += a.w * w.y; acc[3][2] += a.w * w.z; acc[3][3] += a.w * w.w;
        }
        __syncthreads();
    }

    const int n0 = bn + tx * 4;
    float4 bv = make_float4(0.f, 0.f, 0.f, 0.f);
    if (bias) bv = *(const float4*)&bias[n0];
#pragma unroll
    for (int i = 0; i < 4; i++) {
        const int m = bm + ty * 4 + i;
        float4 r;
        r.x = (acc[i][0] + bv.x) * scale;
        r.y = (acc[i][1] + bv.y) * scale;
        r.z = (acc[i][2] + bv.z) * scale;
        r.w = (acc[i][3] + bv.w) * scale;
        *(float4*)&C[(long)m * ldc + n0] = r;
    }
}

// ---------------------------------------------------------------------------
// LayerNorm of pos_emb rows
// ---------------------------------------------------------------------------
__global__ __launch_bounds__(256) void posln_kernel(
    const float* __restrict__ pe, const float* __restrict__ g,
    const float* __restrict__ bb, float* __restrict__ w)
{
    __shared__ float buf[256];
    const int i = blockIdx.x, tid = threadIdx.x;
    const float* row = pe + (long)i * DIM;
    float v0 = row[tid], v1 = row[tid + 256], v2 = row[tid + 512];

    buf[tid] = v0 + v1 + v2;
    __syncthreads();
    for (int off = 128; off > 0; off >>= 1) {
        if (tid < off) buf[tid] += buf[tid + off];
        __syncthreads();
    }
    const float mean = buf[0] * (1.f / 768.f);
    __syncthreads();

    const float d0 = v0 - mean, d1 = v1 - mean, d2 = v2 - mean;
    buf[tid] = d0 * d0 + d1 * d1 + d2 * d2;
    __syncthreads();
    for (int off = 128; off > 0; off >>= 1) {
        if (tid < off) buf[tid] += buf[tid + off];
        __syncthreads();
    }
    const float rstd = rsqrtf(buf[0] * (1.f / 768.f) + 1e-5f);

    float* wr = w + (long)i * DIM;
    wr[tid]       = d0 * rstd * g[tid]       + bb[tid];
    wr[tid + 256] = d1 * rstd * g[tid + 256] + bb[tid + 256];
    wr[tid + 512] = d2 * rstd * g[tid + 512] + bb[tid + 512];
}

// bias[h, ij] += table[rp[ij], h]
__global__ __launch_bounds__(256) void relbias_kernel(
    const float* __restrict__ table, const int* __restrict__ rp,
    float* __restrict__ bias)
{
    const int ij = blockIdx.x * 256 + threadIdx.x;
    const int bucket = rp[ij];
#pragma unroll
    for (int h = 0; h < NH; h++)
        bias[(long)h * SEQ * SEQ + ij] += table[bucket * NH + h];
}

// ---------------------------------------------------------------------------
// weight / bias conversion to bf16 (q-scale folded)
// ---------------------------------------------------------------------------
__global__ __launch_bounds__(256) void convert_qkv_kernel(
    const float* __restrict__ Wq, const float* __restrict__ Wk,
    const float* __restrict__ Wv, bf16* __restrict__ wqkv, float scale)
{
    const long idx = (long)blockIdx.x * 256 + threadIdx.x; // over 6*2304*768/4
    const long e = idx * 4;
    const int k = (int)(e % 768);
    const long nl = e / 768;
    const int n = (int)(nl % 2304);
    const int l = (int)(nl / 2304);

    const float* src;
    float sc = 1.f;
    if (n < 768)       { src = Wq + ((long)l * 768 + n) * 768; sc = scale; }
    else if (n < 1536) { src = Wk + ((long)l * 768 + (n - 768)) * 768; }
    else               { src = Wv + ((long)l * 768 + (n - 1536)) * 768; }

    const float4 v = *(const float4*)&src[k];
    bf16 tmp[4];
    tmp[0] = __float2bfloat16(v.x * sc);
    tmp[1] = __float2bfloat16(v.y * sc);
    tmp[2] = __float2bfloat16(v.z * sc);
    tmp[3] = __float2bfloat16(v.w * sc);
    *(uint2*)&wqkv[((long)l * 2304 + n) * 768 + k] = *(uint2*)tmp;
}

// woT[l][j][c] = bf16(Wo[l][c][j])  (LDS-tiled 32x32 transpose)
__global__ __launch_bounds__(256) void transpose_wo_kernel(
    const float* __restrict__ Wo, bf16* __restrict__ woT)
{
    __shared__ float t[32][33];
    const int l = blockIdx.z;
    const int c0 = blockIdx.x * 32, j0 = blockIdx.y * 32;
    const int tx = threadIdx.x & 31, ty = threadIdx.x >> 5;   // 32 x 8
    const float* src = Wo + (long)l * 768 * 768;
#pragma unroll
    for (int rr = 0; rr < 32; rr += 8)
        t[ty + rr][tx] = src[(long)(c0 + ty + rr) * 768 + j0 + tx];
    __syncthreads();
    bf16* dst = woT + (long)l * 768 * 768;
#pragma unroll
    for (int rr = 0; rr < 32; rr += 8)
        dst[(long)(j0 + ty + rr) * 768 + c0 + tx] = __float2bfloat16(t[tx][ty + rr]);
}

__global__ __launch_bounds__(256) void convert_bias_kernel(
    const float* __restrict__ bq, const float* __restrict__ bk,
    const float* __restrict__ bv, float* __restrict__ bqkv, float scale)
{
    const int idx = blockIdx.x * 256 + threadIdx.x; // over 6*2304
    const int n = idx % 2304;
    const int l = idx / 2304;
    float v;
    if (n < 768)       v = bq[l * 768 + n] * scale;
    else if (n < 1536) v = bk[l * 768 + (n - 768)];
    else               v = bv[l * 768 + (n - 1536)];
    bqkv[idx] = v;
}

// bf[l][n] = wqkv[l+1][n,:] . bo[l] + bqkv[l+1][n]   (l = 0..4)
__global__ __launch_bounds__(256) void fused_bias_kernel(
    const bf16* __restrict__ wqkv, const float* __restrict__ bo,
    const float* __restrict__ bqkv, float* __restrict__ bf_)
{
    const int l = blockIdx.y;                    // 0..4
    const int lane = threadIdx.x & 63, wave = threadIdx.x >> 6;
    const int nloc = wave * 8 + (lane >> 3);     // 0..31
    const int seg = lane & 7;                    // 0..7 (96 c each)
    const int n = blockIdx.x * 32 + nloc;
    const bf16* wrow = wqkv + ((long)(l + 1) * 2304 + n) * 768 + seg * 96;
    const float* bsrc = bo + (long)l * 768 + seg * 96;
    float s = 0.f;
#pragma unroll
    for (int c8 = 0; c8 < 12; c8++) {
        const short8 w8 = *(const short8*)&wrow[c8 * 8];
#pragma unroll
        for (int e = 0; e < 8; e++) {
            bf16 b;
            *(short*)&b = w8[e];
            s += __bfloat162float(b) * bsrc[c8 * 8 + e];
        }
    }
    s += __shfl_xor(s, 1);
    s += __shfl_xor(s, 2);
    s += __shfl_xor(s, 4);
    if (seg == 0) bf_[l * 2304 + n] = s + bqkv[(l + 1) * 2304 + n];
}

// x_bf[t,:] = bf16(embed[tokens[t],:])
__global__ __launch_bounds__(192) void gather_bf16_kernel(
    const int* __restrict__ tokens, const float* __restrict__ emb,
    bf16* __restrict__ x)
{
    const int t = blockIdx.x;
    const int tok = tokens[t];
    const float4 v = ((const float4*)(emb + (long)tok * DIM))[threadIdx.x];
    bf16 tmp[4];
    tmp[0] = __float2bfloat16(v.x);
    tmp[1] = __float2bfloat16(v.y);
    tmp[2] = __float2bfloat16(v.z);
    tmp[3] = __float2bfloat16(v.w);
    *(uint2*)&x[(long)t * DIM + threadIdx.x * 4] = *(uint2*)tmp;
}

// ---------------------------------------------------------------------------
// bf16 MFMA GEMM: C[m,n] = sum_k A[m,k]*B[n,k] + bias[n]
// 128x128 tile, BK=64, double-buffered LDS (ping-pong, statically distinct
// arrays so the compiler can't insert false vmcnt waits before ds_read).
// One barrier per BK iter; prefetch overlaps compute. K % 128 == 0 required.
// XOR-swizzled LDS layout. swz=1: XCD M-stripe (needs 64 m-tiles).
// blockIdx.z batching via az/bz/cz element strides.
// vTout != null: n-tiles >= 1536 write vT[b][h*96+d][s] via LDS-bounce.
// skipQ=1: skip Q n-tiles (bnt<6) for odd m-tiles (only s<16 mod 256 needed).
// ---------------------------------------------------------------------------
#define GEMM_PREF(AS, BS, KB)                                                 \
  {                                                                           \
    _Pragma("unroll")                                                         \
    for (int i = 0; i < 4; i++) {                                             \
      const int u = tid + i * 256;                                            \
      const int r = u >> 3, c = u & 7;                                        \
      const int ca = c ^ (r & 7);                                             \
      ASYNC_COPY16(A + (bm + r) * (long)K + (KB) + ca * 8, &AS[u * 8]);       \
      ASYNC_COPY16(B + (bn + r) * (long)K + (KB) + ca * 8, &BS[u * 8]);       \
    }                                                                         \
  }

#define GEMM_COMPUTE(AS, BS)                                                  \
  {                                                                           \
    _Pragma("unroll")                                                         \
    for (int ks = 0; ks < 2; ks++) {                                          \
      const int cc = ks * 4 + quad;                                           \
      short8 af[4], bfr[4];                                                   \
      _Pragma("unroll")                                                       \
      for (int t = 0; t < 4; t++) {                                           \
        const int ra = wm * 64 + t * 16 + col;                                \
        const int rb = wn * 64 + t * 16 + col;                                \
        af[t]  = *(const short8*)&AS[ra * 64 + ((cc ^ (ra & 7)) * 8)];        \
        bfr[t] = *(const short8*)&BS[rb * 64 + ((cc ^ (rb & 7)) * 8)];        \
      }                                                                       \
      _Pragma("unroll")                                                       \
      for (int tm = 0; tm < 4; tm++)                                          \
        _Pragma("unroll")                                                     \
        for (int tn = 0; tn < 4; tn++)                                        \
          acc[tm][tn] = __builtin_amdgcn_mfma_f32_16x16x32_bf16(af[tm], bfr[tn], acc[tm][tn], 0, 0, 0); \
    }                                                                         \
  }

__global__ __launch_bounds__(256) void gemm_bf16_kernel(
    const bf16* __restrict__ A, const bf16* __restrict__ B,
    const float* __restrict__ bias,
    bf16* __restrict__ Cb, bf16* __restrict__ vTout,
    int N, int K, int swz, long az, long bz, long cz, int skipQ)
{
    __shared__ bf16 As0[128 * 64];   // 16 KB each, 64 KB total
    __shared__ bf16 Bs0[128 * 64];
    __shared__ bf16 As1[128 * 64];
    __shared__ bf16 Bs1[128 * 64];

    A += (long)blockIdx.z * az;
    B += (long)blockIdx.z * bz;
    if (Cb) Cb += (long)blockIdx.z * cz;

    const int tid = threadIdx.x;
    const int lane = tid & 63, wave = tid >> 6;
    const int wm = wave & 1, wn = wave >> 1;

    int bmt, bnt;
    if (swz) {
        const int id = blockIdx.x + gridDim.x * blockIdx.y;
        const int xcd = id & 7, loc = id >> 3;
        bmt = xcd * 8 + (loc & 7);     // m-tile (gridDim.y==64)
        bnt = loc >> 3;                // n-tile
    } else {
        bmt = blockIdx.y;
        bnt = blockIdx.x;
    }
    if (skipQ && bnt < 6 && (bmt & 1)) return;   // block-uniform

    const long bm = (long)bmt * 128, bn = (long)bnt * 128;
    const int col = lane & 15, quad = lane >> 4;

    f32x4 acc[4][4] = {};

    GEMM_PREF(As0, Bs0, 0);
    for (int kk = 0; kk < K; kk += 128) {
        __syncthreads();                 // drains prefetch of As0/Bs0 @ kk
        GEMM_PREF(As1, Bs1, kk + 64);    // overlaps compute below
        GEMM_COMPUTE(As0, Bs0);
        __syncthreads();                 // drains prefetch of As1/Bs1 @ kk+64
        if (kk + 128 < K) GEMM_PREF(As0, Bs0, kk + 128);
        GEMM_COMPUTE(As1, Bs1);
    }

    const bool toVT = (vTout != nullptr) && (bn >= 1536);   // block-uniform

    if (toVT) {
        // -------- wave-local 64x64 transpose through LDS, coalesced write ----
        __syncthreads();
        bf16* tb = (wave < 2 ? As0 : Bs0) + (wave & 1) * 4096;  // 8 KB / wave

#pragma unroll
        for (int tn = 0; tn < 4; tn++) {
            const int nl = tn * 16 + col;
            const float bvv = bias[bn + wn * 64 + nl];
#pragma unroll
            for (int tm = 0; tm < 4; tm++) {
                const int mc = tm * 4 + quad;       // m-chunk (4 bf16)
                bf16 t4[4];
#pragma unroll
                for (int r = 0; r < 4; r++)
                    t4[r] = __float2bfloat16(acc[tm][tn][r] + bvv);
                *(uint2*)&tb[(nl * 16 + (mc ^ (nl & 15))) * 4] = *(uint2*)t4;
            }
        }
        const int b_  = (int)((bm + wm * 64) >> 8);
        const int s0  = (int)((bm + wm * 64) & 255);
        const long nb = bn + wn * 64 - 1536;        // h*96+d base
#pragma unroll
        for (int it2 = 0; it2 < 16; it2++) {
            const int nl = it2 * 4 + quad;
            const uint2 v = *(const uint2*)&tb[(nl * 16 + (col ^ (nl & 15))) * 4];
            *(uint2*)&vTout[((long)b_ * 768 + nb + nl) * 256 + s0 + col * 4] = v;
        }
    } else {
#pragma unroll
        for (int tn = 0; tn < 4; tn++) {
            const long n = bn + wn * 64 + tn * 16 + col;
            const float bvv = bias ? bias[n] : 0.f;
#pragma unroll
            for (int tm = 0; tm < 4; tm++) {
                const long m0 = bm + wm * 64 + tm * 16 + quad * 4;
#pragma unroll
                for (int r = 0; r < 4; r++)
                    Cb[(m0 + r) * N + n] = __float2bfloat16(acc[tm][tn][r] + bvv);
            }
        }
    }
}

// ---------------------------------------------------------------------------
// MFMA attention, zero-staging: Q in regs, K direct from qkv, V direct from
// vT (pre-transposed). LDS = Ps only. Block per (it, h, b), b innermost.
// Final layer: launch grid=256 with 64 threads (1 wave -> rows 0..15 only).
// ---------------------------------------------------------------------------
__global__ __launch_bounds__(256) void attn_mfma_kernel(
    const bf16* __restrict__ qkv, const bf16* __restrict__ vT,
    const float* __restrict__ bias, bf16* __restrict__ o)
{
    constexpr int PS = 264;  // Ps stride (bf16)
    __shared__ bf16 Ps[64 * PS];   // 33.8 KB -> 4 blocks/CU

    const int blk = blockIdx.x;          // (it*8 + h)*32 + b
    const int b  = blk & 31;
    const int h  = (blk >> 5) & 7;
    const int it = blk >> 8;
    const int i0 = it * 64;
    const int tid = threadIdx.x, lane = tid & 63, wave = tid >> 6;
    const int col = lane & 15, quad = lane >> 4;
    const long rowbase = (long)b * SEQ;

    // Q fragments (A-operand layout): row i0+wave*16+col, k = ks*32+quad*8
    short8 aq[3];
    {
        const bf16* qrow = qkv + (rowbase + i0 + wave * 16 + col) * 2304 + h * 96;
#pragma unroll
        for (int ks = 0; ks < 3; ks++)
            aq[ks] = *(const short8*)&qrow[ks * 32 + quad * 8];
    }

    // ---- scores: K fragments direct from global (16 rows x 64B, coalesced) ----
    f32x4 accS[16];
#pragma unroll
    for (int jt = 0; jt < 16; jt++) {
        const bf16* krow = qkv + (rowbase + jt * 16 + col) * 2304 + 768 + h * 96;
        f32x4 a = {};
#pragma unroll
        for (int ks = 0; ks < 3; ks++) {
            const short8 bk_ = *(const short8*)&krow[ks * 32 + quad * 8];
            a = __builtin_amdgcn_mfma_f32_16x16x32_bf16(aq[ks], bk_, a, 0, 0, 0);
        }
        accS[jt] = a;
    }

    // ---- bias + softmax (rows i0+wave*16+quad*4+r, col jt*16+col) ----
    const float* bb = bias + ((long)h * SEQ + i0 + wave * 16 + quad * 4) * SEQ;
#pragma unroll
    for (int jt = 0; jt < 16; jt++)
#pragma unroll
        for (int r = 0; r < 4; r++)
            accS[jt][r] += bb[r * SEQ + jt * 16 + col];

#pragma unroll
    for (int r = 0; r < 4; r++) {
        float m = accS[0][r];
#pragma unroll
        for (int jt = 1; jt < 16; jt++) m = fmaxf(m, accS[jt][r]);
        for (int d = 1; d < 16; d <<= 1) m = fmaxf(m, __shfl_xor(m, d));
        float s = 0.f;
#pragma unroll
        for (int jt = 0; jt < 16; jt++) {
            const float e = __expf(accS[jt][r] - m);
            accS[jt][r] = e;
            s += e;
        }
        for (int d = 1; d < 16; d <<= 1) s += __shfl_xor(s, d);
        const float inv = 1.f / s;
        const int prow = wave * 16 + quad * 4 + r;
#pragma unroll
        for (int jt = 0; jt < 16; jt++)
            Ps[prow * PS + jt * 16 + col] = __float2bfloat16(accS[jt][r] * inv);
    }
    // no barrier: each wave reads only the 16 Ps rows it wrote (lgkmcnt order)

    // ---- O = P.V : V fragments direct from vT (16 rows x 64B, coalesced) ----
    f32x4 accO[6] = {};
    const bf16* vbase = vT + ((long)b * 768 + h * 96) * 256;
    for (int kc = 0; kc < 8; kc++) {
        const short8 ap = *(const short8*)&Ps[(wave * 16 + col) * PS + kc * 32 + quad * 8];
#pragma unroll
        for (int nt = 0; nt < 6; nt++) {
            const short8 bv_ = *(const short8*)&vbase[(nt * 16 + col) * 256 + kc * 32 + quad * 8];
            accO[nt] = __builtin_amdgcn_mfma_f32_16x16x32_bf16(ap, bv_, accO[nt], 0, 0, 0);
        }
    }

#pragma unroll
    for (int nt = 0; nt < 6; nt++)
#pragma unroll
        for (int r = 0; r < 4; r++) {
            const long m = rowbase + i0 + wave * 16 + quad * 4 + r;
            o[m * DIM + h * 96 + nt * 16 + col] = __float2bfloat16(accO[nt][r]);
        }
}

// out[b, ng*32 + tid>>3] = ob[b*256,:] . Wo5[n,:] + bo5[n]
// grid (24, 32): 768 blocks, 8 lanes per dot product.
__global__ __launch_bounds__(256) void final_out_kernel(
    const bf16* __restrict__ ob, const float* __restrict__ Wo5,
    const float* __restrict__ bo5, float* __restrict__ out)
{
    __shared__ float os[768];
    const int b = blockIdx.y, ng = blockIdx.x, tid = threadIdx.x;
    const bf16* orow = ob + (long)b * 256 * 768;
    for (int i = tid; i < 768; i += 256) os[i] = __bfloat162float(orow[i]);
    __syncthreads();

    const int n = ng * 32 + (tid >> 3);
    const int seg = tid & 7;
    const float* wrow = Wo5 + (long)n * 768 + seg * 96;
    const float* xs = &os[seg * 96];
    float s = 0.f;
#pragma unroll
    for (int k = 0; k < 96; k += 4) {
        const float4 w = *(const float4*)&wrow[k];
        s += xs[k] * w.x + xs[k + 1] * w.y + xs[k + 2] * w.z + xs[k + 3] * w.w;
    }
    s += __shfl_xor(s, 1);
    s += __shfl_xor(s, 2);
    s += __shfl_xor(s, 4);
    if (seg == 0) out[b * 768 + n] = s + bo5[n];
}

extern "C" void kernel_launch(void* const* d_in, const int* in_sizes, int n_in,
                              void* d_out, int out_size, void* d_ws, size_t ws_size,
                              hipStream_t stream)
{
    const int*   tokens   = (const int*)d_in[0];
    const float* embed    = (const float*)d_in[1];
    const float* pos_emb  = (const float*)d_in[2];
    const float* pos_q_w  = (const float*)d_in[3];
    const float* pos_q_b  = (const float*)d_in[4];
    const float* pos_k_w  = (const float*)d_in[5];
    const float* pos_k_b  = (const float*)d_in[6];
    const float* pos_ln_g = (const float*)d_in[7];
    const float* pos_ln_b = (const float*)d_in[8];
    const float* rel_tab  = (const float*)d_in[9];
    const int*   rp       = (const int*)d_in[10];
    const float* Wq = (const float*)d_in[11];
    const float* bq = (const float*)d_in[12];
    const float* Wk = (const float*)d_in[13];
    const float* bk = (const float*)d_in[14];
    const float* Wv = (const float*)d_in[15];
    const float* bv = (const float*)d_in[16];
    const float* Wo = (const float*)d_in[17];
    const float* bo = (const float*)d_in[18];
    float* out = (float*)d_out;

    char* p = (char*)d_ws;
    auto alloc = [&](size_t bytes) -> char* {
        char* r = p;
        p += (bytes + 255) & ~(size_t)255;
        return r;
    };
    const long NT = 32L * SEQ;  // 8192

    float* bias  = (float*)alloc(8L * SEQ * SEQ * 4);
    float* wln   = (float*)alloc((long)SEQ * DIM * 4);
    float* pq    = (float*)alloc((long)SEQ * DIM * 4);
    float* pk    = (float*)alloc((long)SEQ * DIM * 4);
    bf16*  xb    = (bf16*) alloc(NT * DIM * 2);
    bf16*  qkv   = (bf16*) alloc(NT * 2304 * 2);
    bf16*  vT    = (bf16*) alloc(NT * DIM * 2);   // [32][768][256]
    bf16*  ob    = (bf16*) alloc(NT * DIM * 2);
    bf16*  wqkv  = (bf16*) alloc(6L * 2304 * 768 * 2);
    bf16*  woT   = (bf16*) alloc(6L * 768 * 768 * 2);
    bf16*  wf    = (bf16*) alloc(5L * 2304 * 768 * 2);
    float* bqkv  = (float*)alloc(6L * 2304 * 4);
    float* bfus  = (float*)alloc(5L * 2304 * 4);

    const float SCALE = 0.07216878364870322f;   // (HD*2)^-0.5

    // ---- weight conversion / fusion ----
    convert_qkv_kernel<<<(6L * 2304 * 768 / 4 + 255) / 256, 256, 0, stream>>>(Wq, Wk, Wv, wqkv, SCALE);
    transpose_wo_kernel<<<dim3(24, 24, 6), 256, 0, stream>>>(Wo, woT);
    convert_bias_kernel<<<(6 * 2304 + 255) / 256, 256, 0, stream>>>(bq, bk, bv, bqkv, SCALE);
    // Wf_l = Wqkv_{l+1} . Wo_l  — all 5 in ONE batched launch (z = l)
    gemm_bf16_kernel<<<dim3(6, 18, 5), 256, 0, stream>>>(
        wqkv + 2304L * 768, woT, nullptr, wf, nullptr, 768, 768, 0,
        2304L * 768, 768L * 768, 2304L * 768, 0);
    fused_bias_kernel<<<dim3(72, 5), 256, 0, stream>>>(wqkv, bo, bqkv, bfus);

    // ---- positional bias precompute (f32) ----
    posln_kernel<<<256, 256, 0, stream>>>(pos_emb, pos_ln_g, pos_ln_b, wln);
    gemm_kernel<<<dim3(12, 4, 1), 256, 0, stream>>>(wln, DIM, 0, pos_q_w, DIM, 0, pos_q_b,
                                                    pq, DIM, 0, SEQ, DIM, DIM, SCALE);
    gemm_kernel<<<dim3(12, 4, 1), 256, 0, stream>>>(wln, DIM, 0, pos_k_w, DIM, 0, pos_k_b,
                                                    pk, DIM, 0, SEQ, DIM, DIM, 1.0f);
    gemm_kernel<<<dim3(4, 4, NH), 256, 0, stream>>>(pq, DIM, HD, pk, DIM, HD, nullptr,
                                                    bias, SEQ, (long)SEQ * SEQ, SEQ, SEQ, HD, 1.0f);
    relbias_kernel<<<256, 256, 0, stream>>>(rel_tab, rp, bias);

    // ---- token embedding -> bf16 ----
    gather_bf16_kernel<<<8192, 192, 0, stream>>>(tokens, embed, xb);

    // ---- layer pipeline: qkv0, then {attn, fused-gemm} x5, attn, final ----
    gemm_bf16_kernel<<<dim3(18, 64, 1), 256, 0, stream>>>(xb, wqkv, bqkv, qkv, vT, 2304, 768, 1, 0, 0, 0, 0);
    for (int l = 0; l < 5; l++) {
        attn_mfma_kernel<<<1024, 256, 0, stream>>>(qkv, vT, bias, ob);
        gemm_bf16_kernel<<<dim3(18, 64, 1), 256, 0, stream>>>(
            ob, wf + (long)l * 2304 * 768, bfus + (long)l * 2304, qkv, vT, 2304, 768, 1, 0, 0, 0,
            (l == 4) ? 1 : 0);
    }
    attn_mfma_kernel<<<256, 64, 0, stream>>>(qkv, vT, bias, ob);   // it=0, 1 wave: rows 0..15
    final_out_kernel<<<dim3(24, 32), 256, 0, stream>>>(ob, Wo + 5L * 768 * 768, bo + 5L * 768, out);
}

// Round 8
// 847.731 us; speedup vs baseline: 1.3476x; 1.0412x over previous
//
#include <hip/hip_runtime.h>
#include <hip/hip_bf16.h>
#include <math.h>

constexpr int SEQ = 256;
constexpr int DIM = 768;
constexpr int NH  = 8;
constexpr int HD  = 96;

typedef __attribute__((ext_vector_type(8))) short short8;
typedef __attribute__((ext_vector_type(4))) float f32x4;
using bf16 = __hip_bfloat16;

#define ASYNC_COPY16(gptr, lptr) \
  __builtin_amdgcn_global_load_lds((const __attribute__((address_space(1))) void*)(gptr), \
                                   (__attribute__((address_space(3))) void*)(lptr), 16, 0, 0)

// ---------------------------------------------------------------------------
// f32 tiled GEMM: C[m,n] = (sum_k A[m,k]*W[n,k] + bias[n]) * scale  (+ rel)
// rtab != null: C[m,n] = acc*scale + rtab[rp[n*256+m]*8 + blockIdx.z]
// (used to emit biasT[h][j][i] with the T5 rel-bias folded in).
// ---------------------------------------------------------------------------
__global__ __launch_bounds__(256) void gemm_kernel(
    const float* __restrict__ A, int lda, long aoz,
    const float* __restrict__ W, int ldw, long woz,
    const float* __restrict__ bias, long boz,
    float* __restrict__ C, int ldc, long coz,
    int M, int N, int K, float scale,
    const int* __restrict__ rp, const float* __restrict__ rtab)
{
    const int hz = blockIdx.z;
    A += (long)hz * aoz;
    W += (long)hz * woz;
    if (bias) bias += (long)hz * boz;
    C += (long)hz * coz;

    __shared__ float As[16][68];
    __shared__ float Ws[16][68];

    const int bm = blockIdx.y * 64;
    const int bn = blockIdx.x * 64;
    const int tid = threadIdx.x;
    const int tx = tid & 15;
    const int ty = tid >> 4;

    float acc[4][4] = {};

    for (int k0 = 0; k0 < K; k0 += 16) {
#pragma unroll
        for (int i = 0; i < 4; i++) {
            int idx = tid + i * 256;
            int r = idx >> 4, c = idx & 15;
            As[c][r] = A[(long)(bm + r) * lda + (k0 + c)];
            Ws[c][r] = W[(long)(bn + r) * ldw + (k0 + c)];
        }
        __syncthreads();
#pragma unroll
        for (int kk = 0; kk < 16; kk++) {
            const float4 a = *(const float4*)&As[kk][ty * 4];
            const float4 w = *(const float4*)&Ws[kk][tx * 4];
            acc[0][0] += a.x * w.x; acc[0][1] += a.x * w.y; acc[0][2] += a.x * w.z; acc[0][3] += a.x * w.w;
            acc[1][0] += a.y * w.x; acc[1][1] += a.y * w.y; acc[1][2] += a.y * w.z; acc[1][3] += a.y * w.w;
            acc[2][0] += a.z * w.x; acc[2][1] += a.z * w.y; acc[2][2] += a.z * w.z; acc[2][3] += a.z * w.w;
            acc[3][0] += a.w * w.x; acc[3][1] += a.w * w.y; acc[3][2] += a.w * w.z; acc[3][3] += a.w * w.w;
        }
        __syncthreads();
    }

    const int n0 = bn + tx * 4;
    float4 bv = make_float4(0.f, 0.f, 0.f, 0.f);
    if (bias) bv = *(const float4*)&bias[n0];
#pragma unroll
    for (int i = 0; i < 4; i++) {
        const int m = bm + ty * 4 + i;
        float4 r;
        if (rtab) {
            r.x = acc[i][0] * scale + rtab[rp[(n0 + 0) * 256 + m] * 8 + hz];
            r.y = acc[i][1] * scale + rtab[rp[(n0 + 1) * 256 + m] * 8 + hz];
            r.z = acc[i][2] * scale + rtab[rp[(n0 + 2) * 256 + m] * 8 + hz];
            r.w = acc[i][3] * scale + rtab[rp[(n0 + 3) * 256 + m] * 8 + hz];
        } else {
            r.x = (acc[i][0] + bv.x) * scale;
            r.y = (acc[i][1] + bv.y) * scale;
            r.z = (acc[i][2] + bv.z) * scale;
            r.w = (acc[i][3] + bv.w) * scale;
        }
        *(float4*)&C[(long)m * ldc + n0] = r;
    }
}

// ---------------------------------------------------------------------------
// Setup mega-kernel: all independent prep in one launch (role by blockIdx).
//  A: convert Wq|Wk|Wv -> wqkv bf16 (q-scale folded)        [0, 10368)
//  B: transpose Wo -> woT bf16                              [+3456)
//  C: convert bq|bk|bv -> bqkv f32 (q-scale folded)         [+54)
//  D: token gather -> xb bf16                               [+8192)
//  E: pos_emb layernorm -> wln f32                          [+256)
//  F: stage pos_q_w|pos_k_w -> wsW contiguous               [+1152)
//  G: stage pos_q_b|pos_k_b -> wsB contiguous               [+2)
// ---------------------------------------------------------------------------
constexpr int RB_A = 10368;
constexpr int RB_B = RB_A + 3456;
constexpr int RB_C = RB_B + 54;
constexpr int RB_D = RB_C + 8192;
constexpr int RB_E = RB_D + 256;
constexpr int RB_F = RB_E + 1152;
constexpr int RB_G = RB_F + 2;

__global__ __launch_bounds__(256) void setup_mega_kernel(
    const int* __restrict__ tokens, const float* __restrict__ embed,
    const float* __restrict__ pos_emb,
    const float* __restrict__ pos_q_w, const float* __restrict__ pos_q_b,
    const float* __restrict__ pos_k_w, const float* __restrict__ pos_k_b,
    const float* __restrict__ pos_ln_g, const float* __restrict__ pos_ln_b,
    const float* __restrict__ Wq, const float* __restrict__ Wk,
    const float* __restrict__ Wv, const float* __restrict__ Wo,
    const float* __restrict__ bq, const float* __restrict__ bk,
    const float* __restrict__ bv,
    bf16* __restrict__ wqkv, bf16* __restrict__ woT, float* __restrict__ bqkv,
    bf16* __restrict__ xb, float* __restrict__ wln,
    float* __restrict__ wsW, float* __restrict__ wsB, float scale)
{
    const int bid = blockIdx.x, tid = threadIdx.x;

    if (bid < RB_A) {
        // ---- convert QKV weights ----
        const long idx = (long)bid * 256 + tid;
        const long e = idx * 4;
        const int k = (int)(e % 768);
        const long nl = e / 768;
        const int n = (int)(nl % 2304);
        const int l = (int)(nl / 2304);
        const float* src;
        float sc = 1.f;
        if (n < 768)       { src = Wq + ((long)l * 768 + n) * 768; sc = scale; }
        else if (n < 1536) { src = Wk + ((long)l * 768 + (n - 768)) * 768; }
        else               { src = Wv + ((long)l * 768 + (n - 1536)) * 768; }
        const float4 v = *(const float4*)&src[k];
        bf16 tmp[4];
        tmp[0] = __float2bfloat16(v.x * sc);
        tmp[1] = __float2bfloat16(v.y * sc);
        tmp[2] = __float2bfloat16(v.z * sc);
        tmp[3] = __float2bfloat16(v.w * sc);
        *(uint2*)&wqkv[((long)l * 2304 + n) * 768 + k] = *(uint2*)tmp;
    } else if (bid < RB_B) {
        // ---- transpose Wo ----
        __shared__ float t[32][33];
        const int b2 = bid - RB_A;
        const int l = b2 / 576, r2 = b2 % 576;
        const int c0 = (r2 % 24) * 32, j0 = (r2 / 24) * 32;
        const int tx = tid & 31, ty = tid >> 5;
        const float* src = Wo + (long)l * 768 * 768;
#pragma unroll
        for (int rr = 0; rr < 32; rr += 8)
            t[ty + rr][tx] = src[(long)(c0 + ty + rr) * 768 + j0 + tx];
        __syncthreads();
        bf16* dst = woT + (long)l * 768 * 768;
#pragma unroll
        for (int rr = 0; rr < 32; rr += 8)
            dst[(long)(j0 + ty + rr) * 768 + c0 + tx] = __float2bfloat16(t[tx][ty + rr]);
    } else if (bid < RB_C) {
        // ---- convert biases ----
        const int idx = (bid - RB_B) * 256 + tid;   // over 6*2304
        if (idx < 6 * 2304) {
            const int n = idx % 2304, l = idx / 2304;
            float v;
            if (n < 768)       v = bq[l * 768 + n] * scale;
            else if (n < 1536) v = bk[l * 768 + (n - 768)];
            else               v = bv[l * 768 + (n - 1536)];
            bqkv[idx] = v;
        }
    } else if (bid < RB_D) {
        // ---- token gather ----
        if (tid < 192) {
            const int t = bid - RB_C;
            const int tok = tokens[t];
            const float4 v = ((const float4*)(embed + (long)tok * DIM))[tid];
            bf16 tmp[4];
            tmp[0] = __float2bfloat16(v.x);
            tmp[1] = __float2bfloat16(v.y);
            tmp[2] = __float2bfloat16(v.z);
            tmp[3] = __float2bfloat16(v.w);
            *(uint2*)&xb[(long)t * DIM + tid * 4] = *(uint2*)tmp;
        }
    } else if (bid < RB_E) {
        // ---- pos layernorm ----
        __shared__ float buf[256];
        const int i = bid - RB_D;
        const float* row = pos_emb + (long)i * DIM;
        float v0 = row[tid], v1 = row[tid + 256], v2 = row[tid + 512];
        buf[tid] = v0 + v1 + v2;
        __syncthreads();
        for (int off = 128; off > 0; off >>= 1) {
            if (tid < off) buf[tid] += buf[tid + off];
            __syncthreads();
        }
        const float mean = buf[0] * (1.f / 768.f);
        __syncthreads();
        const float d0 = v0 - mean, d1 = v1 - mean, d2 = v2 - mean;
        buf[tid] = d0 * d0 + d1 * d1 + d2 * d2;
        __syncthreads();
        for (int off = 128; off > 0; off >>= 1) {
            if (tid < off) buf[tid] += buf[tid + off];
            __syncthreads();
        }
        const float rstd = rsqrtf(buf[0] * (1.f / 768.f) + 1e-5f);
        float* wr = wln + (long)i * DIM;
        wr[tid]       = d0 * rstd * pos_ln_g[tid]       + pos_ln_b[tid];
        wr[tid + 256] = d1 * rstd * pos_ln_g[tid + 256] + pos_ln_b[tid + 256];
        wr[tid + 512] = d2 * rstd * pos_ln_g[tid + 512] + pos_ln_b[tid + 512];
    } else if (bid < RB_F) {
        // ---- stage pos weights contiguously ----
        const long idx = (long)(bid - RB_E) * 256 + tid;
        const long e = idx * 4;
        const float4 v = (e < 589824) ? *(const float4*)&pos_q_w[e]
                                      : *(const float4*)&pos_k_w[e - 589824];
        *(float4*)&wsW[e] = v;
    } else {
        // ---- stage pos biases ----
        const int idx = (bid - RB_F) * 256 + tid;   // over 1536
        wsB[idx] = (idx < 768) ? pos_q_b[idx] : pos_k_b[idx - 768];
    }
}

// bf[l][n] = wqkv[l+1][n,:] . bo[l] + bqkv[l+1][n]   (l = 0..4)
__global__ __launch_bounds__(256) void fused_bias_kernel(
    const bf16* __restrict__ wqkv, const float* __restrict__ bo,
    const float* __restrict__ bqkv, float* __restrict__ bf_)
{
    const int l = blockIdx.y;
    const int lane = threadIdx.x & 63, wave = threadIdx.x >> 6;
    const int nloc = wave * 8 + (lane >> 3);
    const int seg = lane & 7;
    const int n = blockIdx.x * 32 + nloc;
    const bf16* wrow = wqkv + ((long)(l + 1) * 2304 + n) * 768 + seg * 96;
    const float* bsrc = bo + (long)l * 768 + seg * 96;
    float s = 0.f;
#pragma unroll
    for (int c8 = 0; c8 < 12; c8++) {
        const short8 w8 = *(const short8*)&wrow[c8 * 8];
#pragma unroll
        for (int e = 0; e < 8; e++) {
            bf16 b;
            *(short*)&b = w8[e];
            s += __bfloat162float(b) * bsrc[c8 * 8 + e];
        }
    }
    s += __shfl_xor(s, 1);
    s += __shfl_xor(s, 2);
    s += __shfl_xor(s, 4);
    if (seg == 0) bf_[l * 2304 + n] = s + bqkv[(l + 1) * 2304 + n];
}

// ---------------------------------------------------------------------------
// bf16 MFMA GEMM: 128x128 tile, BK=64, ping-pong double-buffered LDS.
// ---------------------------------------------------------------------------
#define GEMM_PREF(AS, BS, KB)                                                 \
  {                                                                           \
    _Pragma("unroll")                                                         \
    for (int i = 0; i < 4; i++) {                                             \
      const int u = tid + i * 256;                                            \
      const int r = u >> 3, c = u & 7;                                        \
      const int ca = c ^ (r & 7);                                             \
      ASYNC_COPY16(A + (bm + r) * (long)K + (KB) + ca * 8, &AS[u * 8]);       \
      ASYNC_COPY16(B + (bn + r) * (long)K + (KB) + ca * 8, &BS[u * 8]);       \
    }                                                                         \
  }

#define GEMM_COMPUTE(AS, BS)                                                  \
  {                                                                           \
    _Pragma("unroll")                                                         \
    for (int ks = 0; ks < 2; ks++) {                                          \
      const int cc = ks * 4 + quad;                                           \
      short8 af[4], bfr[4];                                                   \
      _Pragma("unroll")                                                       \
      for (int t = 0; t < 4; t++) {                                           \
        const int ra = wm * 64 + t * 16 + col;                                \
        const int rb = wn * 64 + t * 16 + col;                                \
        af[t]  = *(const short8*)&AS[ra * 64 + ((cc ^ (ra & 7)) * 8)];        \
        bfr[t] = *(const short8*)&BS[rb * 64 + ((cc ^ (rb & 7)) * 8)];        \
      }                                                                       \
      _Pragma("unroll")                                                       \
      for (int tm = 0; tm < 4; tm++)                                          \
        _Pragma("unroll")                                                     \
        for (int tn = 0; tn < 4; tn++)                                        \
          acc[tm][tn] = __builtin_amdgcn_mfma_f32_16x16x32_bf16(af[tm], bfr[tn], acc[tm][tn], 0, 0, 0); \
    }                                                                         \
  }

__global__ __launch_bounds__(256) void gemm_bf16_kernel(
    const bf16* __restrict__ A, const bf16* __restrict__ B,
    const float* __restrict__ bias,
    bf16* __restrict__ Cb, bf16* __restrict__ vTout,
    int N, int K, int swz, long az, long bz, long cz, int skipQ)
{
    __shared__ bf16 As0[128 * 64];
    __shared__ bf16 Bs0[128 * 64];
    __shared__ bf16 As1[128 * 64];
    __shared__ bf16 Bs1[128 * 64];

    A += (long)blockIdx.z * az;
    B += (long)blockIdx.z * bz;
    if (Cb) Cb += (long)blockIdx.z * cz;

    const int tid = threadIdx.x;
    const int lane = tid & 63, wave = tid >> 6;
    const int wm = wave & 1, wn = wave >> 1;

    int bmt, bnt;
    if (swz) {
        const int id = blockIdx.x + gridDim.x * blockIdx.y;
        const int xcd = id & 7, loc = id >> 3;
        bmt = xcd * 8 + (loc & 7);
        bnt = loc >> 3;
    } else {
        bmt = blockIdx.y;
        bnt = blockIdx.x;
    }
    if (skipQ && bnt < 6 && (bmt & 1)) return;

    const long bm = (long)bmt * 128, bn = (long)bnt * 128;
    const int col = lane & 15, quad = lane >> 4;

    f32x4 acc[4][4] = {};

    GEMM_PREF(As0, Bs0, 0);
    for (int kk = 0; kk < K; kk += 128) {
        __syncthreads();
        GEMM_PREF(As1, Bs1, kk + 64);
        GEMM_COMPUTE(As0, Bs0);
        __syncthreads();
        if (kk + 128 < K) GEMM_PREF(As0, Bs0, kk + 128);
        GEMM_COMPUTE(As1, Bs1);
    }

    const bool toVT = (vTout != nullptr) && (bn >= 1536);

    if (toVT) {
        __syncthreads();
        bf16* tb = (wave < 2 ? As0 : Bs0) + (wave & 1) * 4096;
#pragma unroll
        for (int tn = 0; tn < 4; tn++) {
            const int nl = tn * 16 + col;
            const float bvv = bias[bn + wn * 64 + nl];
#pragma unroll
            for (int tm = 0; tm < 4; tm++) {
                const int mc = tm * 4 + quad;
                bf16 t4[4];
#pragma unroll
                for (int r = 0; r < 4; r++)
                    t4[r] = __float2bfloat16(acc[tm][tn][r] + bvv);
                *(uint2*)&tb[(nl * 16 + (mc ^ (nl & 15))) * 4] = *(uint2*)t4;
            }
        }
        const int b_  = (int)((bm + wm * 64) >> 8);
        const int s0  = (int)((bm + wm * 64) & 255);
        const long nb = bn + wn * 64 - 1536;
#pragma unroll
        for (int it2 = 0; it2 < 16; it2++) {
            const int nl = it2 * 4 + quad;
            const uint2 v = *(const uint2*)&tb[(nl * 16 + (col ^ (nl & 15))) * 4];
            *(uint2*)&vTout[((long)b_ * 768 + nb + nl) * 256 + s0 + col * 4] = v;
        }
    } else {
#pragma unroll
        for (int tn = 0; tn < 4; tn++) {
            const long n = bn + wn * 64 + tn * 16 + col;
            const float bvv = bias ? bias[n] : 0.f;
#pragma unroll
            for (int tm = 0; tm < 4; tm++) {
                const long m0 = bm + wm * 64 + tm * 16 + quad * 4;
#pragma unroll
                for (int r = 0; r < 4; r++)
                    Cb[(m0 + r) * N + n] = __float2bfloat16(acc[tm][tn][r] + bvv);
            }
        }
    }
}

// ---------------------------------------------------------------------------
// MFMA attention: Q in regs, K direct from qkv, V direct from vT, bias from
// biasT[h][j][i] (float4 per lane). LDS = Ps only. Block per (it, h, b).
// Final layer: grid=256, 64 threads (1 wave -> rows 0..15).
// ---------------------------------------------------------------------------
__global__ __launch_bounds__(256) void attn_mfma_kernel(
    const bf16* __restrict__ qkv, const bf16* __restrict__ vT,
    const float* __restrict__ biasT, bf16* __restrict__ o)
{
    constexpr int PS = 264;
    __shared__ bf16 Ps[64 * PS];

    const int blk = blockIdx.x;
    const int b  = blk & 31;
    const int h  = (blk >> 5) & 7;
    const int it = blk >> 8;
    const int i0 = it * 64;
    const int tid = threadIdx.x, lane = tid & 63, wave = tid >> 6;
    const int col = lane & 15, quad = lane >> 4;
    const long rowbase = (long)b * SEQ;

    short8 aq[3];
    {
        const bf16* qrow = qkv + (rowbase + i0 + wave * 16 + col) * 2304 + h * 96;
#pragma unroll
        for (int ks = 0; ks < 3; ks++)
            aq[ks] = *(const short8*)&qrow[ks * 32 + quad * 8];
    }

    f32x4 accS[16];
#pragma unroll
    for (int jt = 0; jt < 16; jt++) {
        const bf16* krow = qkv + (rowbase + jt * 16 + col) * 2304 + 768 + h * 96;
        f32x4 a = {};
#pragma unroll
        for (int ks = 0; ks < 3; ks++) {
            const short8 bk_ = *(const short8*)&krow[ks * 32 + quad * 8];
            a = __builtin_amdgcn_mfma_f32_16x16x32_bf16(aq[ks], bk_, a, 0, 0, 0);
        }
        accS[jt] = a;
    }

    // bias: biasT[h][j = jt*16+col][i = i0+wave*16+quad*4 + r] -> float4
    const float* bbT = biasT + (long)h * SEQ * SEQ + i0 + wave * 16 + quad * 4;
#pragma unroll
    for (int jt = 0; jt < 16; jt++) {
        const float4 bv4 = *(const float4*)&bbT[(jt * 16 + col) * SEQ];
        accS[jt][0] += bv4.x;
        accS[jt][1] += bv4.y;
        accS[jt][2] += bv4.z;
        accS[jt][3] += bv4.w;
    }

#pragma unroll
    for (int r = 0; r < 4; r++) {
        float m = accS[0][r];
#pragma unroll
        for (int jt = 1; jt < 16; jt++) m = fmaxf(m, accS[jt][r]);
        for (int d = 1; d < 16; d <<= 1) m = fmaxf(m, __shfl_xor(m, d));
        float s = 0.f;
#pragma unroll
        for (int jt = 0; jt < 16; jt++) {
            const float e = __expf(accS[jt][r] - m);
            accS[jt][r] = e;
            s += e;
        }
        for (int d = 1; d < 16; d <<= 1) s += __shfl_xor(s, d);
        const float inv = 1.f / s;
        const int prow = wave * 16 + quad * 4 + r;
#pragma unroll
        for (int jt = 0; jt < 16; jt++)
            Ps[prow * PS + jt * 16 + col] = __float2bfloat16(accS[jt][r] * inv);
    }
    // no barrier: each wave reads only the 16 Ps rows it wrote

    f32x4 accO[6] = {};
    const bf16* vbase = vT + ((long)b * 768 + h * 96) * 256;
    for (int kc = 0; kc < 8; kc++) {
        const short8 ap = *(const short8*)&Ps[(wave * 16 + col) * PS + kc * 32 + quad * 8];
#pragma unroll
        for (int nt = 0; nt < 6; nt++) {
            const short8 bv_ = *(const short8*)&vbase[(nt * 16 + col) * 256 + kc * 32 + quad * 8];
            accO[nt] = __builtin_amdgcn_mfma_f32_16x16x32_bf16(ap, bv_, accO[nt], 0, 0, 0);
        }
    }

#pragma unroll
    for (int nt = 0; nt < 6; nt++)
#pragma unroll
        for (int r = 0; r < 4; r++) {
            const long m = rowbase + i0 + wave * 16 + quad * 4 + r;
            o[m * DIM + h * 96 + nt * 16 + col] = __float2bfloat16(accO[nt][r]);
        }
}

// out[b, ng*32 + tid>>3] = ob[b*256,:] . Wo5[n,:] + bo5[n]
__global__ __launch_bounds__(256) void final_out_kernel(
    const bf16* __restrict__ ob, const float* __restrict__ Wo5,
    const float* __restrict__ bo5, float* __restrict__ out)
{
    __shared__ float os[768];
    const int b = blockIdx.y, ng = blockIdx.x, tid = threadIdx.x;
    const bf16* orow = ob + (long)b * 256 * 768;
    for (int i = tid; i < 768; i += 256) os[i] = __bfloat162float(orow[i]);
    __syncthreads();

    const int n = ng * 32 + (tid >> 3);
    const int seg = tid & 7;
    const float* wrow = Wo5 + (long)n * 768 + seg * 96;
    const float* xs = &os[seg * 96];
    float s = 0.f;
#pragma unroll
    for (int k = 0; k < 96; k += 4) {
        const float4 w = *(const float4*)&wrow[k];
        s += xs[k] * w.x + xs[k + 1] * w.y + xs[k + 2] * w.z + xs[k + 3] * w.w;
    }
    s += __shfl_xor(s, 1);
    s += __shfl_xor(s, 2);
    s += __shfl_xor(s, 4);
    if (seg == 0) out[b * 768 + n] = s + bo5[n];
}

extern "C" void kernel_launch(void* const* d_in, const int* in_sizes, int n_in,
                              void* d_out, int out_size, void* d_ws, size_t ws_size,
                              hipStream_t stream)
{
    const int*   tokens   = (const int*)d_in[0];
    const float* embed    = (const float*)d_in[1];
    const float* pos_emb  = (const float*)d_in[2];
    const float* pos_q_w  = (const float*)d_in[3];
    const float* pos_q_b  = (const float*)d_in[4];
    const float* pos_k_w  = (const float*)d_in[5];
    const float* pos_k_b  = (const float*)d_in[6];
    const float* pos_ln_g = (const float*)d_in[7];
    const float* pos_ln_b = (const float*)d_in[8];
    const float* rel_tab  = (const float*)d_in[9];
    const int*   rp       = (const int*)d_in[10];
    const float* Wq = (const float*)d_in[11];
    const float* bq = (const float*)d_in[12];
    const float* Wk = (const float*)d_in[13];
    const float* bk = (const float*)d_in[14];
    const float* Wv = (const float*)d_in[15];
    const float* bv = (const float*)d_in[16];
    const float* Wo = (const float*)d_in[17];
    const float* bo = (const float*)d_in[18];
    float* out = (float*)d_out;

    char* p = (char*)d_ws;
    auto alloc = [&](size_t bytes) -> char* {
        char* r = p;
        p += (bytes + 255) & ~(size_t)255;
        return r;
    };
    const long NT = 32L * SEQ;  // 8192

    float* biasT = (float*)alloc(8L * SEQ * SEQ * 4);       // [h][j][i]
    float* wln   = (float*)alloc((long)SEQ * DIM * 4);
    float* pqk   = (float*)alloc(2L * SEQ * DIM * 4);       // pq | pk
    float* wsW   = (float*)alloc(2L * 768 * 768 * 4);       // posq_w | posk_w
    float* wsB   = (float*)alloc(2L * 768 * 4);
    bf16*  xb    = (bf16*) alloc(NT * DIM * 2);
    bf16*  qkv   = (bf16*) alloc(NT * 2304 * 2);
    bf16*  vT    = (bf16*) alloc(NT * DIM * 2);             // [32][768][256]
    bf16*  ob    = (bf16*) alloc(NT * DIM * 2);
    bf16*  wqkv  = (bf16*) alloc(6L * 2304 * 768 * 2);
    bf16*  woT   = (bf16*) alloc(6L * 768 * 768 * 2);
    bf16*  wf    = (bf16*) alloc(5L * 2304 * 768 * 2);
    float* bqkv  = (float*)alloc(6L * 2304 * 4);
    float* bfus  = (float*)alloc(5L * 2304 * 4);

    const float SCALE = 0.07216878364870322f;   // (HD*2)^-0.5

    // ---- all independent setup in ONE launch ----
    setup_mega_kernel<<<RB_G, 256, 0, stream>>>(
        tokens, embed, pos_emb, pos_q_w, pos_q_b, pos_k_w, pos_k_b,
        pos_ln_g, pos_ln_b, Wq, Wk, Wv, Wo, bq, bk, bv,
        wqkv, woT, bqkv, xb, wln, wsW, wsB, SCALE);

    // Wf_l = Wqkv_{l+1} . Wo_l  (batched, z = l)
    gemm_bf16_kernel<<<dim3(6, 18, 5), 256, 0, stream>>>(
        wqkv + 2304L * 768, woT, nullptr, wf, nullptr, 768, 768, 0,
        2304L * 768, 768L * 768, 2304L * 768, 0);
    fused_bias_kernel<<<dim3(72, 5), 256, 0, stream>>>(wqkv, bo, bqkv, bfus);

    // pos projections pq|pk in one batched launch (z = 0: q, 1: k; scale folded later)
    gemm_kernel<<<dim3(12, 4, 2), 256, 0, stream>>>(
        wln, DIM, 0, wsW, DIM, 768L * 768, wsB, 768,
        pqk, DIM, (long)SEQ * DIM, SEQ, DIM, DIM, 1.0f, nullptr, nullptr);
    // biasT[h][j][i] = SCALE * (pk_j . pq_i) + rel[i,j,h]   (A=pk, W=pq)
    gemm_kernel<<<dim3(4, 4, NH), 256, 0, stream>>>(
        pqk + (long)SEQ * DIM, DIM, HD, pqk, DIM, HD, nullptr, 0,
        biasT, SEQ, (long)SEQ * SEQ, SEQ, SEQ, HD, SCALE, rp, rel_tab);

    // ---- layer pipeline ----
    gemm_bf16_kernel<<<dim3(18, 64, 1), 256, 0, stream>>>(xb, wqkv, bqkv, qkv, vT, 2304, 768, 1, 0, 0, 0, 0);
    for (int l = 0; l < 5; l++) {
        attn_mfma_kernel<<<1024, 256, 0, stream>>>(qkv, vT, biasT, ob);
        gemm_bf16_kernel<<<dim3(18, 64, 1), 256, 0, stream>>>(
            ob, wf + (long)l * 2304 * 768, bfus + (long)l * 2304, qkv, vT, 2304, 768, 1, 0, 0, 0,
            (l == 4) ? 1 : 0);
    }
    attn_mfma_kernel<<<256, 64, 0, stream>>>(qkv, vT, biasT, ob);   // it=0, rows 0..15
    final_out_kernel<<<dim3(24, 32), 256, 0, stream>>>(ob, Wo + 5L * 768 * 768, bo + 5L * 768, out);
}

// Round 9
// 711.991 us; speedup vs baseline: 1.6045x; 1.1906x over previous
//
#include <hip/hip_runtime.h>
#include <hip/hip_bf16.h>
#include <math.h>

constexpr int SEQ = 256;
constexpr int DIM = 768;
constexpr int NH  = 8;
constexpr int HD  = 96;

typedef __attribute__((ext_vector_type(8))) short short8;
typedef __attribute__((ext_vector_type(4))) float f32x4;
using bf16 = __hip_bfloat16;

#define ASYNC_COPY16(gptr, lptr) \
  __builtin_amdgcn_global_load_lds((const __attribute__((address_space(1))) void*)(gptr), \
                                   (__attribute__((address_space(3))) void*)(lptr), 16, 0, 0)

// ---------------------------------------------------------------------------
// f32 tiled GEMM: C[m,n] = (sum_k A[m,k]*W[n,k] + bias[n]) * scale  (+ rel)
// rtab != null: C[m,n] = acc*scale + rtab[rp[n*256+m]*8 + blockIdx.z]
// ---------------------------------------------------------------------------
__global__ __launch_bounds__(256) void gemm_kernel(
    const float* __restrict__ A, int lda, long aoz,
    const float* __restrict__ W, int ldw, long woz,
    const float* __restrict__ bias, long boz,
    float* __restrict__ C, int ldc, long coz,
    int M, int N, int K, float scale,
    const int* __restrict__ rp, const float* __restrict__ rtab)
{
    const int hz = blockIdx.z;
    A += (long)hz * aoz;
    W += (long)hz * woz;
    if (bias) bias += (long)hz * boz;
    C += (long)hz * coz;

    __shared__ float As[16][68];
    __shared__ float Ws[16][68];

    const int bm = blockIdx.y * 64;
    const int bn = blockIdx.x * 64;
    const int tid = threadIdx.x;
    const int tx = tid & 15;
    const int ty = tid >> 4;

    float acc[4][4] = {};

    for (int k0 = 0; k0 < K; k0 += 16) {
#pragma unroll
        for (int i = 0; i < 4; i++) {
            int idx = tid + i * 256;
            int r = idx >> 4, c = idx & 15;
            As[c][r] = A[(long)(bm + r) * lda + (k0 + c)];
            Ws[c][r] = W[(long)(bn + r) * ldw + (k0 + c)];
        }
        __syncthreads();
#pragma unroll
        for (int kk = 0; kk < 16; kk++) {
            const float4 a = *(const float4*)&As[kk][ty * 4];
            const float4 w = *(const float4*)&Ws[kk][tx * 4];
            acc[0][0] += a.x * w.x; acc[0][1] += a.x * w.y; acc[0][2] += a.x * w.z; acc[0][3] += a.x * w.w;
            acc[1][0] += a.y * w.x; acc[1][1] += a.y * w.y; acc[1][2] += a.y * w.z; acc[1][3] += a.y * w.w;
            acc[2][0] += a.z * w.x; acc[2][1] += a.z * w.y; acc[2][2] += a.z * w.z; acc[2][3] += a.z * w.w;
            acc[3][0] += a.w * w.x; acc[3][1] += a.w * w.y; acc[3][2] += a.w * w.z; acc[3][3] += a.w * w.w;
        }
        __syncthreads();
    }

    const int n0 = bn + tx * 4;
    float4 bv = make_float4(0.f, 0.f, 0.f, 0.f);
    if (bias) bv = *(const float4*)&bias[n0];
#pragma unroll
    for (int i = 0; i < 4; i++) {
        const int m = bm + ty * 4 + i;
        float4 r;
        if (rtab) {
            r.x = acc[i][0] * scale + rtab[rp[(n0 + 0) * 256 + m] * 8 + hz];
            r.y = acc[i][1] * scale + rtab[rp[(n0 + 1) * 256 + m] * 8 + hz];
            r.z = acc[i][2] * scale + rtab[rp[(n0 + 2) * 256 + m] * 8 + hz];
            r.w = acc[i][3] * scale + rtab[rp[(n0 + 3) * 256 + m] * 8 + hz];
        } else {
            r.x = (acc[i][0] + bv.x) * scale;
            r.y = (acc[i][1] + bv.y) * scale;
            r.z = (acc[i][2] + bv.z) * scale;
            r.w = (acc[i][3] + bv.w) * scale;
        }
        *(float4*)&C[(long)m * ldc + n0] = r;
    }
}

// ---------------------------------------------------------------------------
// Setup mega-kernel (role by blockIdx ranges) — see R8.
// ---------------------------------------------------------------------------
constexpr int RB_A = 10368;
constexpr int RB_B = RB_A + 3456;
constexpr int RB_C = RB_B + 54;
constexpr int RB_D = RB_C + 8192;
constexpr int RB_E = RB_D + 256;
constexpr int RB_F = RB_E + 1152;
constexpr int RB_G = RB_F + 2;

__global__ __launch_bounds__(256) void setup_mega_kernel(
    const int* __restrict__ tokens, const float* __restrict__ embed,
    const float* __restrict__ pos_emb,
    const float* __restrict__ pos_q_w, const float* __restrict__ pos_q_b,
    const float* __restrict__ pos_k_w, const float* __restrict__ pos_k_b,
    const float* __restrict__ pos_ln_g, const float* __restrict__ pos_ln_b,
    const float* __restrict__ Wq, const float* __restrict__ Wk,
    const float* __restrict__ Wv, const float* __restrict__ Wo,
    const float* __restrict__ bq, const float* __restrict__ bk,
    const float* __restrict__ bv,
    bf16* __restrict__ wqkv, bf16* __restrict__ woT, float* __restrict__ bqkv,
    bf16* __restrict__ xb, float* __restrict__ wln,
    float* __restrict__ wsW, float* __restrict__ wsB, float scale)
{
    const int bid = blockIdx.x, tid = threadIdx.x;

    if (bid < RB_A) {
        const long idx = (long)bid * 256 + tid;
        const long e = idx * 4;
        const int k = (int)(e % 768);
        const long nl = e / 768;
        const int n = (int)(nl % 2304);
        const int l = (int)(nl / 2304);
        const float* src;
        float sc = 1.f;
        if (n < 768)       { src = Wq + ((long)l * 768 + n) * 768; sc = scale; }
        else if (n < 1536) { src = Wk + ((long)l * 768 + (n - 768)) * 768; }
        else               { src = Wv + ((long)l * 768 + (n - 1536)) * 768; }
        const float4 v = *(const float4*)&src[k];
        bf16 tmp[4];
        tmp[0] = __float2bfloat16(v.x * sc);
        tmp[1] = __float2bfloat16(v.y * sc);
        tmp[2] = __float2bfloat16(v.z * sc);
        tmp[3] = __float2bfloat16(v.w * sc);
        *(uint2*)&wqkv[((long)l * 2304 + n) * 768 + k] = *(uint2*)tmp;
    } else if (bid < RB_B) {
        __shared__ float t[32][33];
        const int b2 = bid - RB_A;
        const int l = b2 / 576, r2 = b2 % 576;
        const int c0 = (r2 % 24) * 32, j0 = (r2 / 24) * 32;
        const int tx = tid & 31, ty = tid >> 5;
        const float* src = Wo + (long)l * 768 * 768;
#pragma unroll
        for (int rr = 0; rr < 32; rr += 8)
            t[ty + rr][tx] = src[(long)(c0 + ty + rr) * 768 + j0 + tx];
        __syncthreads();
        bf16* dst = woT + (long)l * 768 * 768;
#pragma unroll
        for (int rr = 0; rr < 32; rr += 8)
            dst[(long)(j0 + ty + rr) * 768 + c0 + tx] = __float2bfloat16(t[tx][ty + rr]);
    } else if (bid < RB_C) {
        const int idx = (bid - RB_B) * 256 + tid;
        if (idx < 6 * 2304) {
            const int n = idx % 2304, l = idx / 2304;
            float v;
            if (n < 768)       v = bq[l * 768 + n] * scale;
            else if (n < 1536) v = bk[l * 768 + (n - 768)];
            else               v = bv[l * 768 + (n - 1536)];
            bqkv[idx] = v;
        }
    } else if (bid < RB_D) {
        if (tid < 192) {
            const int t = bid - RB_C;
            const int tok = tokens[t];
            const float4 v = ((const float4*)(embed + (long)tok * DIM))[tid];
            bf16 tmp[4];
            tmp[0] = __float2bfloat16(v.x);
            tmp[1] = __float2bfloat16(v.y);
            tmp[2] = __float2bfloat16(v.z);
            tmp[3] = __float2bfloat16(v.w);
            *(uint2*)&xb[(long)t * DIM + tid * 4] = *(uint2*)tmp;
        }
    } else if (bid < RB_E) {
        __shared__ float buf[256];
        const int i = bid - RB_D;
        const float* row = pos_emb + (long)i * DIM;
        float v0 = row[tid], v1 = row[tid + 256], v2 = row[tid + 512];
        buf[tid] = v0 + v1 + v2;
        __syncthreads();
        for (int off = 128; off > 0; off >>= 1) {
            if (tid < off) buf[tid] += buf[tid + off];
            __syncthreads();
        }
        const float mean = buf[0] * (1.f / 768.f);
        __syncthreads();
        const float d0 = v0 - mean, d1 = v1 - mean, d2 = v2 - mean;
        buf[tid] = d0 * d0 + d1 * d1 + d2 * d2;
        __syncthreads();
        for (int off = 128; off > 0; off >>= 1) {
            if (tid < off) buf[tid] += buf[tid + off];
            __syncthreads();
        }
        const float rstd = rsqrtf(buf[0] * (1.f / 768.f) + 1e-5f);
        float* wr = wln + (long)i * DIM;
        wr[tid]       = d0 * rstd * pos_ln_g[tid]       + pos_ln_b[tid];
        wr[tid + 256] = d1 * rstd * pos_ln_g[tid + 256] + pos_ln_b[tid + 256];
        wr[tid + 512] = d2 * rstd * pos_ln_g[tid + 512] + pos_ln_b[tid + 512];
    } else if (bid < RB_F) {
        const long idx = (long)(bid - RB_E) * 256 + tid;
        const long e = idx * 4;
        const float4 v = (e < 589824) ? *(const float4*)&pos_q_w[e]
                                      : *(const float4*)&pos_k_w[e - 589824];
        *(float4*)&wsW[e] = v;
    } else {
        const int idx = (bid - RB_F) * 256 + tid;
        wsB[idx] = (idx < 768) ? pos_q_b[idx] : pos_k_b[idx - 768];
    }
}

// bf[l][n] = wqkv[l+1][n,:] . bo[l] + bqkv[l+1][n]   (l = 0..4)
__global__ __launch_bounds__(256) void fused_bias_kernel(
    const bf16* __restrict__ wqkv, const float* __restrict__ bo,
    const float* __restrict__ bqkv, float* __restrict__ bf_)
{
    const int l = blockIdx.y;
    const int lane = threadIdx.x & 63, wave = threadIdx.x >> 6;
    const int nloc = wave * 8 + (lane >> 3);
    const int seg = lane & 7;
    const int n = blockIdx.x * 32 + nloc;
    const bf16* wrow = wqkv + ((long)(l + 1) * 2304 + n) * 768 + seg * 96;
    const float* bsrc = bo + (long)l * 768 + seg * 96;
    float s = 0.f;
#pragma unroll
    for (int c8 = 0; c8 < 12; c8++) {
        const short8 w8 = *(const short8*)&wrow[c8 * 8];
#pragma unroll
        for (int e = 0; e < 8; e++) {
            bf16 b;
            *(short*)&b = w8[e];
            s += __bfloat162float(b) * bsrc[c8 * 8 + e];
        }
    }
    s += __shfl_xor(s, 1);
    s += __shfl_xor(s, 2);
    s += __shfl_xor(s, 4);
    if (seg == 0) bf_[l * 2304 + n] = s + bqkv[(l + 1) * 2304 + n];
}

// ---------------------------------------------------------------------------
// bf16 MFMA GEMM: 128x128 tile, BK=64, ping-pong double-buffered LDS.
// ---------------------------------------------------------------------------
#define GEMM_PREF(AS, BS, KB)                                                 \
  {                                                                           \
    _Pragma("unroll")                                                         \
    for (int i = 0; i < 4; i++) {                                             \
      const int u = tid + i * 256;                                            \
      const int r = u >> 3, c = u & 7;                                        \
      const int ca = c ^ (r & 7);                                             \
      ASYNC_COPY16(A + (bm + r) * (long)K + (KB) + ca * 8, &AS[u * 8]);       \
      ASYNC_COPY16(B + (bn + r) * (long)K + (KB) + ca * 8, &BS[u * 8]);       \
    }                                                                         \
  }

#define GEMM_COMPUTE(AS, BS)                                                  \
  {                                                                           \
    _Pragma("unroll")                                                         \
    for (int ks = 0; ks < 2; ks++) {                                          \
      const int cc = ks * 4 + quad;                                           \
      short8 af[4], bfr[4];                                                   \
      _Pragma("unroll")                                                       \
      for (int t = 0; t < 4; t++) {                                           \
        const int ra = wm * 64 + t * 16 + col;                                \
        const int rb = wn * 64 + t * 16 + col;                                \
        af[t]  = *(const short8*)&AS[ra * 64 + ((cc ^ (ra & 7)) * 8)];        \
        bfr[t] = *(const short8*)&BS[rb * 64 + ((cc ^ (rb & 7)) * 8)];        \
      }                                                                       \
      _Pragma("unroll")                                                       \
      for (int tm = 0; tm < 4; tm++)                                          \
        _Pragma("unroll")                                                     \
        for (int tn = 0; tn < 4; tn++)                                        \
          acc[tm][tn] = __builtin_amdgcn_mfma_f32_16x16x32_bf16(af[tm], bfr[tn], acc[tm][tn], 0, 0, 0); \
    }                                                                         \
  }

__global__ __launch_bounds__(256) void gemm_bf16_kernel(
    const bf16* __restrict__ A, const bf16* __restrict__ B,
    const float* __restrict__ bias,
    bf16* __restrict__ Cb, bf16* __restrict__ vTout,
    int N, int K, int swz, long az, long bz, long cz, int skipQ)
{
    __shared__ bf16 As0[128 * 64];
    __shared__ bf16 Bs0[128 * 64];
    __shared__ bf16 As1[128 * 64];
    __shared__ bf16 Bs1[128 * 64];

    A += (long)blockIdx.z * az;
    B += (long)blockIdx.z * bz;
    if (Cb) Cb += (long)blockIdx.z * cz;

    const int tid = threadIdx.x;
    const int lane = tid & 63, wave = tid >> 6;
    const int wm = wave & 1, wn = wave >> 1;

    int bmt, bnt;
    if (swz) {
        const int id = blockIdx.x + gridDim.x * blockIdx.y;
        const int xcd = id & 7, loc = id >> 3;
        bmt = xcd * 8 + (loc & 7);
        bnt = loc >> 3;
    } else {
        bmt = blockIdx.y;
        bnt = blockIdx.x;
    }
    if (skipQ && bnt < 6 && (bmt & 1)) return;

    const long bm = (long)bmt * 128, bn = (long)bnt * 128;
    const int col = lane & 15, quad = lane >> 4;

    f32x4 acc[4][4] = {};

    GEMM_PREF(As0, Bs0, 0);
    for (int kk = 0; kk < K; kk += 128) {
        __syncthreads();
        GEMM_PREF(As1, Bs1, kk + 64);
        GEMM_COMPUTE(As0, Bs0);
        __syncthreads();
        if (kk + 128 < K) GEMM_PREF(As0, Bs0, kk + 128);
        GEMM_COMPUTE(As1, Bs1);
    }

    const bool toVT = (vTout != nullptr) && (bn >= 1536);

    if (toVT) {
        __syncthreads();
        bf16* tb = (wave < 2 ? As0 : Bs0) + (wave & 1) * 4096;
#pragma unroll
        for (int tn = 0; tn < 4; tn++) {
            const int nl = tn * 16 + col;
            const float bvv = bias[bn + wn * 64 + nl];
#pragma unroll
            for (int tm = 0; tm < 4; tm++) {
                const int mc = tm * 4 + quad;
                bf16 t4[4];
#pragma unroll
                for (int r = 0; r < 4; r++)
                    t4[r] = __float2bfloat16(acc[tm][tn][r] + bvv);
                *(uint2*)&tb[(nl * 16 + (mc ^ (nl & 15))) * 4] = *(uint2*)t4;
            }
        }
        const int b_  = (int)((bm + wm * 64) >> 8);
        const int s0  = (int)((bm + wm * 64) & 255);
        const long nb = bn + wn * 64 - 1536;
#pragma unroll
        for (int it2 = 0; it2 < 16; it2++) {
            const int nl = it2 * 4 + quad;
            const uint2 v = *(const uint2*)&tb[(nl * 16 + (col ^ (nl & 15))) * 4];
            *(uint2*)&vTout[((long)b_ * 768 + nb + nl) * 256 + s0 + col * 4] = v;
        }
    } else {
#pragma unroll
        for (int tn = 0; tn < 4; tn++) {
            const long n = bn + wn * 64 + tn * 16 + col;
            const float bvv = bias ? bias[n] : 0.f;
#pragma unroll
            for (int tm = 0; tm < 4; tm++) {
                const long m0 = bm + wm * 64 + tm * 16 + quad * 4;
#pragma unroll
                for (int r = 0; r < 4; r++)
                    Cb[(m0 + r) * N + n] = __float2bfloat16(acc[tm][tn][r] + bvv);
            }
        }
    }
}

// ---------------------------------------------------------------------------
// MFMA attention with LDS-staged K/V (global_load_lds + XOR chunk swizzle).
// Block per (it, h, b), 256 threads. Q in regs; K chunk: 64 rows x 16-chunk
// alloc (12 valid), p = c ^ (r&15); V chunk: 96 rows x 8 chunks, p = c^(r&7).
// Both layouts: 2-way bank aliasing (free). Ps (bf16, stride 264) for the
// C->A layout transform. biasT[h][j][i] read as float4 (L2-resident).
// ---------------------------------------------------------------------------
__global__ __launch_bounds__(256) void attn_mfma_kernel(
    const bf16* __restrict__ qkv, const bf16* __restrict__ vT,
    const float* __restrict__ biasT, bf16* __restrict__ o)
{
    constexpr int PS = 264;
    __shared__ bf16 Ps[64 * PS];      // 33.8 KB
    __shared__ bf16 KVs[64 * 128];    // 16 KB; V phase uses 96*64 = 12 KB

    const int blk = blockIdx.x;
    const int b  = blk & 31;
    const int h  = (blk >> 5) & 7;
    const int it = blk >> 8;
    const int i0 = it * 64;
    const int tid = threadIdx.x, lane = tid & 63, wave = tid >> 6;
    const int col = lane & 15, quad = lane >> 4;
    const long rowbase = (long)b * SEQ;

    // Q fragments (A-operand layout), direct from global
    short8 aq[3];
    {
        const bf16* qrow = qkv + (rowbase + i0 + wave * 16 + col) * 2304 + h * 96;
#pragma unroll
        for (int ks = 0; ks < 3; ks++)
            aq[ks] = *(const short8*)&qrow[ks * 32 + quad * 8];
    }

    // ---- scores: K staged per 64-j chunk ----
    f32x4 accS[16];
    for (int jc = 0; jc < 4; jc++) {
        __syncthreads();
#pragma unroll
        for (int i = 0; i < 4; i++) {
            const int u = tid + i * 256;          // 0..1023
            const int r = u >> 4, p = u & 15;
            const int c = p ^ (r & 15);           // global 16B chunk (0..15; >=12 fetch junk, in-bounds)
            ASYNC_COPY16(qkv + (rowbase + jc * 64 + r) * 2304 + 768 + h * 96 + c * 8, &KVs[u * 8]);
        }
        __syncthreads();
#pragma unroll
        for (int ks = 0; ks < 3; ks++) {
#pragma unroll
            for (int jt2 = 0; jt2 < 4; jt2++) {
                const int row = jt2 * 16 + col;
                const int c = ks * 4 + quad;
                const short8 bk_ = *(const short8*)&KVs[row * 128 + ((c ^ (row & 15)) * 8)];
                f32x4 a0 = (jc == 0 && ks == 0) ? f32x4{0.f, 0.f, 0.f, 0.f} : accS[jc * 4 + jt2];
                accS[jc * 4 + jt2] = __builtin_amdgcn_mfma_f32_16x16x32_bf16(aq[ks], bk_, a0, 0, 0, 0);
            }
        }
    }

    // ---- bias (biasT[h][j][i], float4 per lane) + softmax ----
    const float* bbT = biasT + (long)h * SEQ * SEQ + i0 + wave * 16 + quad * 4;
#pragma unroll
    for (int jt = 0; jt < 16; jt++) {
        const float4 bv4 = *(const float4*)&bbT[(jt * 16 + col) * SEQ];
        accS[jt][0] += bv4.x;
        accS[jt][1] += bv4.y;
        accS[jt][2] += bv4.z;
        accS[jt][3] += bv4.w;
    }

#pragma unroll
    for (int r = 0; r < 4; r++) {
        float m = accS[0][r];
#pragma unroll
        for (int jt = 1; jt < 16; jt++) m = fmaxf(m, accS[jt][r]);
        for (int d = 1; d < 16; d <<= 1) m = fmaxf(m, __shfl_xor(m, d));
        float s = 0.f;
#pragma unroll
        for (int jt = 0; jt < 16; jt++) {
            const float e = __expf(accS[jt][r] - m);
            accS[jt][r] = e;
            s += e;
        }
        for (int d = 1; d < 16; d <<= 1) s += __shfl_xor(s, d);
        const float inv = 1.f / s;
        const int prow = wave * 16 + quad * 4 + r;
#pragma unroll
        for (int jt = 0; jt < 16; jt++)
            Ps[prow * PS + jt * 16 + col] = __float2bfloat16(accS[jt][r] * inv);
    }
    // no barrier for Ps: each wave reads only the rows it wrote (in-order LDS)

    // ---- O = P.V : V staged per 64-j chunk from vT[b][h*96+d][s] ----
    f32x4 accO[6] = {};
    const bf16* vbase = vT + ((long)b * 768 + h * 96) * 256;
    for (int kc = 0; kc < 4; kc++) {
        __syncthreads();   // K reads / prior V reads done
#pragma unroll
        for (int i = 0; i < 3; i++) {
            const int u = tid + i * 256;          // 0..767
            const int r = u >> 3, p = u & 7;      // r = d row (0..95)
            const int c = p ^ (r & 7);
            ASYNC_COPY16(vbase + r * 256 + kc * 64 + c * 8, &KVs[u * 8]);
        }
        __syncthreads();
#pragma unroll
        for (int k2 = 0; k2 < 2; k2++) {
            const short8 ap = *(const short8*)&Ps[(wave * 16 + col) * PS + kc * 64 + k2 * 32 + quad * 8];
#pragma unroll
            for (int nt = 0; nt < 6; nt++) {
                const int row = nt * 16 + col;
                const int c = k2 * 4 + quad;
                const short8 bv_ = *(const short8*)&KVs[row * 64 + ((c ^ (row & 7)) * 8)];
                accO[nt] = __builtin_amdgcn_mfma_f32_16x16x32_bf16(ap, bv_, accO[nt], 0, 0, 0);
            }
        }
    }

#pragma unroll
    for (int nt = 0; nt < 6; nt++)
#pragma unroll
        for (int r = 0; r < 4; r++) {
            const long m = rowbase + i0 + wave * 16 + quad * 4 + r;
            o[m * DIM + h * 96 + nt * 16 + col] = __float2bfloat16(accO[nt][r]);
        }
}

// out[b, ng*32 + tid>>3] = ob[b*256,:] . Wo5[n,:] + bo5[n]
__global__ __launch_bounds__(256) void final_out_kernel(
    const bf16* __restrict__ ob, const float* __restrict__ Wo5,
    const float* __restrict__ bo5, float* __restrict__ out)
{
    __shared__ float os[768];
    const int b = blockIdx.y, ng = blockIdx.x, tid = threadIdx.x;
    const bf16* orow = ob + (long)b * 256 * 768;
    for (int i = tid; i < 768; i += 256) os[i] = __bfloat162float(orow[i]);
    __syncthreads();

    const int n = ng * 32 + (tid >> 3);
    const int seg = tid & 7;
    const float* wrow = Wo5 + (long)n * 768 + seg * 96;
    const float* xs = &os[seg * 96];
    float s = 0.f;
#pragma unroll
    for (int k = 0; k < 96; k += 4) {
        const float4 w = *(const float4*)&wrow[k];
        s += xs[k] * w.x + xs[k + 1] * w.y + xs[k + 2] * w.z + xs[k + 3] * w.w;
    }
    s += __shfl_xor(s, 1);
    s += __shfl_xor(s, 2);
    s += __shfl_xor(s, 4);
    if (seg == 0) out[b * 768 + n] = s + bo5[n];
}

extern "C" void kernel_launch(void* const* d_in, const int* in_sizes, int n_in,
                              void* d_out, int out_size, void* d_ws, size_t ws_size,
                              hipStream_t stream)
{
    const int*   tokens   = (const int*)d_in[0];
    const float* embed    = (const float*)d_in[1];
    const float* pos_emb  = (const float*)d_in[2];
    const float* pos_q_w  = (const float*)d_in[3];
    const float* pos_q_b  = (const float*)d_in[4];
    const float* pos_k_w  = (const float*)d_in[5];
    const float* pos_k_b  = (const float*)d_in[6];
    const float* pos_ln_g = (const float*)d_in[7];
    const float* pos_ln_b = (const float*)d_in[8];
    const float* rel_tab  = (const float*)d_in[9];
    const int*   rp       = (const int*)d_in[10];
    const float* Wq = (const float*)d_in[11];
    const float* bq = (const float*)d_in[12];
    const float* Wk = (const float*)d_in[13];
    const float* bk = (const float*)d_in[14];
    const float* Wv = (const float*)d_in[15];
    const float* bv = (const float*)d_in[16];
    const float* Wo = (const float*)d_in[17];
    const float* bo = (const float*)d_in[18];
    float* out = (float*)d_out;

    char* p = (char*)d_ws;
    auto alloc = [&](size_t bytes) -> char* {
        char* r = p;
        p += (bytes + 255) & ~(size_t)255;
        return r;
    };
    const long NT = 32L * SEQ;  // 8192

    float* biasT = (float*)alloc(8L * SEQ * SEQ * 4);       // [h][j][i]
    float* wln   = (float*)alloc((long)SEQ * DIM * 4);
    float* pqk   = (float*)alloc(2L * SEQ * DIM * 4);       // pq | pk
    float* wsW   = (float*)alloc(2L * 768 * 768 * 4);       // posq_w | posk_w
    float* wsB   = (float*)alloc(2L * 768 * 4);
    bf16*  xb    = (bf16*) alloc(NT * DIM * 2);
    bf16*  qkv   = (bf16*) alloc(NT * 2304 * 2);
    bf16*  vT    = (bf16*) alloc(NT * DIM * 2);             // [32][768][256]
    bf16*  ob    = (bf16*) alloc(NT * DIM * 2);
    bf16*  wqkv  = (bf16*) alloc(6L * 2304 * 768 * 2);
    bf16*  woT   = (bf16*) alloc(6L * 768 * 768 * 2);
    bf16*  wf    = (bf16*) alloc(5L * 2304 * 768 * 2);
    float* bqkv  = (float*)alloc(6L * 2304 * 4);
    float* bfus  = (float*)alloc(5L * 2304 * 4);

    const float SCALE = 0.07216878364870322f;   // (HD*2)^-0.5

    // ---- all independent setup in ONE launch ----
    setup_mega_kernel<<<RB_G, 256, 0, stream>>>(
        tokens, embed, pos_emb, pos_q_w, pos_q_b, pos_k_w, pos_k_b,
        pos_ln_g, pos_ln_b, Wq, Wk, Wv, Wo, bq, bk, bv,
        wqkv, woT, bqkv, xb, wln, wsW, wsB, SCALE);

    // Wf_l = Wqkv_{l+1} . Wo_l  (batched, z = l)
    gemm_bf16_kernel<<<dim3(6, 18, 5), 256, 0, stream>>>(
        wqkv + 2304L * 768, woT, nullptr, wf, nullptr, 768, 768, 0,
        2304L * 768, 768L * 768, 2304L * 768, 0);
    fused_bias_kernel<<<dim3(72, 5), 256, 0, stream>>>(wqkv, bo, bqkv, bfus);

    // pos projections pq|pk in one batched launch
    gemm_kernel<<<dim3(12, 4, 2), 256, 0, stream>>>(
        wln, DIM, 0, wsW, DIM, 768L * 768, wsB, 768,
        pqk, DIM, (long)SEQ * DIM, SEQ, DIM, DIM, 1.0f, nullptr, nullptr);
    // biasT[h][j][i] = SCALE * (pk_j . pq_i) + rel[i,j,h]
    gemm_kernel<<<dim3(4, 4, NH), 256, 0, stream>>>(
        pqk + (long)SEQ * DIM, DIM, HD, pqk, DIM, HD, nullptr, 0,
        biasT, SEQ, (long)SEQ * SEQ, SEQ, SEQ, HD, SCALE, rp, rel_tab);

    // ---- layer pipeline ----
    gemm_bf16_kernel<<<dim3(18, 64, 1), 256, 0, stream>>>(xb, wqkv, bqkv, qkv, vT, 2304, 768, 1, 0, 0, 0, 0);
    for (int l = 0; l < 5; l++) {
        attn_mfma_kernel<<<1024, 256, 0, stream>>>(qkv, vT, biasT, ob);
        gemm_bf16_kernel<<<dim3(18, 64, 1), 256, 0, stream>>>(
            ob, wf + (long)l * 2304 * 768, bfus + (long)l * 2304, qkv, vT, 2304, 768, 1, 0, 0, 0,
            (l == 4) ? 1 : 0);
    }
    attn_mfma_kernel<<<256, 256, 0, stream>>>(qkv, vT, biasT, ob);   // it=0 only
    final_out_kernel<<<dim3(24, 32), 256, 0, stream>>>(ob, Wo + 5L * 768 * 768, bo + 5L * 768, out);
}

// Round 10
// 701.458 us; speedup vs baseline: 1.6286x; 1.0150x over previous
//
#include <hip/hip_runtime.h>
#include <hip/hip_bf16.h>
#include <math.h>

constexpr int SEQ = 256;
constexpr int DIM = 768;
constexpr int NH  = 8;
constexpr int HD  = 96;

typedef __attribute__((ext_vector_type(8))) short short8;
typedef __attribute__((ext_vector_type(4))) float f32x4;
using bf16 = __hip_bfloat16;

#define ASYNC_COPY16(gptr, lptr) \
  __builtin_amdgcn_global_load_lds((const __attribute__((address_space(1))) void*)(gptr), \
                                   (__attribute__((address_space(3))) void*)(lptr), 16, 0, 0)

// ---------------------------------------------------------------------------
// f32 tiled GEMM: C[m,n] = (sum_k A[m,k]*W[n,k] + bias[n]) * scale  (+ rel)
// rtab != null: C[m,n] = acc*scale + rtab[rp[n*256+m]*8 + blockIdx.z]
// ---------------------------------------------------------------------------
__global__ __launch_bounds__(256) void gemm_kernel(
    const float* __restrict__ A, int lda, long aoz,
    const float* __restrict__ W, int ldw, long woz,
    const float* __restrict__ bias, long boz,
    float* __restrict__ C, int ldc, long coz,
    int M, int N, int K, float scale,
    const int* __restrict__ rp, const float* __restrict__ rtab)
{
    const int hz = blockIdx.z;
    A += (long)hz * aoz;
    W += (long)hz * woz;
    if (bias) bias += (long)hz * boz;
    C += (long)hz * coz;

    __shared__ float As[16][68];
    __shared__ float Ws[16][68];

    const int bm = blockIdx.y * 64;
    const int bn = blockIdx.x * 64;
    const int tid = threadIdx.x;
    const int tx = tid & 15;
    const int ty = tid >> 4;

    float acc[4][4] = {};

    for (int k0 = 0; k0 < K; k0 += 16) {
#pragma unroll
        for (int i = 0; i < 4; i++) {
            int idx = tid + i * 256;
            int r = idx >> 4, c = idx & 15;
            As[c][r] = A[(long)(bm + r) * lda + (k0 + c)];
            Ws[c][r] = W[(long)(bn + r) * ldw + (k0 + c)];
        }
        __syncthreads();
#pragma unroll
        for (int kk = 0; kk < 16; kk++) {
            const float4 a = *(const float4*)&As[kk][ty * 4];
            const float4 w = *(const float4*)&Ws[kk][tx * 4];
            acc[0][0] += a.x * w.x; acc[0][1] += a.x * w.y; acc[0][2] += a.x * w.z; acc[0][3] += a.x * w.w;
            acc[1][0] += a.y * w.x; acc[1][1] += a.y * w.y; acc[1][2] += a.y * w.z; acc[1][3] += a.y * w.w;
            acc[2][0] += a.z * w.x; acc[2][1] += a.z * w.y; acc[2][2] += a.z * w.z; acc[2][3] += a.z * w.w;
            acc[3][0] += a.w * w.x; acc[3][1] += a.w * w.y; acc[3][2] += a.w * w.z; acc[3][3] += a.w * w.w;
        }
        __syncthreads();
    }

    const int n0 = bn + tx * 4;
    float4 bv = make_float4(0.f, 0.f, 0.f, 0.f);
    if (bias) bv = *(const float4*)&bias[n0];
#pragma unroll
    for (int i = 0; i < 4; i++) {
        const int m = bm + ty * 4 + i;
        float4 r;
        if (rtab) {
            r.x = acc[i][0] * scale + rtab[rp[(n0 + 0) * 256 + m] * 8 + hz];
            r.y = acc[i][1] * scale + rtab[rp[(n0 + 1) * 256 + m] * 8 + hz];
            r.z = acc[i][2] * scale + rtab[rp[(n0 + 2) * 256 + m] * 8 + hz];
            r.w = acc[i][3] * scale + rtab[rp[(n0 + 3) * 256 + m] * 8 + hz];
        } else {
            r.x = (acc[i][0] + bv.x) * scale;
            r.y = (acc[i][1] + bv.y) * scale;
            r.z = (acc[i][2] + bv.z) * scale;
            r.w = (acc[i][3] + bv.w) * scale;
        }
        *(float4*)&C[(long)m * ldc + n0] = r;
    }
}

// ---------------------------------------------------------------------------
// Setup mega-kernel (role by blockIdx ranges)
// ---------------------------------------------------------------------------
constexpr int RB_A = 10368;
constexpr int RB_B = RB_A + 3456;
constexpr int RB_C = RB_B + 54;
constexpr int RB_D = RB_C + 8192;
constexpr int RB_E = RB_D + 256;
constexpr int RB_F = RB_E + 1152;
constexpr int RB_G = RB_F + 2;

__global__ __launch_bounds__(256) void setup_mega_kernel(
    const int* __restrict__ tokens, const float* __restrict__ embed,
    const float* __restrict__ pos_emb,
    const float* __restrict__ pos_q_w, const float* __restrict__ pos_q_b,
    const float* __restrict__ pos_k_w, const float* __restrict__ pos_k_b,
    const float* __restrict__ pos_ln_g, const float* __restrict__ pos_ln_b,
    const float* __restrict__ Wq, const float* __restrict__ Wk,
    const float* __restrict__ Wv, const float* __restrict__ Wo,
    const float* __restrict__ bq, const float* __restrict__ bk,
    const float* __restrict__ bv,
    bf16* __restrict__ wqkv, bf16* __restrict__ woT, float* __restrict__ bqkv,
    bf16* __restrict__ xb, float* __restrict__ wln,
    float* __restrict__ wsW, float* __restrict__ wsB, float scale)
{
    const int bid = blockIdx.x, tid = threadIdx.x;

    if (bid < RB_A) {
        const long idx = (long)bid * 256 + tid;
        const long e = idx * 4;
        const int k = (int)(e % 768);
        const long nl = e / 768;
        const int n = (int)(nl % 2304);
        const int l = (int)(nl / 2304);
        const float* src;
        float sc = 1.f;
        if (n < 768)       { src = Wq + ((long)l * 768 + n) * 768; sc = scale; }
        else if (n < 1536) { src = Wk + ((long)l * 768 + (n - 768)) * 768; }
        else               { src = Wv + ((long)l * 768 + (n - 1536)) * 768; }
        const float4 v = *(const float4*)&src[k];
        bf16 tmp[4];
        tmp[0] = __float2bfloat16(v.x * sc);
        tmp[1] = __float2bfloat16(v.y * sc);
        tmp[2] = __float2bfloat16(v.z * sc);
        tmp[3] = __float2bfloat16(v.w * sc);
        *(uint2*)&wqkv[((long)l * 2304 + n) * 768 + k] = *(uint2*)tmp;
    } else if (bid < RB_B) {
        __shared__ float t[32][33];
        const int b2 = bid - RB_A;
        const int l = b2 / 576, r2 = b2 % 576;
        const int c0 = (r2 % 24) * 32, j0 = (r2 / 24) * 32;
        const int tx = tid & 31, ty = tid >> 5;
        const float* src = Wo + (long)l * 768 * 768;
#pragma unroll
        for (int rr = 0; rr < 32; rr += 8)
            t[ty + rr][tx] = src[(long)(c0 + ty + rr) * 768 + j0 + tx];
        __syncthreads();
        bf16* dst = woT + (long)l * 768 * 768;
#pragma unroll
        for (int rr = 0; rr < 32; rr += 8)
            dst[(long)(j0 + ty + rr) * 768 + c0 + tx] = __float2bfloat16(t[tx][ty + rr]);
    } else if (bid < RB_C) {
        const int idx = (bid - RB_B) * 256 + tid;
        if (idx < 6 * 2304) {
            const int n = idx % 2304, l = idx / 2304;
            float v;
            if (n < 768)       v = bq[l * 768 + n] * scale;
            else if (n < 1536) v = bk[l * 768 + (n - 768)];
            else               v = bv[l * 768 + (n - 1536)];
            bqkv[idx] = v;
        }
    } else if (bid < RB_D) {
        if (tid < 192) {
            const int t = bid - RB_C;
            const int tok = tokens[t];
            const float4 v = ((const float4*)(embed + (long)tok * DIM))[tid];
            bf16 tmp[4];
            tmp[0] = __float2bfloat16(v.x);
            tmp[1] = __float2bfloat16(v.y);
            tmp[2] = __float2bfloat16(v.z);
            tmp[3] = __float2bfloat16(v.w);
            *(uint2*)&xb[(long)t * DIM + tid * 4] = *(uint2*)tmp;
        }
    } else if (bid < RB_E) {
        __shared__ float buf[256];
        const int i = bid - RB_D;
        const float* row = pos_emb + (long)i * DIM;
        float v0 = row[tid], v1 = row[tid + 256], v2 = row[tid + 512];
        buf[tid] = v0 + v1 + v2;
        __syncthreads();
        for (int off = 128; off > 0; off >>= 1) {
            if (tid < off) buf[tid] += buf[tid + off];
            __syncthreads();
        }
        const float mean = buf[0] * (1.f / 768.f);
        __syncthreads();
        const float d0 = v0 - mean, d1 = v1 - mean, d2 = v2 - mean;
        buf[tid] = d0 * d0 + d1 * d1 + d2 * d2;
        __syncthreads();
        for (int off = 128; off > 0; off >>= 1) {
            if (tid < off) buf[tid] += buf[tid + off];
            __syncthreads();
        }
        const float rstd = rsqrtf(buf[0] * (1.f / 768.f) + 1e-5f);
        float* wr = wln + (long)i * DIM;
        wr[tid]       = d0 * rstd * pos_ln_g[tid]       + pos_ln_b[tid];
        wr[tid + 256] = d1 * rstd * pos_ln_g[tid + 256] + pos_ln_b[tid + 256];
        wr[tid + 512] = d2 * rstd * pos_ln_g[tid + 512] + pos_ln_b[tid + 512];
    } else if (bid < RB_F) {
        const long idx = (long)(bid - RB_E) * 256 + tid;
        const long e = idx * 4;
        const float4 v = (e < 589824) ? *(const float4*)&pos_q_w[e]
                                      : *(const float4*)&pos_k_w[e - 589824];
        *(float4*)&wsW[e] = v;
    } else {
        const int idx = (bid - RB_F) * 256 + tid;
        wsB[idx] = (idx < 768) ? pos_q_b[idx] : pos_k_b[idx - 768];
    }
}

// bf[l][n] = wqkv[l+1][n,:] . bo[l] + bqkv[l+1][n]   (l = 0..4)
__global__ __launch_bounds__(256) void fused_bias_kernel(
    const bf16* __restrict__ wqkv, const float* __restrict__ bo,
    const float* __restrict__ bqkv, float* __restrict__ bf_)
{
    const int l = blockIdx.y;
    const int lane = threadIdx.x & 63, wave = threadIdx.x >> 6;
    const int nloc = wave * 8 + (lane >> 3);
    const int seg = lane & 7;
    const int n = blockIdx.x * 32 + nloc;
    const bf16* wrow = wqkv + ((long)(l + 1) * 2304 + n) * 768 + seg * 96;
    const float* bsrc = bo + (long)l * 768 + seg * 96;
    float s = 0.f;
#pragma unroll
    for (int c8 = 0; c8 < 12; c8++) {
        const short8 w8 = *(const short8*)&wrow[c8 * 8];
#pragma unroll
        for (int e = 0; e < 8; e++) {
            bf16 b;
            *(short*)&b = w8[e];
            s += __bfloat162float(b) * bsrc[c8 * 8 + e];
        }
    }
    s += __shfl_xor(s, 1);
    s += __shfl_xor(s, 2);
    s += __shfl_xor(s, 4);
    if (seg == 0) bf_[l * 2304 + n] = s + bqkv[(l + 1) * 2304 + n];
}

// ---------------------------------------------------------------------------
// bf16 MFMA GEMM: 128x128 tile, BK=64, ping-pong double-buffered LDS.
// ---------------------------------------------------------------------------
#define GEMM_PREF(AS, BS, KB)                                                 \
  {                                                                           \
    _Pragma("unroll")                                                         \
    for (int i = 0; i < 4; i++) {                                             \
      const int u = tid + i * 256;                                            \
      const int r = u >> 3, c = u & 7;                                        \
      const int ca = c ^ (r & 7);                                             \
      ASYNC_COPY16(A + (bm + r) * (long)K + (KB) + ca * 8, &AS[u * 8]);       \
      ASYNC_COPY16(B + (bn + r) * (long)K + (KB) + ca * 8, &BS[u * 8]);       \
    }                                                                         \
  }

#define GEMM_COMPUTE(AS, BS)                                                  \
  {                                                                           \
    _Pragma("unroll")                                                         \
    for (int ks = 0; ks < 2; ks++) {                                          \
      const int cc = ks * 4 + quad;                                           \
      short8 af[4], bfr[4];                                                   \
      _Pragma("unroll")                                                       \
      for (int t = 0; t < 4; t++) {                                           \
        const int ra = wm * 64 + t * 16 + col;                                \
        const int rb = wn * 64 + t * 16 + col;                                \
        af[t]  = *(const short8*)&AS[ra * 64 + ((cc ^ (ra & 7)) * 8)];        \
        bfr[t] = *(const short8*)&BS[rb * 64 + ((cc ^ (rb & 7)) * 8)];        \
      }                                                                       \
      _Pragma("unroll")                                                       \
      for (int tm = 0; tm < 4; tm++)                                          \
        _Pragma("unroll")                                                     \
        for (int tn = 0; tn < 4; tn++)                                        \
          acc[tm][tn] = __builtin_amdgcn_mfma_f32_16x16x32_bf16(af[tm], bfr[tn], acc[tm][tn], 0, 0, 0); \
    }                                                                         \
  }

__global__ __launch_bounds__(256) void gemm_bf16_kernel(
    const bf16* __restrict__ A, const bf16* __restrict__ B,
    const float* __restrict__ bias,
    bf16* __restrict__ Cb, bf16* __restrict__ vTout,
    int N, int K, int swz, long az, long bz, long cz, int skipQ)
{
    __shared__ bf16 As0[128 * 64];
    __shared__ bf16 Bs0[128 * 64];
    __shared__ bf16 As1[128 * 64];
    __shared__ bf16 Bs1[128 * 64];

    A += (long)blockIdx.z * az;
    B += (long)blockIdx.z * bz;
    if (Cb) Cb += (long)blockIdx.z * cz;

    const int tid = threadIdx.x;
    const int lane = tid & 63, wave = tid >> 6;
    const int wm = wave & 1, wn = wave >> 1;

    int bmt, bnt;
    if (swz) {
        const int id = blockIdx.x + gridDim.x * blockIdx.y;
        const int xcd = id & 7, loc = id >> 3;
        bmt = xcd * 8 + (loc & 7);
        bnt = loc >> 3;
    } else {
        bmt = blockIdx.y;
        bnt = blockIdx.x;
    }
    if (skipQ && bnt < 6 && (bmt & 1)) return;

    const long bm = (long)bmt * 128, bn = (long)bnt * 128;
    const int col = lane & 15, quad = lane >> 4;

    f32x4 acc[4][4] = {};

    GEMM_PREF(As0, Bs0, 0);
    for (int kk = 0; kk < K; kk += 128) {
        __syncthreads();
        GEMM_PREF(As1, Bs1, kk + 64);
        GEMM_COMPUTE(As0, Bs0);
        __syncthreads();
        if (kk + 128 < K) GEMM_PREF(As0, Bs0, kk + 128);
        GEMM_COMPUTE(As1, Bs1);
    }

    const bool toVT = (vTout != nullptr) && (bn >= 1536);

    if (toVT) {
        __syncthreads();
        bf16* tb = (wave < 2 ? As0 : Bs0) + (wave & 1) * 4096;
#pragma unroll
        for (int tn = 0; tn < 4; tn++) {
            const int nl = tn * 16 + col;
            const float bvv = bias[bn + wn * 64 + nl];
#pragma unroll
            for (int tm = 0; tm < 4; tm++) {
                const int mc = tm * 4 + quad;
                bf16 t4[4];
#pragma unroll
                for (int r = 0; r < 4; r++)
                    t4[r] = __float2bfloat16(acc[tm][tn][r] + bvv);
                *(uint2*)&tb[(nl * 16 + (mc ^ (nl & 15))) * 4] = *(uint2*)t4;
            }
        }
        const int b_  = (int)((bm + wm * 64) >> 8);
        const int s0  = (int)((bm + wm * 64) & 255);
        const long nb = bn + wn * 64 - 1536;
#pragma unroll
        for (int it2 = 0; it2 < 16; it2++) {
            const int nl = it2 * 4 + quad;
            const uint2 v = *(const uint2*)&tb[(nl * 16 + (col ^ (nl & 15))) * 4];
            *(uint2*)&vTout[((long)b_ * 768 + nb + nl) * 256 + s0 + col * 4] = v;
        }
    } else {
#pragma unroll
        for (int tn = 0; tn < 4; tn++) {
            const long n = bn + wn * 64 + tn * 16 + col;
            const float bvv = bias ? bias[n] : 0.f;
#pragma unroll
            for (int tm = 0; tm < 4; tm++) {
                const long m0 = bm + wm * 64 + tm * 16 + quad * 4;
#pragma unroll
                for (int r = 0; r < 4; r++)
                    Cb[(m0 + r) * N + n] = __float2bfloat16(acc[tm][tn][r] + bvv);
            }
        }
    }
}

// ---------------------------------------------------------------------------
// MFMA attention with DOUBLE-BUFFERED LDS K/V staging (ping-pong, statically
// distinct buffers). 8 barriers/block (was 16); every global stage overlaps
// compute; V0 prefetch issued before softmax (hidden under exp/shuffles).
// LDS 65 KB -> 2 blocks/CU; grid 1024 = exactly 2 balanced waves.
// ---------------------------------------------------------------------------
#define PREF_K(DST, JC)                                                      \
  { _Pragma("unroll")                                                        \
    for (int i = 0; i < 4; i++) {                                            \
      const int u = tid + i * 256;                                           \
      const int r = u >> 4, pp = u & 15;                                     \
      const int c = pp ^ (r & 15);                                           \
      ASYNC_COPY16(kbase + ((JC) * 64 + r) * 2304 + c * 8, &DST[u * 8]);     \
    } }

#define PREF_V(DST, KC)                                                      \
  { _Pragma("unroll")                                                        \
    for (int i = 0; i < 3; i++) {                                            \
      const int u = tid + i * 256;                                           \
      const int r = u >> 3, pp = u & 7;                                      \
      const int c = pp ^ (r & 7);                                            \
      ASYNC_COPY16(vbase + r * 256 + (KC) * 64 + c * 8, &DST[u * 8]);        \
    } }

#define SCORE(BUF, JC)                                                       \
  { _Pragma("unroll")                                                        \
    for (int ks = 0; ks < 3; ks++) {                                         \
      _Pragma("unroll")                                                      \
      for (int jt2 = 0; jt2 < 4; jt2++) {                                    \
        const int row = jt2 * 16 + col;                                      \
        const int c = ks * 4 + quad;                                         \
        const short8 bk_ = *(const short8*)&BUF[row * 128 + ((c ^ (row & 15)) * 8)]; \
        accS[(JC) * 4 + jt2] = __builtin_amdgcn_mfma_f32_16x16x32_bf16(aq[ks], bk_, accS[(JC) * 4 + jt2], 0, 0, 0); \
      } } }

#define PV(BUF, KC)                                                          \
  { _Pragma("unroll")                                                        \
    for (int k2 = 0; k2 < 2; k2++) {                                         \
      const short8 ap = *(const short8*)&Ps[(wave * 16 + col) * PS + (KC) * 64 + k2 * 32 + quad * 8]; \
      _Pragma("unroll")                                                      \
      for (int nt = 0; nt < 6; nt++) {                                       \
        const int row = nt * 16 + col;                                       \
        const int c = k2 * 4 + quad;                                         \
        const short8 bv_ = *(const short8*)&BUF[row * 64 + ((c ^ (row & 7)) * 8)]; \
        accO[nt] = __builtin_amdgcn_mfma_f32_16x16x32_bf16(ap, bv_, accO[nt], 0, 0, 0); \
      } } }

__global__ __launch_bounds__(256) void attn_mfma_kernel(
    const bf16* __restrict__ qkv, const bf16* __restrict__ vT,
    const float* __restrict__ biasT, bf16* __restrict__ o)
{
    constexpr int PS = 264;
    __shared__ bf16 Ps[64 * PS];      // 33.8 KB
    __shared__ bf16 KV0[64 * 128];    // 16 KB
    __shared__ bf16 KV1[64 * 128];    // 16 KB

    const int blk = blockIdx.x;
    const int b  = blk & 31;
    const int h  = (blk >> 5) & 7;
    const int it = blk >> 8;
    const int i0 = it * 64;
    const int tid = threadIdx.x, lane = tid & 63, wave = tid >> 6;
    const int col = lane & 15, quad = lane >> 4;
    const long rowbase = (long)b * SEQ;

    const bf16* kbase = qkv + rowbase * 2304 + 768 + h * 96;
    const bf16* vbase = vT + ((long)b * 768 + h * 96) * 256;

    PREF_K(KV0, 0);

    // Q fragments (A-operand layout), direct from global (overlaps K0 load)
    short8 aq[3];
    {
        const bf16* qrow = qkv + (rowbase + i0 + wave * 16 + col) * 2304 + h * 96;
#pragma unroll
        for (int ks = 0; ks < 3; ks++)
            aq[ks] = *(const short8*)&qrow[ks * 32 + quad * 8];
    }

    // ---- scores: ping-pong staged K ----
    f32x4 accS[16] = {};
    __syncthreads();            // drain K0 -> KV0
    PREF_K(KV1, 1);
    SCORE(KV0, 0);
    __syncthreads();            // drain K1 -> KV1 (all waves past KV0 reads)
    PREF_K(KV0, 2);
    SCORE(KV1, 1);
    __syncthreads();
    PREF_K(KV1, 3);
    SCORE(KV0, 2);
    __syncthreads();
    PREF_V(KV0, 0);             // V0 load hides under SCORE(3) + softmax
    SCORE(KV1, 3);

    // ---- bias (biasT[h][j][i], float4 per lane) + softmax ----
    const float* bbT = biasT + (long)h * SEQ * SEQ + i0 + wave * 16 + quad * 4;
#pragma unroll
    for (int jt = 0; jt < 16; jt++) {
        const float4 bv4 = *(const float4*)&bbT[(jt * 16 + col) * SEQ];
        accS[jt][0] += bv4.x;
        accS[jt][1] += bv4.y;
        accS[jt][2] += bv4.z;
        accS[jt][3] += bv4.w;
    }

#pragma unroll
    for (int r = 0; r < 4; r++) {
        float m = accS[0][r];
#pragma unroll
        for (int jt = 1; jt < 16; jt++) m = fmaxf(m, accS[jt][r]);
        for (int d = 1; d < 16; d <<= 1) m = fmaxf(m, __shfl_xor(m, d));
        float s = 0.f;
#pragma unroll
        for (int jt = 0; jt < 16; jt++) {
            const float e = __expf(accS[jt][r] - m);
            accS[jt][r] = e;
            s += e;
        }
        for (int d = 1; d < 16; d <<= 1) s += __shfl_xor(s, d);
        const float inv = 1.f / s;
        const int prow = wave * 16 + quad * 4 + r;
#pragma unroll
        for (int jt = 0; jt < 16; jt++)
            Ps[prow * PS + jt * 16 + col] = __float2bfloat16(accS[jt][r] * inv);
    }
    // no barrier for Ps: each wave reads only the rows it wrote (in-order LDS)

    // ---- O = P.V : ping-pong staged V (from vT[b][h*96+d][s]) ----
    f32x4 accO[6] = {};
    __syncthreads();            // drain V0 -> KV0 (all waves past KV1/K3 reads)
    PREF_V(KV1, 1);
    PV(KV0, 0);
    __syncthreads();
    PREF_V(KV0, 2);
    PV(KV1, 1);
    __syncthreads();
    PREF_V(KV1, 3);
    PV(KV0, 2);
    __syncthreads();
    PV(KV1, 3);

#pragma unroll
    for (int nt = 0; nt < 6; nt++)
#pragma unroll
        for (int r = 0; r < 4; r++) {
            const long m = rowbase + i0 + wave * 16 + quad * 4 + r;
            o[m * DIM + h * 96 + nt * 16 + col] = __float2bfloat16(accO[nt][r]);
        }
}

// out[b, ng*32 + tid>>3] = ob[b*256,:] . Wo5[n,:] + bo5[n]
__global__ __launch_bounds__(256) void final_out_kernel(
    const bf16* __restrict__ ob, const float* __restrict__ Wo5,
    const float* __restrict__ bo5, float* __restrict__ out)
{
    __shared__ float os[768];
    const int b = blockIdx.y, ng = blockIdx.x, tid = threadIdx.x;
    const bf16* orow = ob + (long)b * 256 * 768;
    for (int i = tid; i < 768; i += 256) os[i] = __bfloat162float(orow[i]);
    __syncthreads();

    const int n = ng * 32 + (tid >> 3);
    const int seg = tid & 7;
    const float* wrow = Wo5 + (long)n * 768 + seg * 96;
    const float* xs = &os[seg * 96];
    float s = 0.f;
#pragma unroll
    for (int k = 0; k < 96; k += 4) {
        const float4 w = *(const float4*)&wrow[k];
        s += xs[k] * w.x + xs[k + 1] * w.y + xs[k + 2] * w.z + xs[k + 3] * w.w;
    }
    s += __shfl_xor(s, 1);
    s += __shfl_xor(s, 2);
    s += __shfl_xor(s, 4);
    if (seg == 0) out[b * 768 + n] = s + bo5[n];
}

extern "C" void kernel_launch(void* const* d_in, const int* in_sizes, int n_in,
                              void* d_out, int out_size, void* d_ws, size_t ws_size,
                              hipStream_t stream)
{
    const int*   tokens   = (const int*)d_in[0];
    const float* embed    = (const float*)d_in[1];
    const float* pos_emb  = (const float*)d_in[2];
    const float* pos_q_w  = (const float*)d_in[3];
    const float* pos_q_b  = (const float*)d_in[4];
    const float* pos_k_w  = (const float*)d_in[5];
    const float* pos_k_b  = (const float*)d_in[6];
    const float* pos_ln_g = (const float*)d_in[7];
    const float* pos_ln_b = (const float*)d_in[8];
    const float* rel_tab  = (const float*)d_in[9];
    const int*   rp       = (const int*)d_in[10];
    const float* Wq = (const float*)d_in[11];
    const float* bq = (const float*)d_in[12];
    const float* Wk = (const float*)d_in[13];
    const float* bk = (const float*)d_in[14];
    const float* Wv = (const float*)d_in[15];
    const float* bv = (const float*)d_in[16];
    const float* Wo = (const float*)d_in[17];
    const float* bo = (const float*)d_in[18];
    float* out = (float*)d_out;

    char* p = (char*)d_ws;
    auto alloc = [&](size_t bytes) -> char* {
        char* r = p;
        p += (bytes + 255) & ~(size_t)255;
        return r;
    };
    const long NT = 32L * SEQ;  // 8192

    float* biasT = (float*)alloc(8L * SEQ * SEQ * 4);       // [h][j][i]
    float* wln   = (float*)alloc((long)SEQ * DIM * 4);
    float* pqk   = (float*)alloc(2L * SEQ * DIM * 4);       // pq | pk
    float* wsW   = (float*)alloc(2L * 768 * 768 * 4);       // posq_w | posk_w
    float* wsB   = (float*)alloc(2L * 768 * 4);
    bf16*  xb    = (bf16*) alloc(NT * DIM * 2);
    bf16*  qkv   = (bf16*) alloc(NT * 2304 * 2);
    bf16*  vT    = (bf16*) alloc(NT * DIM * 2);             // [32][768][256]
    bf16*  ob    = (bf16*) alloc(NT * DIM * 2);
    bf16*  wqkv  = (bf16*) alloc(6L * 2304 * 768 * 2);
    bf16*  woT   = (bf16*) alloc(6L * 768 * 768 * 2);
    bf16*  wf    = (bf16*) alloc(5L * 2304 * 768 * 2);
    float* bqkv  = (float*)alloc(6L * 2304 * 4);
    float* bfus  = (float*)alloc(5L * 2304 * 4);

    const float SCALE = 0.07216878364870322f;   // (HD*2)^-0.5

    // ---- all independent setup in ONE launch ----
    setup_mega_kernel<<<RB_G, 256, 0, stream>>>(
        tokens, embed, pos_emb, pos_q_w, pos_q_b, pos_k_w, pos_k_b,
        pos_ln_g, pos_ln_b, Wq, Wk, Wv, Wo, bq, bk, bv,
        wqkv, woT, bqkv, xb, wln, wsW, wsB, SCALE);

    // Wf_l = Wqkv_{l+1} . Wo_l  (batched, z = l)
    gemm_bf16_kernel<<<dim3(6, 18, 5), 256, 0, stream>>>(
        wqkv + 2304L * 768, woT, nullptr, wf, nullptr, 768, 768, 0,
        2304L * 768, 768L * 768, 2304L * 768, 0);
    fused_bias_kernel<<<dim3(72, 5), 256, 0, stream>>>(wqkv, bo, bqkv, bfus);

    // pos projections pq|pk in one batched launch
    gemm_kernel<<<dim3(12, 4, 2), 256, 0, stream>>>(
        wln, DIM, 0, wsW, DIM, 768L * 768, wsB, 768,
        pqk, DIM, (long)SEQ * DIM, SEQ, DIM, DIM, 1.0f, nullptr, nullptr);
    // biasT[h][j][i] = SCALE * (pk_j . pq_i) + rel[i,j,h]
    gemm_kernel<<<dim3(4, 4, NH), 256, 0, stream>>>(
        pqk + (long)SEQ * DIM, DIM, HD, pqk, DIM, HD, nullptr, 0,
        biasT, SEQ, (long)SEQ * SEQ, SEQ, SEQ, HD, SCALE, rp, rel_tab);

    // ---- layer pipeline ----
    gemm_bf16_kernel<<<dim3(18, 64, 1), 256, 0, stream>>>(xb, wqkv, bqkv, qkv, vT, 2304, 768, 1, 0, 0, 0, 0);
    for (int l = 0; l < 5; l++) {
        attn_mfma_kernel<<<1024, 256, 0, stream>>>(qkv, vT, biasT, ob);
        gemm_bf16_kernel<<<dim3(18, 64, 1), 256, 0, stream>>>(
            ob, wf + (long)l * 2304 * 768, bfus + (long)l * 2304, qkv, vT, 2304, 768, 1, 0, 0, 0,
            (l == 4) ? 1 : 0);
    }
    attn_mfma_kernel<<<256, 256, 0, stream>>>(qkv, vT, biasT, ob);   // it=0 only
    final_out_kernel<<<dim3(24, 32), 256, 0, stream>>>(ob, Wo + 5L * 768 * 768, bo + 5L * 768, out);
}

// Round 11
// 659.817 us; speedup vs baseline: 1.7314x; 1.0631x over previous
//
#include <hip/hip_runtime.h>
#include <hip/hip_bf16.h>
#include <math.h>

constexpr int SEQ = 256;
constexpr int DIM = 768;
constexpr int NH  = 8;
constexpr int HD  = 96;

typedef __attribute__((ext_vector_type(8))) short short8;
typedef __attribute__((ext_vector_type(4))) float f32x4;
using bf16 = __hip_bfloat16;

#define ASYNC_COPY16(gptr, lptr) \
  __builtin_amdgcn_global_load_lds((const __attribute__((address_space(1))) void*)(gptr), \
                                   (__attribute__((address_space(3))) void*)(lptr), 16, 0, 0)

// ---------------------------------------------------------------------------
// f32 tiled GEMM: C[m,n] = (sum_k A[m,k]*W[n,k] + bias[n]) * scale  (+ rel)
// rtab != null: C[m,n] = acc*scale + rtab[rp[n*256+m]*8 + blockIdx.z]
// ---------------------------------------------------------------------------
__global__ __launch_bounds__(256) void gemm_kernel(
    const float* __restrict__ A, int lda, long aoz,
    const float* __restrict__ W, int ldw, long woz,
    const float* __restrict__ bias, long boz,
    float* __restrict__ C, int ldc, long coz,
    int M, int N, int K, float scale,
    const int* __restrict__ rp, const float* __restrict__ rtab)
{
    const int hz = blockIdx.z;
    A += (long)hz * aoz;
    W += (long)hz * woz;
    if (bias) bias += (long)hz * boz;
    C += (long)hz * coz;

    __shared__ float As[16][68];
    __shared__ float Ws[16][68];

    const int bm = blockIdx.y * 64;
    const int bn = blockIdx.x * 64;
    const int tid = threadIdx.x;
    const int tx = tid & 15;
    const int ty = tid >> 4;

    float acc[4][4] = {};

    for (int k0 = 0; k0 < K; k0 += 16) {
#pragma unroll
        for (int i = 0; i < 4; i++) {
            int idx = tid + i * 256;
            int r = idx >> 4, c = idx & 15;
            As[c][r] = A[(long)(bm + r) * lda + (k0 + c)];
            Ws[c][r] = W[(long)(bn + r) * ldw + (k0 + c)];
        }
        __syncthreads();
#pragma unroll
        for (int kk = 0; kk < 16; kk++) {
            const float4 a = *(const float4*)&As[kk][ty * 4];
            const float4 w = *(const float4*)&Ws[kk][tx * 4];
            acc[0][0] += a.x * w.x; acc[0][1] += a.x * w.y; acc[0][2] += a.x * w.z; acc[0][3] += a.x * w.w;
            acc[1][0] += a.y * w.x; acc[1][1] += a.y * w.y; acc[1][2] += a.y * w.z; acc[1][3] += a.y * w.w;
            acc[2][0] += a.z * w.x; acc[2][1] += a.z * w.y; acc[2][2] += a.z * w.z; acc[2][3] += a.z * w.w;
            acc[3][0] += a.w * w.x; acc[3][1] += a.w * w.y; acc[3][2] += a.w * w.z; acc[3][3] += a.w * w.w;
        }
        __syncthreads();
    }

    const int n0 = bn + tx * 4;
    float4 bv = make_float4(0.f, 0.f, 0.f, 0.f);
    if (bias) bv = *(const float4*)&bias[n0];
#pragma unroll
    for (int i = 0; i < 4; i++) {
        const int m = bm + ty * 4 + i;
        float4 r;
        if (rtab) {
            r.x = acc[i][0] * scale + rtab[rp[(n0 + 0) * 256 + m] * 8 + hz];
            r.y = acc[i][1] * scale + rtab[rp[(n0 + 1) * 256 + m] * 8 + hz];
            r.z = acc[i][2] * scale + rtab[rp[(n0 + 2) * 256 + m] * 8 + hz];
            r.w = acc[i][3] * scale + rtab[rp[(n0 + 3) * 256 + m] * 8 + hz];
        } else {
            r.x = (acc[i][0] + bv.x) * scale;
            r.y = (acc[i][1] + bv.y) * scale;
            r.z = (acc[i][2] + bv.z) * scale;
            r.w = (acc[i][3] + bv.w) * scale;
        }
        *(float4*)&C[(long)m * ldc + n0] = r;
    }
}

// ---------------------------------------------------------------------------
// Setup mega-kernel (role by blockIdx ranges)
// ---------------------------------------------------------------------------
constexpr int RB_A = 10368;
constexpr int RB_B = RB_A + 3456;
constexpr int RB_C = RB_B + 54;
constexpr int RB_D = RB_C + 8192;
constexpr int RB_E = RB_D + 256;
constexpr int RB_F = RB_E + 1152;
constexpr int RB_G = RB_F + 2;

__global__ __launch_bounds__(256) void setup_mega_kernel(
    const int* __restrict__ tokens, const float* __restrict__ embed,
    const float* __restrict__ pos_emb,
    const float* __restrict__ pos_q_w, const float* __restrict__ pos_q_b,
    const float* __restrict__ pos_k_w, const float* __restrict__ pos_k_b,
    const float* __restrict__ pos_ln_g, const float* __restrict__ pos_ln_b,
    const float* __restrict__ Wq, const float* __restrict__ Wk,
    const float* __restrict__ Wv, const float* __restrict__ Wo,
    const float* __restrict__ bq, const float* __restrict__ bk,
    const float* __restrict__ bv,
    bf16* __restrict__ wqkv, bf16* __restrict__ woT, float* __restrict__ bqkv,
    bf16* __restrict__ xb, float* __restrict__ wln,
    float* __restrict__ wsW, float* __restrict__ wsB, float scale)
{
    const int bid = blockIdx.x, tid = threadIdx.x;

    if (bid < RB_A) {
        const long idx = (long)bid * 256 + tid;
        const long e = idx * 4;
        const int k = (int)(e % 768);
        const long nl = e / 768;
        const int n = (int)(nl % 2304);
        const int l = (int)(nl / 2304);
        const float* src;
        float sc = 1.f;
        if (n < 768)       { src = Wq + ((long)l * 768 + n) * 768; sc = scale; }
        else if (n < 1536) { src = Wk + ((long)l * 768 + (n - 768)) * 768; }
        else               { src = Wv + ((long)l * 768 + (n - 1536)) * 768; }
        const float4 v = *(const float4*)&src[k];
        bf16 tmp[4];
        tmp[0] = __float2bfloat16(v.x * sc);
        tmp[1] = __float2bfloat16(v.y * sc);
        tmp[2] = __float2bfloat16(v.z * sc);
        tmp[3] = __float2bfloat16(v.w * sc);
        *(uint2*)&wqkv[((long)l * 2304 + n) * 768 + k] = *(uint2*)tmp;
    } else if (bid < RB_B) {
        __shared__ float t[32][33];
        const int b2 = bid - RB_A;
        const int l = b2 / 576, r2 = b2 % 576;
        const int c0 = (r2 % 24) * 32, j0 = (r2 / 24) * 32;
        const int tx = tid & 31, ty = tid >> 5;
        const float* src = Wo + (long)l * 768 * 768;
#pragma unroll
        for (int rr = 0; rr < 32; rr += 8)
            t[ty + rr][tx] = src[(long)(c0 + ty + rr) * 768 + j0 + tx];
        __syncthreads();
        bf16* dst = woT + (long)l * 768 * 768;
#pragma unroll
        for (int rr = 0; rr < 32; rr += 8)
            dst[(long)(j0 + ty + rr) * 768 + c0 + tx] = __float2bfloat16(t[tx][ty + rr]);
    } else if (bid < RB_C) {
        const int idx = (bid - RB_B) * 256 + tid;
        if (idx < 6 * 2304) {
            const int n = idx % 2304, l = idx / 2304;
            float v;
            if (n < 768)       v = bq[l * 768 + n] * scale;
            else if (n < 1536) v = bk[l * 768 + (n - 768)];
            else               v = bv[l * 768 + (n - 1536)];
            bqkv[idx] = v;
        }
    } else if (bid < RB_D) {
        if (tid < 192) {
            const int t = bid - RB_C;
            const int tok = tokens[t];
            const float4 v = ((const float4*)(embed + (long)tok * DIM))[tid];
            bf16 tmp[4];
            tmp[0] = __float2bfloat16(v.x);
            tmp[1] = __float2bfloat16(v.y);
            tmp[2] = __float2bfloat16(v.z);
            tmp[3] = __float2bfloat16(v.w);
            *(uint2*)&xb[(long)t * DIM + tid * 4] = *(uint2*)tmp;
        }
    } else if (bid < RB_E) {
        __shared__ float buf[256];
        const int i = bid - RB_D;
        const float* row = pos_emb + (long)i * DIM;
        float v0 = row[tid], v1 = row[tid + 256], v2 = row[tid + 512];
        buf[tid] = v0 + v1 + v2;
        __syncthreads();
        for (int off = 128; off > 0; off >>= 1) {
            if (tid < off) buf[tid] += buf[tid + off];
            __syncthreads();
        }
        const float mean = buf[0] * (1.f / 768.f);
        __syncthreads();
        const float d0 = v0 - mean, d1 = v1 - mean, d2 = v2 - mean;
        buf[tid] = d0 * d0 + d1 * d1 + d2 * d2;
        __syncthreads();
        for (int off = 128; off > 0; off >>= 1) {
            if (tid < off) buf[tid] += buf[tid + off];
            __syncthreads();
        }
        const float rstd = rsqrtf(buf[0] * (1.f / 768.f) + 1e-5f);
        float* wr = wln + (long)i * DIM;
        wr[tid]       = d0 * rstd * pos_ln_g[tid]       + pos_ln_b[tid];
        wr[tid + 256] = d1 * rstd * pos_ln_g[tid + 256] + pos_ln_b[tid + 256];
        wr[tid + 512] = d2 * rstd * pos_ln_g[tid + 512] + pos_ln_b[tid + 512];
    } else if (bid < RB_F) {
        const long idx = (long)(bid - RB_E) * 256 + tid;
        const long e = idx * 4;
        const float4 v = (e < 589824) ? *(const float4*)&pos_q_w[e]
                                      : *(const float4*)&pos_k_w[e - 589824];
        *(float4*)&wsW[e] = v;
    } else {
        const int idx = (bid - RB_F) * 256 + tid;
        wsB[idx] = (idx < 768) ? pos_q_b[idx] : pos_k_b[idx - 768];
    }
}

// bf[l][n] = wqkv[l+1][n,:] . bo[l] + bqkv[l+1][n]   (l = 0..4)
__global__ __launch_bounds__(256) void fused_bias_kernel(
    const bf16* __restrict__ wqkv, const float* __restrict__ bo,
    const float* __restrict__ bqkv, float* __restrict__ bf_)
{
    const int l = blockIdx.y;
    const int lane = threadIdx.x & 63, wave = threadIdx.x >> 6;
    const int nloc = wave * 8 + (lane >> 3);
    const int seg = lane & 7;
    const int n = blockIdx.x * 32 + nloc;
    const bf16* wrow = wqkv + ((long)(l + 1) * 2304 + n) * 768 + seg * 96;
    const float* bsrc = bo + (long)l * 768 + seg * 96;
    float s = 0.f;
#pragma unroll
    for (int c8 = 0; c8 < 12; c8++) {
        const short8 w8 = *(const short8*)&wrow[c8 * 8];
#pragma unroll
        for (int e = 0; e < 8; e++) {
            bf16 b;
            *(short*)&b = w8[e];
            s += __bfloat162float(b) * bsrc[c8 * 8 + e];
        }
    }
    s += __shfl_xor(s, 1);
    s += __shfl_xor(s, 2);
    s += __shfl_xor(s, 4);
    if (seg == 0) bf_[l * 2304 + n] = s + bqkv[(l + 1) * 2304 + n];
}

// ---------------------------------------------------------------------------
// bf16 MFMA GEMM: 128x128 tile, BK=64, ping-pong double-buffered LDS.
// 512 threads / 8 waves (2m x 4n, wave tile 64x32) -> 16 waves/CU at 2
// blocks/CU: 2x the latency-hiding pool of the 4-wave version, same LDS.
// Per-element K-summation order identical to the 4-wave version.
// ---------------------------------------------------------------------------
#define GEMM_PREF(AS, BS, KB)                                                 \
  {                                                                           \
    _Pragma("unroll")                                                         \
    for (int i = 0; i < 2; i++) {                                             \
      const int u = tid + i * 512;                                            \
      const int r = u >> 3, c = u & 7;                                        \
      const int ca = c ^ (r & 7);                                             \
      ASYNC_COPY16(A + (bm + r) * (long)K + (KB) + ca * 8, &AS[u * 8]);       \
      ASYNC_COPY16(B + (bn + r) * (long)K + (KB) + ca * 8, &BS[u * 8]);       \
    }                                                                         \
  }

#define GEMM_COMPUTE(AS, BS)                                                  \
  {                                                                           \
    _Pragma("unroll")                                                         \
    for (int ks = 0; ks < 2; ks++) {                                          \
      const int cc = ks * 4 + quad;                                           \
      short8 af[4], bfr[2];                                                   \
      _Pragma("unroll")                                                       \
      for (int t = 0; t < 4; t++) {                                           \
        const int ra = wm * 64 + t * 16 + col;                                \
        af[t] = *(const short8*)&AS[ra * 64 + ((cc ^ (ra & 7)) * 8)];         \
      }                                                                       \
      _Pragma("unroll")                                                       \
      for (int t = 0; t < 2; t++) {                                           \
        const int rb = wn * 32 + t * 16 + col;                                \
        bfr[t] = *(const short8*)&BS[rb * 64 + ((cc ^ (rb & 7)) * 8)];        \
      }                                                                       \
      _Pragma("unroll")                                                       \
      for (int tm = 0; tm < 4; tm++)                                          \
        _Pragma("unroll")                                                     \
        for (int tn = 0; tn < 2; tn++)                                        \
          acc[tm][tn] = __builtin_amdgcn_mfma_f32_16x16x32_bf16(af[tm], bfr[tn], acc[tm][tn], 0, 0, 0); \
    }                                                                         \
  }

__global__ __launch_bounds__(512, 4) void gemm_bf16_kernel(
    const bf16* __restrict__ A, const bf16* __restrict__ B,
    const float* __restrict__ bias,
    bf16* __restrict__ Cb, bf16* __restrict__ vTout,
    int N, int K, int swz, long az, long bz, long cz, int skipQ)
{
    __shared__ bf16 As0[128 * 64];
    __shared__ bf16 Bs0[128 * 64];
    __shared__ bf16 As1[128 * 64];
    __shared__ bf16 Bs1[128 * 64];

    A += (long)blockIdx.z * az;
    B += (long)blockIdx.z * bz;
    if (Cb) Cb += (long)blockIdx.z * cz;

    const int tid = threadIdx.x;
    const int lane = tid & 63, wave = tid >> 6;   // 8 waves
    const int wm = wave & 1, wn = wave >> 1;      // 2m x 4n

    int bmt, bnt;
    if (swz) {
        const int id = blockIdx.x + gridDim.x * blockIdx.y;
        const int xcd = id & 7, loc = id >> 3;
        bmt = xcd * 8 + (loc & 7);
        bnt = loc >> 3;
    } else {
        bmt = blockIdx.y;
        bnt = blockIdx.x;
    }
    if (skipQ && bnt < 6 && (bmt & 1)) return;

    const long bm = (long)bmt * 128, bn = (long)bnt * 128;
    const int col = lane & 15, quad = lane >> 4;

    f32x4 acc[4][2] = {};

    GEMM_PREF(As0, Bs0, 0);
    for (int kk = 0; kk < K; kk += 128) {
        __syncthreads();
        GEMM_PREF(As1, Bs1, kk + 64);
        GEMM_COMPUTE(As0, Bs0);
        __syncthreads();
        if (kk + 128 < K) GEMM_PREF(As0, Bs0, kk + 128);
        GEMM_COMPUTE(As1, Bs1);
    }

    const bool toVT = (vTout != nullptr) && (bn >= 1536);

    if (toVT) {
        // wave-local 64m x 32n transpose through LDS (4 KB scratch per wave)
        __syncthreads();
        bf16* tb = (wave < 4 ? As0 : Bs0) + (wave & 3) * 2048;
#pragma unroll
        for (int tn = 0; tn < 2; tn++) {
            const int nl = tn * 16 + col;                 // 0..31
            const float bvv = bias[bn + wn * 32 + nl];
#pragma unroll
            for (int tm = 0; tm < 4; tm++) {
                const int mc = tm * 4 + quad;             // 0..15 (4-bf16 m-chunk)
                bf16 t4[4];
#pragma unroll
                for (int r = 0; r < 4; r++)
                    t4[r] = __float2bfloat16(acc[tm][tn][r] + bvv);
                *(uint2*)&tb[(nl * 16 + (mc ^ (nl & 15))) * 4] = *(uint2*)t4;
            }
        }
        const int b_  = (int)((bm + wm * 64) >> 8);
        const int s0  = (int)((bm + wm * 64) & 255);
        const long nb = bn + wn * 32 - 1536;
#pragma unroll
        for (int it2 = 0; it2 < 8; it2++) {
            const int nl = it2 * 4 + quad;                // 0..31
            const uint2 v = *(const uint2*)&tb[(nl * 16 + (col ^ (nl & 15))) * 4];
            *(uint2*)&vTout[((long)b_ * 768 + nb + nl) * 256 + s0 + col * 4] = v;
        }
    } else {
#pragma unroll
        for (int tn = 0; tn < 2; tn++) {
            const long n = bn + wn * 32 + tn * 16 + col;
            const float bvv = bias ? bias[n] : 0.f;
#pragma unroll
            for (int tm = 0; tm < 4; tm++) {
                const long m0 = bm + wm * 64 + tm * 16 + quad * 4;
#pragma unroll
                for (int r = 0; r < 4; r++)
                    Cb[(m0 + r) * N + n] = __float2bfloat16(acc[tm][tn][r] + bvv);
            }
        }
    }
}

// ---------------------------------------------------------------------------
// MFMA attention with double-buffered LDS K/V staging (see R10).
// ---------------------------------------------------------------------------
#define PREF_K(DST, JC)                                                      \
  { _Pragma("unroll")                                                        \
    for (int i = 0; i < 4; i++) {                                            \
      const int u = tid + i * 256;                                           \
      const int r = u >> 4, pp = u & 15;                                     \
      const int c = pp ^ (r & 15);                                           \
      ASYNC_COPY16(kbase + ((JC) * 64 + r) * 2304 + c * 8, &DST[u * 8]);     \
    } }

#define PREF_V(DST, KC)                                                      \
  { _Pragma("unroll")                                                        \
    for (int i = 0; i < 3; i++) {                                            \
      const int u = tid + i * 256;                                           \
      const int r = u >> 3, pp = u & 7;                                      \
      const int c = pp ^ (r & 7);                                            \
      ASYNC_COPY16(vbase + r * 256 + (KC) * 64 + c * 8, &DST[u * 8]);        \
    } }

#define SCORE(BUF, JC)                                                       \
  { _Pragma("unroll")                                                        \
    for (int ks = 0; ks < 3; ks++) {                                         \
      _Pragma("unroll")                                                      \
      for (int jt2 = 0; jt2 < 4; jt2++) {                                    \
        const int row = jt2 * 16 + col;                                      \
        const int c = ks * 4 + quad;                                         \
        const short8 bk_ = *(const short8*)&BUF[row * 128 + ((c ^ (row & 15)) * 8)]; \
        accS[(JC) * 4 + jt2] = __builtin_amdgcn_mfma_f32_16x16x32_bf16(aq[ks], bk_, accS[(JC) * 4 + jt2], 0, 0, 0); \
      } } }

#define PV(BUF, KC)                                                          \
  { _Pragma("unroll")                                                        \
    for (int k2 = 0; k2 < 2; k2++) {                                         \
      const short8 ap = *(const short8*)&Ps[(wave * 16 + col) * PS + (KC) * 64 + k2 * 32 + quad * 8]; \
      _Pragma("unroll")                                                      \
      for (int nt = 0; nt < 6; nt++) {                                       \
        const int row = nt * 16 + col;                                       \
        const int c = k2 * 4 + quad;                                         \
        const short8 bv_ = *(const short8*)&BUF[row * 64 + ((c ^ (row & 7)) * 8)]; \
        accO[nt] = __builtin_amdgcn_mfma_f32_16x16x32_bf16(ap, bv_, accO[nt], 0, 0, 0); \
      } } }

__global__ __launch_bounds__(256) void attn_mfma_kernel(
    const bf16* __restrict__ qkv, const bf16* __restrict__ vT,
    const float* __restrict__ biasT, bf16* __restrict__ o)
{
    constexpr int PS = 264;
    __shared__ bf16 Ps[64 * PS];      // 33.8 KB
    __shared__ bf16 KV0[64 * 128];    // 16 KB
    __shared__ bf16 KV1[64 * 128];    // 16 KB

    const int blk = blockIdx.x;
    const int b  = blk & 31;
    const int h  = (blk >> 5) & 7;
    const int it = blk >> 8;
    const int i0 = it * 64;
    const int tid = threadIdx.x, lane = tid & 63, wave = tid >> 6;
    const int col = lane & 15, quad = lane >> 4;
    const long rowbase = (long)b * SEQ;

    const bf16* kbase = qkv + rowbase * 2304 + 768 + h * 96;
    const bf16* vbase = vT + ((long)b * 768 + h * 96) * 256;

    PREF_K(KV0, 0);

    short8 aq[3];
    {
        const bf16* qrow = qkv + (rowbase + i0 + wave * 16 + col) * 2304 + h * 96;
#pragma unroll
        for (int ks = 0; ks < 3; ks++)
            aq[ks] = *(const short8*)&qrow[ks * 32 + quad * 8];
    }

    f32x4 accS[16] = {};
    __syncthreads();
    PREF_K(KV1, 1);
    SCORE(KV0, 0);
    __syncthreads();
    PREF_K(KV0, 2);
    SCORE(KV1, 1);
    __syncthreads();
    PREF_K(KV1, 3);
    SCORE(KV0, 2);
    __syncthreads();
    PREF_V(KV0, 0);
    SCORE(KV1, 3);

    const float* bbT = biasT + (long)h * SEQ * SEQ + i0 + wave * 16 + quad * 4;
#pragma unroll
    for (int jt = 0; jt < 16; jt++) {
        const float4 bv4 = *(const float4*)&bbT[(jt * 16 + col) * SEQ];
        accS[jt][0] += bv4.x;
        accS[jt][1] += bv4.y;
        accS[jt][2] += bv4.z;
        accS[jt][3] += bv4.w;
    }

#pragma unroll
    for (int r = 0; r < 4; r++) {
        float m = accS[0][r];
#pragma unroll
        for (int jt = 1; jt < 16; jt++) m = fmaxf(m, accS[jt][r]);
        for (int d = 1; d < 16; d <<= 1) m = fmaxf(m, __shfl_xor(m, d));
        float s = 0.f;
#pragma unroll
        for (int jt = 0; jt < 16; jt++) {
            const float e = __expf(accS[jt][r] - m);
            accS[jt][r] = e;
            s += e;
        }
        for (int d = 1; d < 16; d <<= 1) s += __shfl_xor(s, d);
        const float inv = 1.f / s;
        const int prow = wave * 16 + quad * 4 + r;
#pragma unroll
        for (int jt = 0; jt < 16; jt++)
            Ps[prow * PS + jt * 16 + col] = __float2bfloat16(accS[jt][r] * inv);
    }
    // no barrier for Ps: each wave reads only the rows it wrote

    f32x4 accO[6] = {};
    __syncthreads();
    PREF_V(KV1, 1);
    PV(KV0, 0);
    __syncthreads();
    PREF_V(KV0, 2);
    PV(KV1, 1);
    __syncthreads();
    PREF_V(KV1, 3);
    PV(KV0, 2);
    __syncthreads();
    PV(KV1, 3);

#pragma unroll
    for (int nt = 0; nt < 6; nt++)
#pragma unroll
        for (int r = 0; r < 4; r++) {
            const long m = rowbase + i0 + wave * 16 + quad * 4 + r;
            o[m * DIM + h * 96 + nt * 16 + col] = __float2bfloat16(accO[nt][r]);
        }
}

// out[b, ng*32 + tid>>3] = ob[b*256,:] . Wo5[n,:] + bo5[n]
__global__ __launch_bounds__(256) void final_out_kernel(
    const bf16* __restrict__ ob, const float* __restrict__ Wo5,
    const float* __restrict__ bo5, float* __restrict__ out)
{
    __shared__ float os[768];
    const int b = blockIdx.y, ng = blockIdx.x, tid = threadIdx.x;
    const bf16* orow = ob + (long)b * 256 * 768;
    for (int i = tid; i < 768; i += 256) os[i] = __bfloat162float(orow[i]);
    __syncthreads();

    const int n = ng * 32 + (tid >> 3);
    const int seg = tid & 7;
    const float* wrow = Wo5 + (long)n * 768 + seg * 96;
    const float* xs = &os[seg * 96];
    float s = 0.f;
#pragma unroll
    for (int k = 0; k < 96; k += 4) {
        const float4 w = *(const float4*)&wrow[k];
        s += xs[k] * w.x + xs[k + 1] * w.y + xs[k + 2] * w.z + xs[k + 3] * w.w;
    }
    s += __shfl_xor(s, 1);
    s += __shfl_xor(s, 2);
    s += __shfl_xor(s, 4);
    if (seg == 0) out[b * 768 + n] = s + bo5[n];
}

extern "C" void kernel_launch(void* const* d_in, const int* in_sizes, int n_in,
                              void* d_out, int out_size, void* d_ws, size_t ws_size,
                              hipStream_t stream)
{
    const int*   tokens   = (const int*)d_in[0];
    const float* embed    = (const float*)d_in[1];
    const float* pos_emb  = (const float*)d_in[2];
    const float* pos_q_w  = (const float*)d_in[3];
    const float* pos_q_b  = (const float*)d_in[4];
    const float* pos_k_w  = (const float*)d_in[5];
    const float* pos_k_b  = (const float*)d_in[6];
    const float* pos_ln_g = (const float*)d_in[7];
    const float* pos_ln_b = (const float*)d_in[8];
    const float* rel_tab  = (const float*)d_in[9];
    const int*   rp       = (const int*)d_in[10];
    const float* Wq = (const float*)d_in[11];
    const float* bq = (const float*)d_in[12];
    const float* Wk = (const float*)d_in[13];
    const float* bk = (const float*)d_in[14];
    const float* Wv = (const float*)d_in[15];
    const float* bv = (const float*)d_in[16];
    const float* Wo = (const float*)d_in[17];
    const float* bo = (const float*)d_in[18];
    float* out = (float*)d_out;

    char* p = (char*)d_ws;
    auto alloc = [&](size_t bytes) -> char* {
        char* r = p;
        p += (bytes + 255) & ~(size_t)255;
        return r;
    };
    const long NT = 32L * SEQ;  // 8192

    float* biasT = (float*)alloc(8L * SEQ * SEQ * 4);       // [h][j][i]
    float* wln   = (float*)alloc((long)SEQ * DIM * 4);
    float* pqk   = (float*)alloc(2L * SEQ * DIM * 4);       // pq | pk
    float* wsW   = (float*)alloc(2L * 768 * 768 * 4);       // posq_w | posk_w
    float* wsB   = (float*)alloc(2L * 768 * 4);
    bf16*  xb    = (bf16*) alloc(NT * DIM * 2);
    bf16*  qkv   = (bf16*) alloc(NT * 2304 * 2);
    bf16*  vT    = (bf16*) alloc(NT * DIM * 2);             // [32][768][256]
    bf16*  ob    = (bf16*) alloc(NT * DIM * 2);
    bf16*  wqkv  = (bf16*) alloc(6L * 2304 * 768 * 2);
    bf16*  woT   = (bf16*) alloc(6L * 768 * 768 * 2);
    bf16*  wf    = (bf16*) alloc(5L * 2304 * 768 * 2);
    float* bqkv  = (float*)alloc(6L * 2304 * 4);
    float* bfus  = (float*)alloc(5L * 2304 * 4);

    const float SCALE = 0.07216878364870322f;   // (HD*2)^-0.5

    // ---- all independent setup in ONE launch ----
    setup_mega_kernel<<<RB_G, 256, 0, stream>>>(
        tokens, embed, pos_emb, pos_q_w, pos_q_b, pos_k_w, pos_k_b,
        pos_ln_g, pos_ln_b, Wq, Wk, Wv, Wo, bq, bk, bv,
        wqkv, woT, bqkv, xb, wln, wsW, wsB, SCALE);

    // Wf_l = Wqkv_{l+1} . Wo_l  (batched, z = l)
    gemm_bf16_kernel<<<dim3(6, 18, 5), 512, 0, stream>>>(
        wqkv + 2304L * 768, woT, nullptr, wf, nullptr, 768, 768, 0,
        2304L * 768, 768L * 768, 2304L * 768, 0);
    fused_bias_kernel<<<dim3(72, 5), 256, 0, stream>>>(wqkv, bo, bqkv, bfus);

    // pos projections pq|pk in one batched launch
    gemm_kernel<<<dim3(12, 4, 2), 256, 0, stream>>>(
        wln, DIM, 0, wsW, DIM, 768L * 768, wsB, 768,
        pqk, DIM, (long)SEQ * DIM, SEQ, DIM, DIM, 1.0f, nullptr, nullptr);
    // biasT[h][j][i] = SCALE * (pk_j . pq_i) + rel[i,j,h]
    gemm_kernel<<<dim3(4, 4, NH), 256, 0, stream>>>(
        pqk + (long)SEQ * DIM, DIM, HD, pqk, DIM, HD, nullptr, 0,
        biasT, SEQ, (long)SEQ * SEQ, SEQ, SEQ, HD, SCALE, rp, rel_tab);

    // ---- layer pipeline ----
    gemm_bf16_kernel<<<dim3(18, 64, 1), 512, 0, stream>>>(xb, wqkv, bqkv, qkv, vT, 2304, 768, 1, 0, 0, 0, 0);
    for (int l = 0; l < 5; l++) {
        attn_mfma_kernel<<<1024, 256, 0, stream>>>(qkv, vT, biasT, ob);
        gemm_bf16_kernel<<<dim3(18, 64, 1), 512, 0, stream>>>(
            ob, wf + (long)l * 2304 * 768, bfus + (long)l * 2304, qkv, vT, 2304, 768, 1, 0, 0, 0,
            (l == 4) ? 1 : 0);
    }
    attn_mfma_kernel<<<256, 256, 0, stream>>>(qkv, vT, biasT, ob);   // it=0 only
    final_out_kernel<<<dim3(24, 32), 256, 0, stream>>>(ob, Wo + 5L * 768 * 768, bo + 5L * 768, out);
}